// Round 9
// baseline (403.067 us; speedup 1.0000x reference)
//
#include <hip/hip_runtime.h>
#include <math.h>

#define DE 128
#define NEG_SLOPE 0.2f
#define LOG2E 1.4426950408889634f
#define ESHIFT2 57.707801635559926f      /* 40 * log2(e)  (entity) */
#define ESHIFT_AGG 28.853900817779268f   /* 20 * log2(e)  (aggregate) */

typedef __attribute__((ext_vector_type(4))) float f4;
typedef __attribute__((ext_vector_type(2))) float f2;
typedef _Float16 half_t;
typedef __attribute__((ext_vector_type(2))) _Float16 h2;
typedef __attribute__((ext_vector_type(4))) _Float16 h4v;
typedef __attribute__((ext_vector_type(8))) _Float16 h8;

// All-reduce within each 16-lane DPP row (lane gets its row's sum). 4 DPP adds.
__device__ __forceinline__ float row16_allred(float x) {
    union fi { float f; int i; };
    fi a; a.f = x;
    fi t;
    t.i = __builtin_amdgcn_update_dpp(0, a.i, 0x121, 0xf, 0xf, true); a.f += t.f; // row_ror:1
    t.i = __builtin_amdgcn_update_dpp(0, a.i, 0x122, 0xf, 0xf, true); a.f += t.f; // row_ror:2
    t.i = __builtin_amdgcn_update_dpp(0, a.i, 0x124, 0xf, 0xf, true); a.f += t.f; // row_ror:4
    t.i = __builtin_amdgcn_update_dpp(0, a.i, 0x128, 0xf, 0xf, true); a.f += t.f; // row_ror:8
    return a.f;
}

// All-reduce within each 32-lane half: 4 ROW_ROR DPP adds (16-lane row sums)
// + one ds_swizzle xor-16 (BitMode 0x401F: lane' = (lane&31)^16) + add.
__device__ __forceinline__ float red32(float x) {
    union fi { float f; int i; };
    fi a; a.f = x;
    fi t;
    t.i = __builtin_amdgcn_update_dpp(0, a.i, 0x121, 0xf, 0xf, true); a.f += t.f; // row_ror:1
    t.i = __builtin_amdgcn_update_dpp(0, a.i, 0x122, 0xf, 0xf, true); a.f += t.f; // row_ror:2
    t.i = __builtin_amdgcn_update_dpp(0, a.i, 0x124, 0xf, 0xf, true); a.f += t.f; // row_ror:4
    t.i = __builtin_amdgcn_update_dpp(0, a.i, 0x128, 0xf, 0xf, true); a.f += t.f; // row_ror:8
    t.i = __builtin_amdgcn_ds_swizzle(a.i, 0x401F);                  a.f += t.f; // xor 16
    return a.f;
}

// ---------------------------------------------------------------- CSR build
__global__ __launch_bounds__(256) void k_count(const int* __restrict__ ei, int E, int N,
                                               int* __restrict__ cnt) {
    int e = blockIdx.x * blockDim.x + threadIdx.x;
    int total = E + N;
    if (e >= total) return;
    int dst = (e < E) ? ei[E + e] : (e - E);
    atomicAdd(&cnt[dst], 1);
}

__global__ __launch_bounds__(1024) void k_scan(const int* __restrict__ cnt, int n,
                                               int* __restrict__ indptr) {
    __shared__ int wsum[16];
    __shared__ int btot;
    int tid = threadIdx.x, lane = tid & 63, w = tid >> 6;
    int carry = 0;
    for (int base = 0; base < n; base += 1024) {
        int i = base + tid;
        int v = (i < n) ? cnt[i] : 0;
        int x = v;
#pragma unroll
        for (int off = 1; off < 64; off <<= 1) {
            int t = __shfl_up(x, off, 64);
            if (lane >= off) x += t;
        }
        if (lane == 63) wsum[w] = x;
        __syncthreads();
        if (w == 0) {
            int s = (lane < 16) ? wsum[lane] : 0;
#pragma unroll
            for (int off = 1; off < 16; off <<= 1) {
                int t = __shfl_up(s, off, 64);
                if (lane >= off) s += t;
            }
            if (lane < 16) wsum[lane] = s;
            if (lane == 15) btot = s;
        }
        __syncthreads();
        int wexcl = (w == 0) ? 0 : wsum[w - 1];
        if (i < n) indptr[i] = carry + wexcl + (x - v);
        carry += btot;
        __syncthreads();
    }
    if (tid == 0) indptr[n] = carry;
}

__global__ __launch_bounds__(256) void k_fill(const int* __restrict__ ei, int E, int N,
                                              const int* __restrict__ indptr,
                                              int* __restrict__ cur, int* __restrict__ adj) {
    int e = blockIdx.x * blockDim.x + threadIdx.x;
    int total = E + N;
    if (e >= total) return;
    int src, dst;
    if (e < E) { src = ei[e]; dst = ei[E + e]; }
    else       { src = dst = e - E; }
    int pos = indptr[dst] + atomicAdd(&cur[dst], 1);
    adj[pos] = src;
}

// ---------------------------------------------------------------- small f32 GEMM (500-row rel tables)
template <int RPT>
__global__ __launch_bounds__(256) void k_gemm(const float* __restrict__ in, int rows,
                                              const float* __restrict__ W, int ldw, int wcol0,
                                              const float* __restrict__ bias,
                                              float* __restrict__ out) {
    __shared__ float Wt[128 * 128];
    const int tid = threadIdx.x;
#pragma unroll
    for (int it = 0; it < 16; ++it) {
        int idx = it * 256 + tid;
        int c = idx & 127, k4 = idx >> 7;
        f4 wv = *(const f4*)(W + (size_t)c * ldw + wcol0 + k4 * 4);
#pragma unroll
        for (int j = 0; j < 4; ++j) Wt[(4 * k4 + j) * 128 + c] = wv[j];
    }
    __syncthreads();

    const int cgrp = tid & 15, rgrp = tid >> 4;
    const int c0 = cgrp * 4;
    const int row0 = blockIdx.x * (16 * RPT) + rgrp * RPT;

    const float* rowp[RPT];
#pragma unroll
    for (int i = 0; i < RPT; ++i)
        rowp[i] = in + (size_t)min(row0 + i, rows - 1) * 128;

    float acc[RPT][8];
#pragma unroll
    for (int i = 0; i < RPT; ++i)
#pragma unroll
        for (int j = 0; j < 8; ++j) acc[i][j] = 0.f;

#pragma unroll 1
    for (int k = 0; k < 128; k += 4) {
        f4 a[RPT];
#pragma unroll
        for (int i = 0; i < RPT; ++i) a[i] = *(const f4*)(rowp[i] + k);
#pragma unroll
        for (int kk = 0; kk < 4; ++kk) {
            f4 b0 = *(const f4*)&Wt[(k + kk) * 128 + c0];
            f4 b1 = *(const f4*)&Wt[(k + kk) * 128 + c0 + 64];
#pragma unroll
            for (int i = 0; i < RPT; ++i) {
                float av = a[i][kk];
#pragma unroll
                for (int j = 0; j < 4; ++j) {
                    acc[i][j]     = fmaf(av, b0[j], acc[i][j]);
                    acc[i][j + 4] = fmaf(av, b1[j], acc[i][j + 4]);
                }
            }
        }
    }
    f4 bi0 = {0.f,0.f,0.f,0.f}, bi1 = {0.f,0.f,0.f,0.f};
    if (bias) { bi0 = *(const f4*)(bias + c0); bi1 = *(const f4*)(bias + c0 + 64); }
#pragma unroll
    for (int i = 0; i < RPT; ++i) {
        int r = row0 + i;
        if (r < rows) {
            f4 v0, v1;
#pragma unroll
            for (int j = 0; j < 4; ++j) { v0[j] = acc[i][j] + bi0[j]; v1[j] = acc[i][j+4] + bi1[j]; }
            *(f4*)(out + (size_t)r * 128 + c0) = v0;
            *(f4*)(out + (size_t)r * 128 + c0 + 64) = v1;
        }
    }
}

// ---------------------------------------------------------------- MFMA GEMM (fp16 in, f32 acc)
// NOTE: als/ald are stored PRE-SCALED by log2(e) (consumed by k_aggregate's exp2).
template <typename AT>
__global__ __launch_bounds__(256) void k_gemm_mfma(const AT* __restrict__ A, int rows,
                                                   const float* __restrict__ W, int ldw, int wcol0,
                                                   const float* __restrict__ bias,
                                                   const float* __restrict__ addtab,
                                                   const int* __restrict__ addidx,
                                                   const float* __restrict__ avs,
                                                   const float* __restrict__ avd,
                                                   float* __restrict__ als,
                                                   float* __restrict__ ald,
                                                   half_t* __restrict__ out16) {
    __shared__ alignas(16) char ldsbuf[128 * 136 * 2];  // Wl (fp16) then aliased as Dl (f32)
    half_t* Wl = (half_t*)ldsbuf;
    float*  Dl = (float*)ldsbuf;

    const int tid = threadIdx.x;
    const int row0 = blockIdx.x * 64;

    for (int i = tid * 4; i < 128 * 128; i += 1024) {
        int c = i >> 7, k = i & 127;
        f4 wv = *(const f4*)(W + (size_t)c * ldw + wcol0 + k);
        h4v hv = {(half_t)wv[0], (half_t)wv[1], (half_t)wv[2], (half_t)wv[3]};
        *(h4v*)(Wl + c * 136 + k) = hv;
    }
    __syncthreads();

    const int wv_id = tid >> 6, l = tid & 63, lr = l & 15, lk = l >> 4;
    const int r_a = min(row0 + wv_id * 16 + lr, rows - 1);

    h8 af[4];
#pragma unroll
    for (int ks = 0; ks < 4; ++ks) {
        if constexpr (sizeof(AT) == 4) {
            f4 a0 = *(const f4*)(A + (size_t)r_a * 128 + ks * 32 + lk * 8);
            f4 a1 = *(const f4*)(A + (size_t)r_a * 128 + ks * 32 + lk * 8 + 4);
            h8 v = {(half_t)a0[0], (half_t)a0[1], (half_t)a0[2], (half_t)a0[3],
                    (half_t)a1[0], (half_t)a1[1], (half_t)a1[2], (half_t)a1[3]};
            af[ks] = v;
        } else {
            af[ks] = *(const h8*)(A + (size_t)r_a * 128 + ks * 32 + lk * 8);
        }
    }

    f4 acc[8];
#pragma unroll
    for (int t = 0; t < 8; ++t) acc[t] = (f4){0.f, 0.f, 0.f, 0.f};
#pragma unroll
    for (int ks = 0; ks < 4; ++ks) {
#pragma unroll
        for (int t = 0; t < 8; ++t) {
            h8 bf = *(const h8*)(Wl + (t * 16 + lr) * 136 + ks * 32 + lk * 8);
            acc[t] = __builtin_amdgcn_mfma_f32_16x16x32_f16(af[ks], bf, acc[t], 0, 0, 0);
        }
    }
    __syncthreads();

#pragma unroll
    for (int t = 0; t < 8; ++t)
#pragma unroll
        for (int q = 0; q < 4; ++q)
            Dl[(wv_id * 16 + lk * 4 + q) * 132 + t * 16 + lr] = acc[t][q];
    __syncthreads();

    const int cl = (tid & 15) * 8;
    f4 bi0 = {0.f,0.f,0.f,0.f}, bi1 = bi0;
    if (bias) { bi0 = *(const f4*)(bias + cl); bi1 = *(const f4*)(bias + cl + 4); }
    f4 as0 = {0.f,0.f,0.f,0.f}, as1 = as0, ad0 = as0, ad1 = as0;
    if (als) {
        as0 = *(const f4*)(avs + cl) * LOG2E; as1 = *(const f4*)(avs + cl + 4) * LOG2E;
        ad0 = *(const f4*)(avd + cl) * LOG2E; ad1 = *(const f4*)(avd + cl + 4) * LOG2E;
    }
#pragma unroll
    for (int pass = 0; pass < 4; ++pass) {
        int lrow = pass * 16 + (tid >> 4);
        int r = row0 + lrow;
        bool ok = r < rows;
        f4 v0 = *(const f4*)(Dl + lrow * 132 + cl);
        f4 v1 = *(const f4*)(Dl + lrow * 132 + cl + 4);
        v0 += bi0; v1 += bi1;
        if (addtab) {
            int ri = addidx[min(r, rows - 1)];
            v0 += *(const f4*)(addtab + (size_t)ri * 128 + cl);
            v1 += *(const f4*)(addtab + (size_t)ri * 128 + cl + 4);
        }
        if (als) {
            float ps = 0.f, pd = 0.f;
#pragma unroll
            for (int j = 0; j < 4; ++j) {
                ps += v0[j] * as0[j] + v1[j] * as1[j];
                pd += v0[j] * ad0[j] + v1[j] * ad1[j];
            }
            ps = row16_allred(ps);
            pd = row16_allred(pd);
            if ((tid & 15) == 0 && ok) { als[r] = ps; ald[r] = pd; }
        }
        if (ok) {
            h8 o = {(half_t)v0[0], (half_t)v0[1], (half_t)v0[2], (half_t)v0[3],
                    (half_t)v1[0], (half_t)v1[1], (half_t)v1[2], (half_t)v1[3]};
            *(h8*)(out16 + (size_t)r * 128 + cl) = o;
        }
    }
}

// ---------------------------------------------------------------- entity attention
// TWO nodes per wave: lanes 0-31 = node A, 32-63 = node B; lane owns 4 cols
// (8B h4 gathers; row still 256B). 32-lane allreduce = 4 DPP + 1 ds_swizzle.
// Shift folded into lane-0 partial; statically unrolled double-buffer (r5
// register discipline). Softmax weights via exp2 (prescaled rp).
__global__ __launch_bounds__(256, 5) void k_entity(const int* __restrict__ hA,
                                                   const int* __restrict__ tA,
                                                   const int* __restrict__ ridx,
                                                   const half_t* __restrict__ pattr,
                                                   const float* __restrict__ prel,
                                                   half_t* __restrict__ s_emb16, int N) {
    const int tid = threadIdx.x;
    const int wv = (blockIdx.x * 256 + tid) >> 6;
    const int nodeA = wv * 2;
    if (nodeA >= N) return;
    const int lane = tid & 63;
    const int node = min(nodeA + (lane >> 5), N - 1);  // N odd tail: dup write, same value
    const int sl = lane & 31;
    const int c = sl * 4;

    const int* __restrict__ hp = hA + (size_t)node * 16;
    const int* __restrict__ tp = tA + (size_t)node * 16;
    const int ri = ridx[node];
    f4 rp4 = *(const f4*)(prel + (size_t)ri * 128 + c);
    float rs0 = rp4[0] * LOG2E, rs1 = rp4[1] * LOG2E;
    float rs2 = rp4[2] * LOG2E, rs3 = rp4[3] * LOG2E;
    const float init = (sl == 0) ? -ESHIFT2 : 0.f;

    float sh = 0.f, st = 0.f;
    float acch[4] = {0.f, 0.f, 0.f, 0.f}, acct[4] = {0.f, 0.f, 0.f, 0.f};

    auto ld = [&](int idx) -> h4v { return *(const h4v*)(pattr + (size_t)idx * 128 + c); };

    h4v bh[2][4], bt[2][4];
    {
        int4 ih = *(const int4*)hp, it = *(const int4*)tp;
        bh[0][0] = ld(ih.x); bh[0][1] = ld(ih.y); bh[0][2] = ld(ih.z); bh[0][3] = ld(ih.w);
        bt[0][0] = ld(it.x); bt[0][1] = ld(it.y); bt[0][2] = ld(it.z); bt[0][3] = ld(it.w);
    }
#pragma unroll
    for (int b = 0; b < 4; ++b) {
        const int cur = b & 1, nxt = cur ^ 1;
        if (b < 3) {
            int4 ih = *(const int4*)(hp + 4 * (b + 1));
            int4 it = *(const int4*)(tp + 4 * (b + 1));
            bh[nxt][0] = ld(ih.x); bh[nxt][1] = ld(ih.y); bh[nxt][2] = ld(ih.z); bh[nxt][3] = ld(ih.w);
            bt[nxt][0] = ld(it.x); bt[nxt][1] = ld(it.y); bt[nxt][2] = ld(it.z); bt[nxt][3] = ld(it.w);
        }
#pragma unroll
        for (int q = 0; q < 4; ++q) {
            h4v vh = bh[cur][q], vt = bt[cur][q];
            float fh[4], ft[4];
#pragma unroll
            for (int j = 0; j < 4; ++j) { fh[j] = (float)vh[j]; ft[j] = (float)vt[j]; }
            float ph0 = fmaf(fh[0], rs0, init); ph0 = fmaf(fh[2], rs2, ph0);
            float ph1 = fmaf(fh[1], rs1, 0.f);  ph1 = fmaf(fh[3], rs3, ph1);
            float pt0 = fmaf(ft[0], rs0, init); pt0 = fmaf(ft[2], rs2, pt0);
            float pt1 = fmaf(ft[1], rs1, 0.f);  pt1 = fmaf(ft[3], rs3, pt1);
            float Sh = red32(ph0 + ph1);
            float St = red32(pt0 + pt1);
            float wh = exp2f(Sh);
            float wt = exp2f(St);
            sh += wh; st += wt;
#pragma unroll
            for (int j = 0; j < 4; ++j) {
                acch[j] = fmaf(wh, fh[j], acch[j]);
                acct[j] = fmaf(wt, ft[j], acct[j]);
            }
        }
    }
    float invh = 1.f / sh, invt = 1.f / st;
    h4v o;
#pragma unroll
    for (int j = 0; j < 4; ++j) o[j] = (half_t)(acch[j] * invh + acct[j] * invt);
    *(h4v*)(s_emb16 + (size_t)node * 128 + c) = o;
}

// ---------------------------------------------------------------- GAT aggregate (CSR)
// TWO nodes per wave (halves), lane owns 4 cols (8B h4 gathers). Edge scalars
// via per-half same-address vector loads; als/ald are pre-scaled by log2(e)
// -> exp2 directly. Batch-4 edge unroll with predication; adj padded +8; index
// clamped vs pad garbage. Single pass, shift-invariant softmax (shift 20).
__global__ __launch_bounds__(256) void k_aggregate(const int* __restrict__ indptr,
                                                   const int* __restrict__ adj,
                                                   const half_t* __restrict__ hsrc,
                                                   const float* __restrict__ als,
                                                   const float* __restrict__ ald,
                                                   const float* __restrict__ bias,
                                                   float* __restrict__ out,
                                                   half_t* __restrict__ out16, int N) {
    const int tid = threadIdx.x;
    const int wv = (blockIdx.x * 256 + tid) >> 6;
    const int nodeA = wv * 2;
    if (nodeA >= N) return;
    const int lane = tid & 63;
    const int node = min(nodeA + (lane >> 5), N - 1);
    const int sl = lane & 31;
    const int c = sl * 4;

    const int beg = indptr[node];
    const int deg = indptr[node + 1] - beg;
    const float adn = ald[node];  // pre-scaled by log2(e)

    float acc[4] = {0.f, 0.f, 0.f, 0.f};
    float exsum = 0.f;
#pragma unroll 1
    for (int j0 = 0; j0 < deg; j0 += 4) {
        int sr[4];
#pragma unroll
        for (int q = 0; q < 4; ++q) sr[q] = adj[beg + j0 + q];  // padded; same addr per half
#pragma unroll
        for (int q = 0; q < 4; ++q) {
            bool ok = (j0 + q) < deg;
            int s = ((unsigned)sr[q] < (unsigned)N) ? sr[q] : 0;  // pad-garbage guard
            float e = als[s] + adn;
            e = fmaxf(e, NEG_SLOPE * e);
            float ex = ok ? exp2f(e - ESHIFT_AGG) : 0.f;
            h4v v = *(const h4v*)(hsrc + (size_t)s * 128 + c);
            exsum += ex;
#pragma unroll
            for (int j = 0; j < 4; ++j) acc[j] = fmaf(ex, (float)v[j], acc[j]);
        }
    }
    float inv = 1.f / exsum;
    if (out) {
        f4 o;
#pragma unroll
        for (int j = 0; j < 4; ++j) o[j] = fmaf(acc[j], inv, bias[c + j]);
        *(f4*)(out + (size_t)node * 128 + c) = o;
    } else {
        h4v o;
#pragma unroll
        for (int j = 0; j < 4; ++j) o[j] = (half_t)fmaf(acc[j], inv, bias[c + j]);
        *(h4v*)(out16 + (size_t)node * 128 + c) = o;
    }
}

// ---------------------------------------------------------------- launch
extern "C" void kernel_launch(void* const* d_in, const int* in_sizes, int n_in,
                              void* d_out, int out_size, void* d_ws, size_t ws_size,
                              hipStream_t stream) {
    const int*   hA   = (const int*)d_in[0];
    const int*   tA   = (const int*)d_in[1];
    const int*   rix  = (const int*)d_in[2];
    const int*   ei   = (const int*)d_in[3];
    const float* attr_table = (const float*)d_in[4];
    const float* rel_table  = (const float*)d_in[5];
    const float* femb_w = (const float*)d_in[6];
    const float* femb_b = (const float*)d_in[7];
    const float* g1w  = (const float*)d_in[8];
    const float* g1as = (const float*)d_in[9];
    const float* g1ad = (const float*)d_in[10];
    const float* g1b  = (const float*)d_in[11];
    const float* g2w  = (const float*)d_in[12];
    const float* g2as = (const float*)d_in[13];
    const float* g2ad = (const float*)d_in[14];
    const float* g2b  = (const float*)d_in[15];

    const int N  = in_sizes[2];
    const int E  = in_sizes[3] / 2;
    const int NA = in_sizes[4] / DE;
    const int NR = in_sizes[5] / DE;
    const int EN = E + N;

    char* p = (char*)d_ws;
    auto alloc = [&](size_t bytes) -> char* {
        char* q = p;
        p += (bytes + 255) & ~(size_t)255;
        return q;
    };
    half_t* proj16 = (half_t*)alloc((size_t)NA * DE * 2);
    half_t* s16    = (half_t*)alloc((size_t)N * DE * 2);
    half_t* h16    = (half_t*)alloc((size_t)N * DE * 2);
    half_t* x116   = (half_t*)alloc((size_t)N * DE * 2);
    float* prel    = (float*)alloc((size_t)NR * DE * 4);
    float* rel2    = (float*)alloc((size_t)NR * DE * 4);
    float* alps    = (float*)alloc((size_t)N * 4);
    float* alpd    = (float*)alloc((size_t)N * 4);
    int*   indptr  = (int*)alloc((size_t)(N + 1) * 4);
    int*   cnt     = (int*)alloc((size_t)N * 4);
    int*   cur     = (int*)alloc((size_t)N * 4);
    int*   adj     = (int*)alloc((size_t)(EN + 8) * 4);  // +8 pad for batch over-read

    dim3 b256(256);

    // CSR build (same edge set both layers -> build once)
    hipMemsetAsync(cnt, 0, (size_t)N * 4, stream);
    hipMemsetAsync(cur, 0, (size_t)N * 4, stream);
    k_count<<<dim3((EN + 255) / 256), b256, 0, stream>>>(ei, E, N, cnt);
    k_scan<<<dim3(1), dim3(1024), 0, stream>>>(cnt, N, indptr);
    k_fill<<<dim3((EN + 255) / 256), b256, 0, stream>>>(ei, E, N, indptr, cur, adj);

    // rel-table projections (500 rows, f32 path)
    k_gemm<2><<<dim3((NR + 31) / 32), b256, 0, stream>>>(rel_table, NR, femb_w, DE, 0,
                                                         femb_b, prel);
    k_gemm<2><<<dim3((NR + 31) / 32), b256, 0, stream>>>(rel_table, NR, g1w, 2 * DE, DE,
                                                         nullptr, rel2);

    // attr table projection straight to fp16 (MFMA, f32 A-path)
    k_gemm_mfma<float><<<dim3((NA + 63) / 64), b256, 0, stream>>>(attr_table, NA,
        femb_w, DE, 0, femb_b, nullptr, nullptr, nullptr, nullptr, nullptr, nullptr, proj16);

    // entity attention (h + t fused), TWO nodes per wave
    k_entity<<<dim3((N + 7) / 8), b256, 0, stream>>>(hA, tA, rix, proj16, prel, s16, N);

    // GAT layer 1: h = s_emb @ Wl.T + rel2[r_idx]; alpha fused (pre-scaled); h fp16
    k_gemm_mfma<half_t><<<dim3((N + 63) / 64), b256, 0, stream>>>(s16, N,
        g1w, 2 * DE, 0, nullptr, rel2, rix, g1as, g1ad, alps, alpd, h16);
    k_aggregate<<<dim3((N + 7) / 8), b256, 0, stream>>>(indptr, adj, h16, alps, alpd, g1b,
                                                        nullptr, x116, N);

    // GAT layer 2
    k_gemm_mfma<half_t><<<dim3((N + 63) / 64), b256, 0, stream>>>(x116, N,
        g2w, DE, 0, nullptr, nullptr, nullptr, g2as, g2ad, alps, alpd, h16);
    k_aggregate<<<dim3((N + 7) / 8), b256, 0, stream>>>(indptr, adj, h16, alps, alpd, g2b,
                                                        (float*)d_out, nullptr, N);
}

// Round 10
// 329.349 us; speedup vs baseline: 1.2238x; 1.2238x over previous
//
#include <hip/hip_runtime.h>
#include <math.h>

#define DE 128
#define NEG_SLOPE 0.2f
#define LOG2E 1.4426950408889634f
#define ESHIFT2 57.707801635559926f      /* 40 * log2(e)  (entity) */
#define ESHIFT_AGG 28.853900817779268f   /* 20 * log2(e)  (aggregate) */

typedef __attribute__((ext_vector_type(4))) float f4;
typedef __attribute__((ext_vector_type(2))) float f2;
typedef _Float16 half_t;
typedef __attribute__((ext_vector_type(2))) _Float16 h2;
typedef __attribute__((ext_vector_type(4))) _Float16 h4v;
typedef __attribute__((ext_vector_type(8))) _Float16 h8;

// Wave64 sum-reduce on the VALU only (DPP adds + readlane), zero LDS-pipe ops.
__device__ __forceinline__ float wave_red_bcast(float x) {
    union fi { float f; int i; };
    fi a; a.f = x;
    fi t;
    t.i = __builtin_amdgcn_update_dpp(0, a.i, 0x111, 0xf, 0xf, true); a.f += t.f; // row_shr:1
    t.i = __builtin_amdgcn_update_dpp(0, a.i, 0x112, 0xf, 0xf, true); a.f += t.f; // row_shr:2
    t.i = __builtin_amdgcn_update_dpp(0, a.i, 0x114, 0xf, 0xf, true); a.f += t.f; // row_shr:4
    t.i = __builtin_amdgcn_update_dpp(0, a.i, 0x118, 0xf, 0xf, true); a.f += t.f; // row_shr:8
    t.i = __builtin_amdgcn_update_dpp(0, a.i, 0x142, 0xa, 0xf, true); a.f += t.f; // row_bcast:15
    t.i = __builtin_amdgcn_update_dpp(0, a.i, 0x143, 0xc, 0xf, true); a.f += t.f; // row_bcast:31
    fi r; r.i = __builtin_amdgcn_readlane(a.i, 63);
    return r.f;
}

// All-reduce within each 16-lane DPP row (lane gets its row's sum). 4 DPP adds.
__device__ __forceinline__ float row16_allred(float x) {
    union fi { float f; int i; };
    fi a; a.f = x;
    fi t;
    t.i = __builtin_amdgcn_update_dpp(0, a.i, 0x121, 0xf, 0xf, true); a.f += t.f; // row_ror:1
    t.i = __builtin_amdgcn_update_dpp(0, a.i, 0x122, 0xf, 0xf, true); a.f += t.f; // row_ror:2
    t.i = __builtin_amdgcn_update_dpp(0, a.i, 0x124, 0xf, 0xf, true); a.f += t.f; // row_ror:4
    t.i = __builtin_amdgcn_update_dpp(0, a.i, 0x128, 0xf, 0xf, true); a.f += t.f; // row_ror:8
    return a.f;
}

// ---------------------------------------------------------------- CSR build
__global__ __launch_bounds__(256) void k_count(const int* __restrict__ ei, int E, int N,
                                               int* __restrict__ cnt) {
    int e = blockIdx.x * blockDim.x + threadIdx.x;
    int total = E + N;
    if (e >= total) return;
    int dst = (e < E) ? ei[E + e] : (e - E);
    atomicAdd(&cnt[dst], 1);
}

__global__ __launch_bounds__(1024) void k_scan(const int* __restrict__ cnt, int n,
                                               int* __restrict__ indptr) {
    __shared__ int wsum[16];
    __shared__ int btot;
    int tid = threadIdx.x, lane = tid & 63, w = tid >> 6;
    int carry = 0;
    for (int base = 0; base < n; base += 1024) {
        int i = base + tid;
        int v = (i < n) ? cnt[i] : 0;
        int x = v;
#pragma unroll
        for (int off = 1; off < 64; off <<= 1) {
            int t = __shfl_up(x, off, 64);
            if (lane >= off) x += t;
        }
        if (lane == 63) wsum[w] = x;
        __syncthreads();
        if (w == 0) {
            int s = (lane < 16) ? wsum[lane] : 0;
#pragma unroll
            for (int off = 1; off < 16; off <<= 1) {
                int t = __shfl_up(s, off, 64);
                if (lane >= off) s += t;
            }
            if (lane < 16) wsum[lane] = s;
            if (lane == 15) btot = s;
        }
        __syncthreads();
        int wexcl = (w == 0) ? 0 : wsum[w - 1];
        if (i < n) indptr[i] = carry + wexcl + (x - v);
        carry += btot;
        __syncthreads();
    }
    if (tid == 0) indptr[n] = carry;
}

__global__ __launch_bounds__(256) void k_fill(const int* __restrict__ ei, int E, int N,
                                              const int* __restrict__ indptr,
                                              int* __restrict__ cur, int* __restrict__ adj) {
    int e = blockIdx.x * blockDim.x + threadIdx.x;
    int total = E + N;
    if (e >= total) return;
    int src, dst;
    if (e < E) { src = ei[e]; dst = ei[E + e]; }
    else       { src = dst = e - E; }
    int pos = indptr[dst] + atomicAdd(&cur[dst], 1);
    adj[pos] = src;
}

// ---------------------------------------------------------------- small f32 GEMM (500-row rel tables)
template <int RPT>
__global__ __launch_bounds__(256) void k_gemm(const float* __restrict__ in, int rows,
                                              const float* __restrict__ W, int ldw, int wcol0,
                                              const float* __restrict__ bias,
                                              float* __restrict__ out) {
    __shared__ float Wt[128 * 128];
    const int tid = threadIdx.x;
#pragma unroll
    for (int it = 0; it < 16; ++it) {
        int idx = it * 256 + tid;
        int c = idx & 127, k4 = idx >> 7;
        f4 wv = *(const f4*)(W + (size_t)c * ldw + wcol0 + k4 * 4);
#pragma unroll
        for (int j = 0; j < 4; ++j) Wt[(4 * k4 + j) * 128 + c] = wv[j];
    }
    __syncthreads();

    const int cgrp = tid & 15, rgrp = tid >> 4;
    const int c0 = cgrp * 4;
    const int row0 = blockIdx.x * (16 * RPT) + rgrp * RPT;

    const float* rowp[RPT];
#pragma unroll
    for (int i = 0; i < RPT; ++i)
        rowp[i] = in + (size_t)min(row0 + i, rows - 1) * 128;

    float acc[RPT][8];
#pragma unroll
    for (int i = 0; i < RPT; ++i)
#pragma unroll
        for (int j = 0; j < 8; ++j) acc[i][j] = 0.f;

#pragma unroll 1
    for (int k = 0; k < 128; k += 4) {
        f4 a[RPT];
#pragma unroll
        for (int i = 0; i < RPT; ++i) a[i] = *(const f4*)(rowp[i] + k);
#pragma unroll
        for (int kk = 0; kk < 4; ++kk) {
            f4 b0 = *(const f4*)&Wt[(k + kk) * 128 + c0];
            f4 b1 = *(const f4*)&Wt[(k + kk) * 128 + c0 + 64];
#pragma unroll
            for (int i = 0; i < RPT; ++i) {
                float av = a[i][kk];
#pragma unroll
                for (int j = 0; j < 4; ++j) {
                    acc[i][j]     = fmaf(av, b0[j], acc[i][j]);
                    acc[i][j + 4] = fmaf(av, b1[j], acc[i][j + 4]);
                }
            }
        }
    }
    f4 bi0 = {0.f,0.f,0.f,0.f}, bi1 = {0.f,0.f,0.f,0.f};
    if (bias) { bi0 = *(const f4*)(bias + c0); bi1 = *(const f4*)(bias + c0 + 64); }
#pragma unroll
    for (int i = 0; i < RPT; ++i) {
        int r = row0 + i;
        if (r < rows) {
            f4 v0, v1;
#pragma unroll
            for (int j = 0; j < 4; ++j) { v0[j] = acc[i][j] + bi0[j]; v1[j] = acc[i][j+4] + bi1[j]; }
            *(f4*)(out + (size_t)r * 128 + c0) = v0;
            *(f4*)(out + (size_t)r * 128 + c0 + 64) = v1;
        }
    }
}

// ---------------------------------------------------------------- MFMA GEMM (fp16 in, f32 acc)
// NOTE: als/ald are stored PRE-SCALED by log2(e) (consumed by k_aggregate's exp2).
template <typename AT>
__global__ __launch_bounds__(256) void k_gemm_mfma(const AT* __restrict__ A, int rows,
                                                   const float* __restrict__ W, int ldw, int wcol0,
                                                   const float* __restrict__ bias,
                                                   const float* __restrict__ addtab,
                                                   const int* __restrict__ addidx,
                                                   const float* __restrict__ avs,
                                                   const float* __restrict__ avd,
                                                   float* __restrict__ als,
                                                   float* __restrict__ ald,
                                                   half_t* __restrict__ out16) {
    __shared__ alignas(16) char ldsbuf[128 * 136 * 2];  // Wl (fp16) then aliased as Dl (f32)
    half_t* Wl = (half_t*)ldsbuf;
    float*  Dl = (float*)ldsbuf;

    const int tid = threadIdx.x;
    const int row0 = blockIdx.x * 64;

    for (int i = tid * 4; i < 128 * 128; i += 1024) {
        int c = i >> 7, k = i & 127;
        f4 wv = *(const f4*)(W + (size_t)c * ldw + wcol0 + k);
        h4v hv = {(half_t)wv[0], (half_t)wv[1], (half_t)wv[2], (half_t)wv[3]};
        *(h4v*)(Wl + c * 136 + k) = hv;
    }
    __syncthreads();

    const int wv_id = tid >> 6, l = tid & 63, lr = l & 15, lk = l >> 4;
    const int r_a = min(row0 + wv_id * 16 + lr, rows - 1);

    h8 af[4];
#pragma unroll
    for (int ks = 0; ks < 4; ++ks) {
        if constexpr (sizeof(AT) == 4) {
            f4 a0 = *(const f4*)(A + (size_t)r_a * 128 + ks * 32 + lk * 8);
            f4 a1 = *(const f4*)(A + (size_t)r_a * 128 + ks * 32 + lk * 8 + 4);
            h8 v = {(half_t)a0[0], (half_t)a0[1], (half_t)a0[2], (half_t)a0[3],
                    (half_t)a1[0], (half_t)a1[1], (half_t)a1[2], (half_t)a1[3]};
            af[ks] = v;
        } else {
            af[ks] = *(const h8*)(A + (size_t)r_a * 128 + ks * 32 + lk * 8);
        }
    }

    f4 acc[8];
#pragma unroll
    for (int t = 0; t < 8; ++t) acc[t] = (f4){0.f, 0.f, 0.f, 0.f};
#pragma unroll
    for (int ks = 0; ks < 4; ++ks) {
#pragma unroll
        for (int t = 0; t < 8; ++t) {
            h8 bf = *(const h8*)(Wl + (t * 16 + lr) * 136 + ks * 32 + lk * 8);
            acc[t] = __builtin_amdgcn_mfma_f32_16x16x32_f16(af[ks], bf, acc[t], 0, 0, 0);
        }
    }
    __syncthreads();

#pragma unroll
    for (int t = 0; t < 8; ++t)
#pragma unroll
        for (int q = 0; q < 4; ++q)
            Dl[(wv_id * 16 + lk * 4 + q) * 132 + t * 16 + lr] = acc[t][q];
    __syncthreads();

    const int cl = (tid & 15) * 8;
    f4 bi0 = {0.f,0.f,0.f,0.f}, bi1 = bi0;
    if (bias) { bi0 = *(const f4*)(bias + cl); bi1 = *(const f4*)(bias + cl + 4); }
    f4 as0 = {0.f,0.f,0.f,0.f}, as1 = as0, ad0 = as0, ad1 = as0;
    if (als) {
        as0 = *(const f4*)(avs + cl) * LOG2E; as1 = *(const f4*)(avs + cl + 4) * LOG2E;
        ad0 = *(const f4*)(avd + cl) * LOG2E; ad1 = *(const f4*)(avd + cl + 4) * LOG2E;
    }
#pragma unroll
    for (int pass = 0; pass < 4; ++pass) {
        int lrow = pass * 16 + (tid >> 4);
        int r = row0 + lrow;
        bool ok = r < rows;
        f4 v0 = *(const f4*)(Dl + lrow * 132 + cl);
        f4 v1 = *(const f4*)(Dl + lrow * 132 + cl + 4);
        v0 += bi0; v1 += bi1;
        if (addtab) {
            int ri = addidx[min(r, rows - 1)];
            v0 += *(const f4*)(addtab + (size_t)ri * 128 + cl);
            v1 += *(const f4*)(addtab + (size_t)ri * 128 + cl + 4);
        }
        if (als) {
            float ps = 0.f, pd = 0.f;
#pragma unroll
            for (int j = 0; j < 4; ++j) {
                ps += v0[j] * as0[j] + v1[j] * as1[j];
                pd += v0[j] * ad0[j] + v1[j] * ad1[j];
            }
            ps = row16_allred(ps);
            pd = row16_allred(pd);
            if ((tid & 15) == 0 && ok) { als[r] = ps; ald[r] = pd; }
        }
        if (ok) {
            h8 o = {(half_t)v0[0], (half_t)v0[1], (half_t)v0[2], (half_t)v0[3],
                    (half_t)v1[0], (half_t)v1[1], (half_t)v1[2], (half_t)v1[3]};
            *(h8*)(out16 + (size_t)r * 128 + cl) = o;
        }
    }
}

// ---------------------------------------------------------------- entity attention (r8 structure — measured optimum)
// One wave per node; lane owns cols {2l,2l+1} (4B fp16 gathers, whole wave
// covers one 256B row per instruction). Pure-VALU DPP reduce; shift-invariant
// softmax, fixed shift 40 via exp2 (prescaled rp). fp16 output.
__global__ __launch_bounds__(256) void k_entity(const int* __restrict__ hA,
                                                const int* __restrict__ tA,
                                                const int* __restrict__ ridx,
                                                const half_t* __restrict__ pattr,
                                                const float* __restrict__ prel,
                                                half_t* __restrict__ s_emb16, int N) {
    int w = (blockIdx.x * blockDim.x + threadIdx.x) >> 6;
    if (w >= N) return;
    w = __builtin_amdgcn_readfirstlane(w);
    const int lane = threadIdx.x & 63;
    const int c = lane * 2;
    const int ri = ridx[w];
    const f2 rp = *(const f2*)(prel + (size_t)ri * 128 + c);
    const float rs0 = rp[0] * LOG2E, rs1 = rp[1] * LOG2E;
    const int* __restrict__ hp = hA + (size_t)w * 16;
    const int* __restrict__ tp = tA + (size_t)w * 16;

    f2 oh = {0.f, 0.f}, ot = {0.f, 0.f};
    float sh = 0.f, st = 0.f;

    h2 bh[2][4], bt[2][4];
#pragma unroll
    for (int q = 0; q < 4; ++q) {
        bh[0][q] = *(const h2*)(pattr + (size_t)hp[q] * 128 + c);
        bt[0][q] = *(const h2*)(pattr + (size_t)tp[q] * 128 + c);
    }
#pragma unroll
    for (int b = 0; b < 4; ++b) {
        const int cur = b & 1, nxt = cur ^ 1;
        if (b < 3) {
#pragma unroll
            for (int q = 0; q < 4; ++q) {
                bh[nxt][q] = *(const h2*)(pattr + (size_t)hp[4 * (b + 1) + q] * 128 + c);
                bt[nxt][q] = *(const h2*)(pattr + (size_t)tp[4 * (b + 1) + q] * 128 + c);
            }
        }
        float fh0[4], fh1[4], ft0[4], ft1[4], pph[4], ppt[4];
#pragma unroll
        for (int q = 0; q < 4; ++q) {
            fh0[q] = (float)bh[cur][q][0]; fh1[q] = (float)bh[cur][q][1];
            ft0[q] = (float)bt[cur][q][0]; ft1[q] = (float)bt[cur][q][1];
            pph[q] = rs0 * fh0[q] + rs1 * fh1[q];
            ppt[q] = rs0 * ft0[q] + rs1 * ft1[q];
        }
        float Sh[4], St[4];
#pragma unroll
        for (int q = 0; q < 4; ++q) {
            Sh[q] = wave_red_bcast(pph[q]);
            St[q] = wave_red_bcast(ppt[q]);
        }
#pragma unroll
        for (int q = 0; q < 4; ++q) {
            float wh = exp2f(Sh[q] - ESHIFT2);
            float wt = exp2f(St[q] - ESHIFT2);
            sh += wh; st += wt;
            oh[0] = fmaf(wh, fh0[q], oh[0]); oh[1] = fmaf(wh, fh1[q], oh[1]);
            ot[0] = fmaf(wt, ft0[q], ot[0]); ot[1] = fmaf(wt, ft1[q], ot[1]);
        }
    }
    float invh = 1.f / sh, invt = 1.f / st;
    h2 hv = {(half_t)(oh[0] * invh + ot[0] * invt),
             (half_t)(oh[1] * invh + ot[1] * invt)};
    *(h2*)(s_emb16 + (size_t)w * 128 + c) = hv;
}

// ---------------------------------------------------------------- GAT aggregate (CSR)
// TWO nodes per wave (halves), lane owns 4 cols (8B h4 gathers). als/ald are
// pre-scaled by log2(e) -> exp2 directly. Batch-4 edge unroll with predication;
// adj padded +8; index clamped vs pad garbage. Single pass, shift 20.
__global__ __launch_bounds__(256) void k_aggregate(const int* __restrict__ indptr,
                                                   const int* __restrict__ adj,
                                                   const half_t* __restrict__ hsrc,
                                                   const float* __restrict__ als,
                                                   const float* __restrict__ ald,
                                                   const float* __restrict__ bias,
                                                   float* __restrict__ out,
                                                   half_t* __restrict__ out16, int N) {
    const int tid = threadIdx.x;
    const int wv = (blockIdx.x * 256 + tid) >> 6;
    const int nodeA = wv * 2;
    if (nodeA >= N) return;
    const int lane = tid & 63;
    const int node = min(nodeA + (lane >> 5), N - 1);
    const int sl = lane & 31;
    const int c = sl * 4;

    const int beg = indptr[node];
    const int deg = indptr[node + 1] - beg;
    const float adn = ald[node];  // pre-scaled by log2(e)

    float acc[4] = {0.f, 0.f, 0.f, 0.f};
    float exsum = 0.f;
#pragma unroll 1
    for (int j0 = 0; j0 < deg; j0 += 4) {
        int sr[4];
#pragma unroll
        for (int q = 0; q < 4; ++q) sr[q] = adj[beg + j0 + q];  // padded; same addr per half
#pragma unroll
        for (int q = 0; q < 4; ++q) {
            bool ok = (j0 + q) < deg;
            int s = ((unsigned)sr[q] < (unsigned)N) ? sr[q] : 0;  // pad-garbage guard
            float e = als[s] + adn;
            e = fmaxf(e, NEG_SLOPE * e);
            float ex = ok ? exp2f(e - ESHIFT_AGG) : 0.f;
            h4v v = *(const h4v*)(hsrc + (size_t)s * 128 + c);
            exsum += ex;
#pragma unroll
            for (int j = 0; j < 4; ++j) acc[j] = fmaf(ex, (float)v[j], acc[j]);
        }
    }
    float inv = 1.f / exsum;
    if (out) {
        f4 o;
#pragma unroll
        for (int j = 0; j < 4; ++j) o[j] = fmaf(acc[j], inv, bias[c + j]);
        *(f4*)(out + (size_t)node * 128 + c) = o;
    } else {
        h4v o;
#pragma unroll
        for (int j = 0; j < 4; ++j) o[j] = (half_t)fmaf(acc[j], inv, bias[c + j]);
        *(h4v*)(out16 + (size_t)node * 128 + c) = o;
    }
}

// ---------------------------------------------------------------- launch
extern "C" void kernel_launch(void* const* d_in, const int* in_sizes, int n_in,
                              void* d_out, int out_size, void* d_ws, size_t ws_size,
                              hipStream_t stream) {
    const int*   hA   = (const int*)d_in[0];
    const int*   tA   = (const int*)d_in[1];
    const int*   rix  = (const int*)d_in[2];
    const int*   ei   = (const int*)d_in[3];
    const float* attr_table = (const float*)d_in[4];
    const float* rel_table  = (const float*)d_in[5];
    const float* femb_w = (const float*)d_in[6];
    const float* femb_b = (const float*)d_in[7];
    const float* g1w  = (const float*)d_in[8];
    const float* g1as = (const float*)d_in[9];
    const float* g1ad = (const float*)d_in[10];
    const float* g1b  = (const float*)d_in[11];
    const float* g2w  = (const float*)d_in[12];
    const float* g2as = (const float*)d_in[13];
    const float* g2ad = (const float*)d_in[14];
    const float* g2b  = (const float*)d_in[15];

    const int N  = in_sizes[2];
    const int E  = in_sizes[3] / 2;
    const int NA = in_sizes[4] / DE;
    const int NR = in_sizes[5] / DE;
    const int EN = E + N;

    char* p = (char*)d_ws;
    auto alloc = [&](size_t bytes) -> char* {
        char* q = p;
        p += (bytes + 255) & ~(size_t)255;
        return q;
    };
    half_t* proj16 = (half_t*)alloc((size_t)NA * DE * 2);
    half_t* s16    = (half_t*)alloc((size_t)N * DE * 2);
    half_t* h16    = (half_t*)alloc((size_t)N * DE * 2);
    half_t* x116   = (half_t*)alloc((size_t)N * DE * 2);
    float* prel    = (float*)alloc((size_t)NR * DE * 4);
    float* rel2    = (float*)alloc((size_t)NR * DE * 4);
    float* alps    = (float*)alloc((size_t)N * 4);
    float* alpd    = (float*)alloc((size_t)N * 4);
    int*   indptr  = (int*)alloc((size_t)(N + 1) * 4);
    int*   cnt     = (int*)alloc((size_t)N * 4);
    int*   cur     = (int*)alloc((size_t)N * 4);
    int*   adj     = (int*)alloc((size_t)(EN + 8) * 4);  // +8 pad for batch over-read

    dim3 b256(256);

    // CSR build (same edge set both layers -> build once)
    hipMemsetAsync(cnt, 0, (size_t)N * 4, stream);
    hipMemsetAsync(cur, 0, (size_t)N * 4, stream);
    k_count<<<dim3((EN + 255) / 256), b256, 0, stream>>>(ei, E, N, cnt);
    k_scan<<<dim3(1), dim3(1024), 0, stream>>>(cnt, N, indptr);
    k_fill<<<dim3((EN + 255) / 256), b256, 0, stream>>>(ei, E, N, indptr, cur, adj);

    // rel-table projections (500 rows, f32 path)
    k_gemm<2><<<dim3((NR + 31) / 32), b256, 0, stream>>>(rel_table, NR, femb_w, DE, 0,
                                                         femb_b, prel);
    k_gemm<2><<<dim3((NR + 31) / 32), b256, 0, stream>>>(rel_table, NR, g1w, 2 * DE, DE,
                                                         nullptr, rel2);

    // attr table projection straight to fp16 (MFMA, f32 A-path)
    k_gemm_mfma<float><<<dim3((NA + 63) / 64), b256, 0, stream>>>(attr_table, NA,
        femb_w, DE, 0, femb_b, nullptr, nullptr, nullptr, nullptr, nullptr, nullptr, proj16);

    // entity attention (h + t fused), ONE node per wave (r8 structure)
    k_entity<<<dim3((N + 3) / 4), b256, 0, stream>>>(hA, tA, rix, proj16, prel, s16, N);

    // GAT layer 1: h = s_emb @ Wl.T + rel2[r_idx]; alpha fused (pre-scaled); h fp16
    k_gemm_mfma<half_t><<<dim3((N + 63) / 64), b256, 0, stream>>>(s16, N,
        g1w, 2 * DE, 0, nullptr, rel2, rix, g1as, g1ad, alps, alpd, h16);
    k_aggregate<<<dim3((N + 7) / 8), b256, 0, stream>>>(indptr, adj, h16, alps, alpd, g1b,
                                                        nullptr, x116, N);

    // GAT layer 2
    k_gemm_mfma<half_t><<<dim3((N + 63) / 64), b256, 0, stream>>>(x116, N,
        g2w, DE, 0, nullptr, nullptr, nullptr, g2as, g2ad, alps, alpd, h16);
    k_aggregate<<<dim3((N + 7) / 8), b256, 0, stream>>>(indptr, adj, h16, alps, alpd, g2b,
                                                        (float*)d_out, nullptr, N);
}

// Round 11
// 324.950 us; speedup vs baseline: 1.2404x; 1.0135x over previous
//
#include <hip/hip_runtime.h>
#include <math.h>

#define DE 128
#define NEG_SLOPE 0.2f
#define LOG2E 1.4426950408889634f
#define ESHIFT2 57.707801635559926f      /* 40 * log2(e)  (entity) */
#define ESHIFT_AGG 28.853900817779268f   /* 20 * log2(e)  (aggregate) */

typedef __attribute__((ext_vector_type(4))) float f4;
typedef __attribute__((ext_vector_type(2))) float f2;
typedef _Float16 half_t;
typedef __attribute__((ext_vector_type(2))) _Float16 h2;
typedef __attribute__((ext_vector_type(4))) _Float16 h4v;
typedef __attribute__((ext_vector_type(8))) _Float16 h8;

// Wave64 sum-reduce on the VALU only (DPP adds + readlane), zero LDS-pipe ops.
__device__ __forceinline__ float wave_red_bcast(float x) {
    union fi { float f; int i; };
    fi a; a.f = x;
    fi t;
    t.i = __builtin_amdgcn_update_dpp(0, a.i, 0x111, 0xf, 0xf, true); a.f += t.f; // row_shr:1
    t.i = __builtin_amdgcn_update_dpp(0, a.i, 0x112, 0xf, 0xf, true); a.f += t.f; // row_shr:2
    t.i = __builtin_amdgcn_update_dpp(0, a.i, 0x114, 0xf, 0xf, true); a.f += t.f; // row_shr:4
    t.i = __builtin_amdgcn_update_dpp(0, a.i, 0x118, 0xf, 0xf, true); a.f += t.f; // row_shr:8
    t.i = __builtin_amdgcn_update_dpp(0, a.i, 0x142, 0xa, 0xf, true); a.f += t.f; // row_bcast:15
    t.i = __builtin_amdgcn_update_dpp(0, a.i, 0x143, 0xc, 0xf, true); a.f += t.f; // row_bcast:31
    fi r; r.i = __builtin_amdgcn_readlane(a.i, 63);
    return r.f;
}

// All-reduce within each 16-lane DPP row (lane gets its row's sum). 4 DPP adds.
__device__ __forceinline__ float row16_allred(float x) {
    union fi { float f; int i; };
    fi a; a.f = x;
    fi t;
    t.i = __builtin_amdgcn_update_dpp(0, a.i, 0x121, 0xf, 0xf, true); a.f += t.f; // row_ror:1
    t.i = __builtin_amdgcn_update_dpp(0, a.i, 0x122, 0xf, 0xf, true); a.f += t.f; // row_ror:2
    t.i = __builtin_amdgcn_update_dpp(0, a.i, 0x124, 0xf, 0xf, true); a.f += t.f; // row_ror:4
    t.i = __builtin_amdgcn_update_dpp(0, a.i, 0x128, 0xf, 0xf, true); a.f += t.f; // row_ror:8
    return a.f;
}

// ---------------------------------------------------------------- CSR build
__global__ __launch_bounds__(256) void k_count(const int* __restrict__ ei, int E, int N,
                                               int* __restrict__ cnt) {
    int e = blockIdx.x * blockDim.x + threadIdx.x;
    int total = E + N;
    if (e >= total) return;
    int dst = (e < E) ? ei[E + e] : (e - E);
    atomicAdd(&cnt[dst], 1);
}

__global__ __launch_bounds__(1024) void k_scan(const int* __restrict__ cnt, int n,
                                               int* __restrict__ indptr) {
    __shared__ int wsum[16];
    __shared__ int btot;
    int tid = threadIdx.x, lane = tid & 63, w = tid >> 6;
    int carry = 0;
    for (int base = 0; base < n; base += 1024) {
        int i = base + tid;
        int v = (i < n) ? cnt[i] : 0;
        int x = v;
#pragma unroll
        for (int off = 1; off < 64; off <<= 1) {
            int t = __shfl_up(x, off, 64);
            if (lane >= off) x += t;
        }
        if (lane == 63) wsum[w] = x;
        __syncthreads();
        if (w == 0) {
            int s = (lane < 16) ? wsum[lane] : 0;
#pragma unroll
            for (int off = 1; off < 16; off <<= 1) {
                int t = __shfl_up(s, off, 64);
                if (lane >= off) s += t;
            }
            if (lane < 16) wsum[lane] = s;
            if (lane == 15) btot = s;
        }
        __syncthreads();
        int wexcl = (w == 0) ? 0 : wsum[w - 1];
        if (i < n) indptr[i] = carry + wexcl + (x - v);
        carry += btot;
        __syncthreads();
    }
    if (tid == 0) indptr[n] = carry;
}

__global__ __launch_bounds__(256) void k_fill(const int* __restrict__ ei, int E, int N,
                                              const int* __restrict__ indptr,
                                              int* __restrict__ cur, int* __restrict__ adj) {
    int e = blockIdx.x * blockDim.x + threadIdx.x;
    int total = E + N;
    if (e >= total) return;
    int src, dst;
    if (e < E) { src = ei[e]; dst = ei[E + e]; }
    else       { src = dst = e - E; }
    int pos = indptr[dst] + atomicAdd(&cur[dst], 1);
    adj[pos] = src;
}

// ---------------------------------------------------------------- small f32 GEMM (500-row rel tables)
template <int RPT>
__global__ __launch_bounds__(256) void k_gemm(const float* __restrict__ in, int rows,
                                              const float* __restrict__ W, int ldw, int wcol0,
                                              const float* __restrict__ bias,
                                              float* __restrict__ out) {
    __shared__ float Wt[128 * 128];
    const int tid = threadIdx.x;
#pragma unroll
    for (int it = 0; it < 16; ++it) {
        int idx = it * 256 + tid;
        int c = idx & 127, k4 = idx >> 7;
        f4 wv = *(const f4*)(W + (size_t)c * ldw + wcol0 + k4 * 4);
#pragma unroll
        for (int j = 0; j < 4; ++j) Wt[(4 * k4 + j) * 128 + c] = wv[j];
    }
    __syncthreads();

    const int cgrp = tid & 15, rgrp = tid >> 4;
    const int c0 = cgrp * 4;
    const int row0 = blockIdx.x * (16 * RPT) + rgrp * RPT;

    const float* rowp[RPT];
#pragma unroll
    for (int i = 0; i < RPT; ++i)
        rowp[i] = in + (size_t)min(row0 + i, rows - 1) * 128;

    float acc[RPT][8];
#pragma unroll
    for (int i = 0; i < RPT; ++i)
#pragma unroll
        for (int j = 0; j < 8; ++j) acc[i][j] = 0.f;

#pragma unroll 1
    for (int k = 0; k < 128; k += 4) {
        f4 a[RPT];
#pragma unroll
        for (int i = 0; i < RPT; ++i) a[i] = *(const f4*)(rowp[i] + k);
#pragma unroll
        for (int kk = 0; kk < 4; ++kk) {
            f4 b0 = *(const f4*)&Wt[(k + kk) * 128 + c0];
            f4 b1 = *(const f4*)&Wt[(k + kk) * 128 + c0 + 64];
#pragma unroll
            for (int i = 0; i < RPT; ++i) {
                float av = a[i][kk];
#pragma unroll
                for (int j = 0; j < 4; ++j) {
                    acc[i][j]     = fmaf(av, b0[j], acc[i][j]);
                    acc[i][j + 4] = fmaf(av, b1[j], acc[i][j + 4]);
                }
            }
        }
    }
    f4 bi0 = {0.f,0.f,0.f,0.f}, bi1 = {0.f,0.f,0.f,0.f};
    if (bias) { bi0 = *(const f4*)(bias + c0); bi1 = *(const f4*)(bias + c0 + 64); }
#pragma unroll
    for (int i = 0; i < RPT; ++i) {
        int r = row0 + i;
        if (r < rows) {
            f4 v0, v1;
#pragma unroll
            for (int j = 0; j < 4; ++j) { v0[j] = acc[i][j] + bi0[j]; v1[j] = acc[i][j+4] + bi1[j]; }
            *(f4*)(out + (size_t)r * 128 + c0) = v0;
            *(f4*)(out + (size_t)r * 128 + c0 + 64) = v1;
        }
    }
}

// ---------------------------------------------------------------- MFMA GEMM (fp16 in, f32 acc)
// NOTE: als/ald are stored PRE-SCALED by log2(e) (consumed by k_aggregate's exp2).
template <typename AT>
__global__ __launch_bounds__(256) void k_gemm_mfma(const AT* __restrict__ A, int rows,
                                                   const float* __restrict__ W, int ldw, int wcol0,
                                                   const float* __restrict__ bias,
                                                   const float* __restrict__ addtab,
                                                   const int* __restrict__ addidx,
                                                   const float* __restrict__ avs,
                                                   const float* __restrict__ avd,
                                                   float* __restrict__ als,
                                                   float* __restrict__ ald,
                                                   half_t* __restrict__ out16) {
    __shared__ alignas(16) char ldsbuf[128 * 136 * 2];  // Wl (fp16) then aliased as Dl (f32)
    half_t* Wl = (half_t*)ldsbuf;
    float*  Dl = (float*)ldsbuf;

    const int tid = threadIdx.x;
    const int row0 = blockIdx.x * 64;

    for (int i = tid * 4; i < 128 * 128; i += 1024) {
        int c = i >> 7, k = i & 127;
        f4 wv = *(const f4*)(W + (size_t)c * ldw + wcol0 + k);
        h4v hv = {(half_t)wv[0], (half_t)wv[1], (half_t)wv[2], (half_t)wv[3]};
        *(h4v*)(Wl + c * 136 + k) = hv;
    }
    __syncthreads();

    const int wv_id = tid >> 6, l = tid & 63, lr = l & 15, lk = l >> 4;
    const int r_a = min(row0 + wv_id * 16 + lr, rows - 1);

    h8 af[4];
#pragma unroll
    for (int ks = 0; ks < 4; ++ks) {
        if constexpr (sizeof(AT) == 4) {
            f4 a0 = *(const f4*)(A + (size_t)r_a * 128 + ks * 32 + lk * 8);
            f4 a1 = *(const f4*)(A + (size_t)r_a * 128 + ks * 32 + lk * 8 + 4);
            h8 v = {(half_t)a0[0], (half_t)a0[1], (half_t)a0[2], (half_t)a0[3],
                    (half_t)a1[0], (half_t)a1[1], (half_t)a1[2], (half_t)a1[3]};
            af[ks] = v;
        } else {
            af[ks] = *(const h8*)(A + (size_t)r_a * 128 + ks * 32 + lk * 8);
        }
    }

    f4 acc[8];
#pragma unroll
    for (int t = 0; t < 8; ++t) acc[t] = (f4){0.f, 0.f, 0.f, 0.f};
#pragma unroll
    for (int ks = 0; ks < 4; ++ks) {
#pragma unroll
        for (int t = 0; t < 8; ++t) {
            h8 bf = *(const h8*)(Wl + (t * 16 + lr) * 136 + ks * 32 + lk * 8);
            acc[t] = __builtin_amdgcn_mfma_f32_16x16x32_f16(af[ks], bf, acc[t], 0, 0, 0);
        }
    }
    __syncthreads();

#pragma unroll
    for (int t = 0; t < 8; ++t)
#pragma unroll
        for (int q = 0; q < 4; ++q)
            Dl[(wv_id * 16 + lk * 4 + q) * 132 + t * 16 + lr] = acc[t][q];
    __syncthreads();

    const int cl = (tid & 15) * 8;
    f4 bi0 = {0.f,0.f,0.f,0.f}, bi1 = bi0;
    if (bias) { bi0 = *(const f4*)(bias + cl); bi1 = *(const f4*)(bias + cl + 4); }
    f4 as0 = {0.f,0.f,0.f,0.f}, as1 = as0, ad0 = as0, ad1 = as0;
    if (als) {
        as0 = *(const f4*)(avs + cl) * LOG2E; as1 = *(const f4*)(avs + cl + 4) * LOG2E;
        ad0 = *(const f4*)(avd + cl) * LOG2E; ad1 = *(const f4*)(avd + cl + 4) * LOG2E;
    }
#pragma unroll
    for (int pass = 0; pass < 4; ++pass) {
        int lrow = pass * 16 + (tid >> 4);
        int r = row0 + lrow;
        bool ok = r < rows;
        f4 v0 = *(const f4*)(Dl + lrow * 132 + cl);
        f4 v1 = *(const f4*)(Dl + lrow * 132 + cl + 4);
        v0 += bi0; v1 += bi1;
        if (addtab) {
            int ri = addidx[min(r, rows - 1)];
            v0 += *(const f4*)(addtab + (size_t)ri * 128 + cl);
            v1 += *(const f4*)(addtab + (size_t)ri * 128 + cl + 4);
        }
        if (als) {
            float ps = 0.f, pd = 0.f;
#pragma unroll
            for (int j = 0; j < 4; ++j) {
                ps += v0[j] * as0[j] + v1[j] * as1[j];
                pd += v0[j] * ad0[j] + v1[j] * ad1[j];
            }
            ps = row16_allred(ps);
            pd = row16_allred(pd);
            if ((tid & 15) == 0 && ok) { als[r] = ps; ald[r] = pd; }
        }
        if (ok) {
            h8 o = {(half_t)v0[0], (half_t)v0[1], (half_t)v0[2], (half_t)v0[3],
                    (half_t)v1[0], (half_t)v1[1], (half_t)v1[2], (half_t)v1[3]};
            *(h8*)(out16 + (size_t)r * 128 + cl) = o;
        }
    }
}

// ---------------------------------------------------------------- entity attention (r8 skeleton, VALU-thinned)
// One wave per node; lane owns cols {2l,2l+1} (4B fp16 gathers, whole wave =
// one 256B row per instruction — the measured-optimal access shape; FROZEN).
// VALU diet vs r8: score partial = single v_dot2_f32_f16 (fp16 rp, fp16 ap,
// f32 acc) with the softmax shift folded into lane 0's C operand; weighted
// accumulation via v_fma_mix (fp16 source, f32 acc) -> zero explicit cvts.
// 64-lane DPP reduce unchanged.
__global__ __launch_bounds__(256) void k_entity(const int* __restrict__ hA,
                                                const int* __restrict__ tA,
                                                const int* __restrict__ ridx,
                                                const half_t* __restrict__ pattr,
                                                const float* __restrict__ prel,
                                                half_t* __restrict__ s_emb16, int N) {
    int w = (blockIdx.x * blockDim.x + threadIdx.x) >> 6;
    if (w >= N) return;
    w = __builtin_amdgcn_readfirstlane(w);
    const int lane = threadIdx.x & 63;
    const int c = lane * 2;
    const int ri = ridx[w];
    const f2 rp = *(const f2*)(prel + (size_t)ri * 128 + c);
    // rp pre-scaled by log2(e), quantized to fp16 for v_dot2 (adds ~5e-4 rel noise)
    const h2 rph = {(half_t)(rp[0] * LOG2E), (half_t)(rp[1] * LOG2E)};
    const float init = (lane == 0) ? -ESHIFT2 : 0.f;  // shift enters each dot ONCE
    const int* __restrict__ hp = hA + (size_t)w * 16;
    const int* __restrict__ tp = tA + (size_t)w * 16;

    f2 oh = {0.f, 0.f}, ot = {0.f, 0.f};
    float sh = 0.f, st = 0.f;

    h2 bh[2][4], bt[2][4];
#pragma unroll
    for (int q = 0; q < 4; ++q) {
        bh[0][q] = *(const h2*)(pattr + (size_t)hp[q] * 128 + c);
        bt[0][q] = *(const h2*)(pattr + (size_t)tp[q] * 128 + c);
    }
#pragma unroll
    for (int b = 0; b < 4; ++b) {
        const int cur = b & 1, nxt = cur ^ 1;
        if (b < 3) {
#pragma unroll
            for (int q = 0; q < 4; ++q) {
                bh[nxt][q] = *(const h2*)(pattr + (size_t)hp[4 * (b + 1) + q] * 128 + c);
                bt[nxt][q] = *(const h2*)(pattr + (size_t)tp[4 * (b + 1) + q] * 128 + c);
            }
        }
        float pph[4], ppt[4];
#pragma unroll
        for (int q = 0; q < 4; ++q) {
            pph[q] = __builtin_amdgcn_fdot2(rph, bh[cur][q], init, false);  // v_dot2_f32_f16
            ppt[q] = __builtin_amdgcn_fdot2(rph, bt[cur][q], init, false);
        }
        float Sh[4], St[4];  // 8 independent DPP chains -> latency overlapped
#pragma unroll
        for (int q = 0; q < 4; ++q) {
            Sh[q] = wave_red_bcast(pph[q]);
            St[q] = wave_red_bcast(ppt[q]);
        }
#pragma unroll
        for (int q = 0; q < 4; ++q) {
            float wh = exp2f(Sh[q]);
            float wt = exp2f(St[q]);
            sh += wh; st += wt;
            // v_fma_mix: fp16 source, f32 mul/acc — no explicit cvt
            oh[0] = fmaf(wh, (float)bh[cur][q][0], oh[0]);
            oh[1] = fmaf(wh, (float)bh[cur][q][1], oh[1]);
            ot[0] = fmaf(wt, (float)bt[cur][q][0], ot[0]);
            ot[1] = fmaf(wt, (float)bt[cur][q][1], ot[1]);
        }
    }
    float invh = 1.f / sh, invt = 1.f / st;
    h2 hv = {(half_t)(oh[0] * invh + ot[0] * invt),
             (half_t)(oh[1] * invh + ot[1] * invt)};
    *(h2*)(s_emb16 + (size_t)w * 128 + c) = hv;
}

// ---------------------------------------------------------------- GAT aggregate (CSR)
// TWO nodes per wave (halves), lane owns 4 cols (8B h4 gathers). als/ald are
// pre-scaled by log2(e) -> exp2 directly. Batch-4 edge unroll with predication;
// adj padded +8; index clamped vs pad garbage. Single pass, shift 20.
__global__ __launch_bounds__(256) void k_aggregate(const int* __restrict__ indptr,
                                                   const int* __restrict__ adj,
                                                   const half_t* __restrict__ hsrc,
                                                   const float* __restrict__ als,
                                                   const float* __restrict__ ald,
                                                   const float* __restrict__ bias,
                                                   float* __restrict__ out,
                                                   half_t* __restrict__ out16, int N) {
    const int tid = threadIdx.x;
    const int wv = (blockIdx.x * 256 + tid) >> 6;
    const int nodeA = wv * 2;
    if (nodeA >= N) return;
    const int lane = tid & 63;
    const int node = min(nodeA + (lane >> 5), N - 1);
    const int sl = lane & 31;
    const int c = sl * 4;

    const int beg = indptr[node];
    const int deg = indptr[node + 1] - beg;
    const float adn = ald[node];  // pre-scaled by log2(e)

    float acc[4] = {0.f, 0.f, 0.f, 0.f};
    float exsum = 0.f;
#pragma unroll 1
    for (int j0 = 0; j0 < deg; j0 += 4) {
        int sr[4];
#pragma unroll
        for (int q = 0; q < 4; ++q) sr[q] = adj[beg + j0 + q];  // padded; same addr per half
#pragma unroll
        for (int q = 0; q < 4; ++q) {
            bool ok = (j0 + q) < deg;
            int s = ((unsigned)sr[q] < (unsigned)N) ? sr[q] : 0;  // pad-garbage guard
            float e = als[s] + adn;
            e = fmaxf(e, NEG_SLOPE * e);
            float ex = ok ? exp2f(e - ESHIFT_AGG) : 0.f;
            h4v v = *(const h4v*)(hsrc + (size_t)s * 128 + c);
            exsum += ex;
#pragma unroll
            for (int j = 0; j < 4; ++j) acc[j] = fmaf(ex, (float)v[j], acc[j]);
        }
    }
    float inv = 1.f / exsum;
    if (out) {
        f4 o;
#pragma unroll
        for (int j = 0; j < 4; ++j) o[j] = fmaf(acc[j], inv, bias[c + j]);
        *(f4*)(out + (size_t)node * 128 + c) = o;
    } else {
        h4v o;
#pragma unroll
        for (int j = 0; j < 4; ++j) o[j] = (half_t)fmaf(acc[j], inv, bias[c + j]);
        *(h4v*)(out16 + (size_t)node * 128 + c) = o;
    }
}

// ---------------------------------------------------------------- launch
extern "C" void kernel_launch(void* const* d_in, const int* in_sizes, int n_in,
                              void* d_out, int out_size, void* d_ws, size_t ws_size,
                              hipStream_t stream) {
    const int*   hA   = (const int*)d_in[0];
    const int*   tA   = (const int*)d_in[1];
    const int*   rix  = (const int*)d_in[2];
    const int*   ei   = (const int*)d_in[3];
    const float* attr_table = (const float*)d_in[4];
    const float* rel_table  = (const float*)d_in[5];
    const float* femb_w = (const float*)d_in[6];
    const float* femb_b = (const float*)d_in[7];
    const float* g1w  = (const float*)d_in[8];
    const float* g1as = (const float*)d_in[9];
    const float* g1ad = (const float*)d_in[10];
    const float* g1b  = (const float*)d_in[11];
    const float* g2w  = (const float*)d_in[12];
    const float* g2as = (const float*)d_in[13];
    const float* g2ad = (const float*)d_in[14];
    const float* g2b  = (const float*)d_in[15];

    const int N  = in_sizes[2];
    const int E  = in_sizes[3] / 2;
    const int NA = in_sizes[4] / DE;
    const int NR = in_sizes[5] / DE;
    const int EN = E + N;

    char* p = (char*)d_ws;
    auto alloc = [&](size_t bytes) -> char* {
        char* q = p;
        p += (bytes + 255) & ~(size_t)255;
        return q;
    };
    half_t* proj16 = (half_t*)alloc((size_t)NA * DE * 2);
    half_t* s16    = (half_t*)alloc((size_t)N * DE * 2);
    half_t* h16    = (half_t*)alloc((size_t)N * DE * 2);
    half_t* x116   = (half_t*)alloc((size_t)N * DE * 2);
    float* prel    = (float*)alloc((size_t)NR * DE * 4);
    float* rel2    = (float*)alloc((size_t)NR * DE * 4);
    float* alps    = (float*)alloc((size_t)N * 4);
    float* alpd    = (float*)alloc((size_t)N * 4);
    int*   indptr  = (int*)alloc((size_t)(N + 1) * 4);
    int*   cnt     = (int*)alloc((size_t)N * 4);
    int*   cur     = (int*)alloc((size_t)N * 4);
    int*   adj     = (int*)alloc((size_t)(EN + 8) * 4);  // +8 pad for batch over-read

    dim3 b256(256);

    // CSR build (same edge set both layers -> build once)
    hipMemsetAsync(cnt, 0, (size_t)N * 4, stream);
    hipMemsetAsync(cur, 0, (size_t)N * 4, stream);
    k_count<<<dim3((EN + 255) / 256), b256, 0, stream>>>(ei, E, N, cnt);
    k_scan<<<dim3(1), dim3(1024), 0, stream>>>(cnt, N, indptr);
    k_fill<<<dim3((EN + 255) / 256), b256, 0, stream>>>(ei, E, N, indptr, cur, adj);

    // rel-table projections (500 rows, f32 path)
    k_gemm<2><<<dim3((NR + 31) / 32), b256, 0, stream>>>(rel_table, NR, femb_w, DE, 0,
                                                         femb_b, prel);
    k_gemm<2><<<dim3((NR + 31) / 32), b256, 0, stream>>>(rel_table, NR, g1w, 2 * DE, DE,
                                                         nullptr, rel2);

    // attr table projection straight to fp16 (MFMA, f32 A-path)
    k_gemm_mfma<float><<<dim3((NA + 63) / 64), b256, 0, stream>>>(attr_table, NA,
        femb_w, DE, 0, femb_b, nullptr, nullptr, nullptr, nullptr, nullptr, nullptr, proj16);

    // entity attention (h + t fused), ONE node per wave (r8 structure)
    k_entity<<<dim3((N + 3) / 4), b256, 0, stream>>>(hA, tA, rix, proj16, prel, s16, N);

    // GAT layer 1: h = s_emb @ Wl.T + rel2[r_idx]; alpha fused (pre-scaled); h fp16
    k_gemm_mfma<half_t><<<dim3((N + 63) / 64), b256, 0, stream>>>(s16, N,
        g1w, 2 * DE, 0, nullptr, rel2, rix, g1as, g1ad, alps, alpd, h16);
    k_aggregate<<<dim3((N + 7) / 8), b256, 0, stream>>>(indptr, adj, h16, alps, alpd, g1b,
                                                        nullptr, x116, N);

    // GAT layer 2
    k_gemm_mfma<half_t><<<dim3((N + 63) / 64), b256, 0, stream>>>(x116, N,
        g2w, DE, 0, nullptr, nullptr, nullptr, g2as, g2ad, alps, alpd, h16);
    k_aggregate<<<dim3((N + 7) / 8), b256, 0, stream>>>(indptr, adj, h16, alps, alpd, g2b,
                                                        (float*)d_out, nullptr, N);
}

// Round 12
// 322.879 us; speedup vs baseline: 1.2484x; 1.0064x over previous
//
#include <hip/hip_runtime.h>
#include <math.h>

#define DE 128
#define NEG_SLOPE 0.2f
#define LOG2E 1.4426950408889634f
#define ESHIFT2 57.707801635559926f      /* 40 * log2(e)  (entity) */
#define ESHIFT_AGG 28.853900817779268f   /* 20 * log2(e)  (aggregate) */

typedef __attribute__((ext_vector_type(4))) float f4;
typedef __attribute__((ext_vector_type(2))) float f2;
typedef _Float16 half_t;
typedef __attribute__((ext_vector_type(2))) _Float16 h2;
typedef __attribute__((ext_vector_type(4))) _Float16 h4v;
typedef __attribute__((ext_vector_type(8))) _Float16 h8;

// Wave64 sum-reduce on the VALU only (DPP adds + readlane), zero LDS-pipe ops.
__device__ __forceinline__ float wave_red_bcast(float x) {
    union fi { float f; int i; };
    fi a; a.f = x;
    fi t;
    t.i = __builtin_amdgcn_update_dpp(0, a.i, 0x111, 0xf, 0xf, true); a.f += t.f; // row_shr:1
    t.i = __builtin_amdgcn_update_dpp(0, a.i, 0x112, 0xf, 0xf, true); a.f += t.f; // row_shr:2
    t.i = __builtin_amdgcn_update_dpp(0, a.i, 0x114, 0xf, 0xf, true); a.f += t.f; // row_shr:4
    t.i = __builtin_amdgcn_update_dpp(0, a.i, 0x118, 0xf, 0xf, true); a.f += t.f; // row_shr:8
    t.i = __builtin_amdgcn_update_dpp(0, a.i, 0x142, 0xa, 0xf, true); a.f += t.f; // row_bcast:15
    t.i = __builtin_amdgcn_update_dpp(0, a.i, 0x143, 0xc, 0xf, true); a.f += t.f; // row_bcast:31
    fi r; r.i = __builtin_amdgcn_readlane(a.i, 63);
    return r.f;
}

// All-reduce within each 16-lane DPP row (lane gets its row's sum). 4 DPP adds.
__device__ __forceinline__ float row16_allred(float x) {
    union fi { float f; int i; };
    fi a; a.f = x;
    fi t;
    t.i = __builtin_amdgcn_update_dpp(0, a.i, 0x121, 0xf, 0xf, true); a.f += t.f; // row_ror:1
    t.i = __builtin_amdgcn_update_dpp(0, a.i, 0x122, 0xf, 0xf, true); a.f += t.f; // row_ror:2
    t.i = __builtin_amdgcn_update_dpp(0, a.i, 0x124, 0xf, 0xf, true); a.f += t.f; // row_ror:4
    t.i = __builtin_amdgcn_update_dpp(0, a.i, 0x128, 0xf, 0xf, true); a.f += t.f; // row_ror:8
    return a.f;
}

// ---------------------------------------------------------------- CSR build
__global__ __launch_bounds__(256) void k_count(const int* __restrict__ ei, int E, int N,
                                               int* __restrict__ cnt) {
    int e = blockIdx.x * blockDim.x + threadIdx.x;
    int total = E + N;
    if (e >= total) return;
    int dst = (e < E) ? ei[E + e] : (e - E);
    atomicAdd(&cnt[dst], 1);
}

__global__ __launch_bounds__(1024) void k_scan(const int* __restrict__ cnt, int n,
                                               int* __restrict__ indptr) {
    __shared__ int wsum[16];
    __shared__ int btot;
    int tid = threadIdx.x, lane = tid & 63, w = tid >> 6;
    int carry = 0;
    for (int base = 0; base < n; base += 1024) {
        int i = base + tid;
        int v = (i < n) ? cnt[i] : 0;
        int x = v;
#pragma unroll
        for (int off = 1; off < 64; off <<= 1) {
            int t = __shfl_up(x, off, 64);
            if (lane >= off) x += t;
        }
        if (lane == 63) wsum[w] = x;
        __syncthreads();
        if (w == 0) {
            int s = (lane < 16) ? wsum[lane] : 0;
#pragma unroll
            for (int off = 1; off < 16; off <<= 1) {
                int t = __shfl_up(s, off, 64);
                if (lane >= off) s += t;
            }
            if (lane < 16) wsum[lane] = s;
            if (lane == 15) btot = s;
        }
        __syncthreads();
        int wexcl = (w == 0) ? 0 : wsum[w - 1];
        if (i < n) indptr[i] = carry + wexcl + (x - v);
        carry += btot;
        __syncthreads();
    }
    if (tid == 0) indptr[n] = carry;
}

__global__ __launch_bounds__(256) void k_fill(const int* __restrict__ ei, int E, int N,
                                              const int* __restrict__ indptr,
                                              int* __restrict__ cur, int* __restrict__ adj) {
    int e = blockIdx.x * blockDim.x + threadIdx.x;
    int total = E + N;
    if (e >= total) return;
    int src, dst;
    if (e < E) { src = ei[e]; dst = ei[E + e]; }
    else       { src = dst = e - E; }
    int pos = indptr[dst] + atomicAdd(&cur[dst], 1);
    adj[pos] = src;
}

// ---------------------------------------------------------------- small f32 GEMM (500-row rel tables)
template <int RPT>
__global__ __launch_bounds__(256) void k_gemm(const float* __restrict__ in, int rows,
                                              const float* __restrict__ W, int ldw, int wcol0,
                                              const float* __restrict__ bias,
                                              float* __restrict__ out) {
    __shared__ float Wt[128 * 128];
    const int tid = threadIdx.x;
#pragma unroll
    for (int it = 0; it < 16; ++it) {
        int idx = it * 256 + tid;
        int c = idx & 127, k4 = idx >> 7;
        f4 wv = *(const f4*)(W + (size_t)c * ldw + wcol0 + k4 * 4);
#pragma unroll
        for (int j = 0; j < 4; ++j) Wt[(4 * k4 + j) * 128 + c] = wv[j];
    }
    __syncthreads();

    const int cgrp = tid & 15, rgrp = tid >> 4;
    const int c0 = cgrp * 4;
    const int row0 = blockIdx.x * (16 * RPT) + rgrp * RPT;

    const float* rowp[RPT];
#pragma unroll
    for (int i = 0; i < RPT; ++i)
        rowp[i] = in + (size_t)min(row0 + i, rows - 1) * 128;

    float acc[RPT][8];
#pragma unroll
    for (int i = 0; i < RPT; ++i)
#pragma unroll
        for (int j = 0; j < 8; ++j) acc[i][j] = 0.f;

#pragma unroll 1
    for (int k = 0; k < 128; k += 4) {
        f4 a[RPT];
#pragma unroll
        for (int i = 0; i < RPT; ++i) a[i] = *(const f4*)(rowp[i] + k);
#pragma unroll
        for (int kk = 0; kk < 4; ++kk) {
            f4 b0 = *(const f4*)&Wt[(k + kk) * 128 + c0];
            f4 b1 = *(const f4*)&Wt[(k + kk) * 128 + c0 + 64];
#pragma unroll
            for (int i = 0; i < RPT; ++i) {
                float av = a[i][kk];
#pragma unroll
                for (int j = 0; j < 4; ++j) {
                    acc[i][j]     = fmaf(av, b0[j], acc[i][j]);
                    acc[i][j + 4] = fmaf(av, b1[j], acc[i][j + 4]);
                }
            }
        }
    }
    f4 bi0 = {0.f,0.f,0.f,0.f}, bi1 = {0.f,0.f,0.f,0.f};
    if (bias) { bi0 = *(const f4*)(bias + c0); bi1 = *(const f4*)(bias + c0 + 64); }
#pragma unroll
    for (int i = 0; i < RPT; ++i) {
        int r = row0 + i;
        if (r < rows) {
            f4 v0, v1;
#pragma unroll
            for (int j = 0; j < 4; ++j) { v0[j] = acc[i][j] + bi0[j]; v1[j] = acc[i][j+4] + bi1[j]; }
            *(f4*)(out + (size_t)r * 128 + c0) = v0;
            *(f4*)(out + (size_t)r * 128 + c0 + 64) = v1;
        }
    }
}

// ---------------------------------------------------------------- MFMA GEMM (fp16 in, f32 acc)
// NOTE: als/ald are stored PRE-SCALED by log2(e) (consumed by k_aggregate's exp2).
template <typename AT>
__global__ __launch_bounds__(256) void k_gemm_mfma(const AT* __restrict__ A, int rows,
                                                   const float* __restrict__ W, int ldw, int wcol0,
                                                   const float* __restrict__ bias,
                                                   const float* __restrict__ addtab,
                                                   const int* __restrict__ addidx,
                                                   const float* __restrict__ avs,
                                                   const float* __restrict__ avd,
                                                   float* __restrict__ als,
                                                   float* __restrict__ ald,
                                                   half_t* __restrict__ out16) {
    __shared__ alignas(16) char ldsbuf[128 * 136 * 2];  // Wl (fp16) then aliased as Dl (f32)
    half_t* Wl = (half_t*)ldsbuf;
    float*  Dl = (float*)ldsbuf;

    const int tid = threadIdx.x;
    const int row0 = blockIdx.x * 64;

    for (int i = tid * 4; i < 128 * 128; i += 1024) {
        int c = i >> 7, k = i & 127;
        f4 wv = *(const f4*)(W + (size_t)c * ldw + wcol0 + k);
        h4v hv = {(half_t)wv[0], (half_t)wv[1], (half_t)wv[2], (half_t)wv[3]};
        *(h4v*)(Wl + c * 136 + k) = hv;
    }
    __syncthreads();

    const int wv_id = tid >> 6, l = tid & 63, lr = l & 15, lk = l >> 4;
    const int r_a = min(row0 + wv_id * 16 + lr, rows - 1);

    h8 af[4];
#pragma unroll
    for (int ks = 0; ks < 4; ++ks) {
        if constexpr (sizeof(AT) == 4) {
            f4 a0 = *(const f4*)(A + (size_t)r_a * 128 + ks * 32 + lk * 8);
            f4 a1 = *(const f4*)(A + (size_t)r_a * 128 + ks * 32 + lk * 8 + 4);
            h8 v = {(half_t)a0[0], (half_t)a0[1], (half_t)a0[2], (half_t)a0[3],
                    (half_t)a1[0], (half_t)a1[1], (half_t)a1[2], (half_t)a1[3]};
            af[ks] = v;
        } else {
            af[ks] = *(const h8*)(A + (size_t)r_a * 128 + ks * 32 + lk * 8);
        }
    }

    f4 acc[8];
#pragma unroll
    for (int t = 0; t < 8; ++t) acc[t] = (f4){0.f, 0.f, 0.f, 0.f};
#pragma unroll
    for (int ks = 0; ks < 4; ++ks) {
#pragma unroll
        for (int t = 0; t < 8; ++t) {
            h8 bf = *(const h8*)(Wl + (t * 16 + lr) * 136 + ks * 32 + lk * 8);
            acc[t] = __builtin_amdgcn_mfma_f32_16x16x32_f16(af[ks], bf, acc[t], 0, 0, 0);
        }
    }
    __syncthreads();

#pragma unroll
    for (int t = 0; t < 8; ++t)
#pragma unroll
        for (int q = 0; q < 4; ++q)
            Dl[(wv_id * 16 + lk * 4 + q) * 132 + t * 16 + lr] = acc[t][q];
    __syncthreads();

    const int cl = (tid & 15) * 8;
    f4 bi0 = {0.f,0.f,0.f,0.f}, bi1 = bi0;
    if (bias) { bi0 = *(const f4*)(bias + cl); bi1 = *(const f4*)(bias + cl + 4); }
    f4 as0 = {0.f,0.f,0.f,0.f}, as1 = as0, ad0 = as0, ad1 = as0;
    if (als) {
        as0 = *(const f4*)(avs + cl) * LOG2E; as1 = *(const f4*)(avs + cl + 4) * LOG2E;
        ad0 = *(const f4*)(avd + cl) * LOG2E; ad1 = *(const f4*)(avd + cl + 4) * LOG2E;
    }
#pragma unroll
    for (int pass = 0; pass < 4; ++pass) {
        int lrow = pass * 16 + (tid >> 4);
        int r = row0 + lrow;
        bool ok = r < rows;
        f4 v0 = *(const f4*)(Dl + lrow * 132 + cl);
        f4 v1 = *(const f4*)(Dl + lrow * 132 + cl + 4);
        v0 += bi0; v1 += bi1;
        if (addtab) {
            int ri = addidx[min(r, rows - 1)];
            v0 += *(const f4*)(addtab + (size_t)ri * 128 + cl);
            v1 += *(const f4*)(addtab + (size_t)ri * 128 + cl + 4);
        }
        if (als) {
            float ps = 0.f, pd = 0.f;
#pragma unroll
            for (int j = 0; j < 4; ++j) {
                ps += v0[j] * as0[j] + v1[j] * as1[j];
                pd += v0[j] * ad0[j] + v1[j] * ad1[j];
            }
            ps = row16_allred(ps);
            pd = row16_allred(pd);
            if ((tid & 15) == 0 && ok) { als[r] = ps; ald[r] = pd; }
        }
        if (ok) {
            h8 o = {(half_t)v0[0], (half_t)v0[1], (half_t)v0[2], (half_t)v0[3],
                    (half_t)v1[0], (half_t)v1[1], (half_t)v1[2], (half_t)v1[3]};
            *(h8*)(out16 + (size_t)r * 128 + cl) = o;
        }
    }
}

// ---------------------------------------------------------------- entity attention (r11 — FROZEN)
__global__ __launch_bounds__(256) void k_entity(const int* __restrict__ hA,
                                                const int* __restrict__ tA,
                                                const int* __restrict__ ridx,
                                                const half_t* __restrict__ pattr,
                                                const float* __restrict__ prel,
                                                half_t* __restrict__ s_emb16, int N) {
    int w = (blockIdx.x * blockDim.x + threadIdx.x) >> 6;
    if (w >= N) return;
    w = __builtin_amdgcn_readfirstlane(w);
    const int lane = threadIdx.x & 63;
    const int c = lane * 2;
    const int ri = ridx[w];
    const f2 rp = *(const f2*)(prel + (size_t)ri * 128 + c);
    const h2 rph = {(half_t)(rp[0] * LOG2E), (half_t)(rp[1] * LOG2E)};
    const float init = (lane == 0) ? -ESHIFT2 : 0.f;
    const int* __restrict__ hp = hA + (size_t)w * 16;
    const int* __restrict__ tp = tA + (size_t)w * 16;

    f2 oh = {0.f, 0.f}, ot = {0.f, 0.f};
    float sh = 0.f, st = 0.f;

    h2 bh[2][4], bt[2][4];
#pragma unroll
    for (int q = 0; q < 4; ++q) {
        bh[0][q] = *(const h2*)(pattr + (size_t)hp[q] * 128 + c);
        bt[0][q] = *(const h2*)(pattr + (size_t)tp[q] * 128 + c);
    }
#pragma unroll
    for (int b = 0; b < 4; ++b) {
        const int cur = b & 1, nxt = cur ^ 1;
        if (b < 3) {
#pragma unroll
            for (int q = 0; q < 4; ++q) {
                bh[nxt][q] = *(const h2*)(pattr + (size_t)hp[4 * (b + 1) + q] * 128 + c);
                bt[nxt][q] = *(const h2*)(pattr + (size_t)tp[4 * (b + 1) + q] * 128 + c);
            }
        }
        float pph[4], ppt[4];
#pragma unroll
        for (int q = 0; q < 4; ++q) {
            pph[q] = __builtin_amdgcn_fdot2(rph, bh[cur][q], init, false);  // v_dot2_f32_f16
            ppt[q] = __builtin_amdgcn_fdot2(rph, bt[cur][q], init, false);
        }
        float Sh[4], St[4];
#pragma unroll
        for (int q = 0; q < 4; ++q) {
            Sh[q] = wave_red_bcast(pph[q]);
            St[q] = wave_red_bcast(ppt[q]);
        }
#pragma unroll
        for (int q = 0; q < 4; ++q) {
            float wh = exp2f(Sh[q]);
            float wt = exp2f(St[q]);
            sh += wh; st += wt;
            oh[0] = fmaf(wh, (float)bh[cur][q][0], oh[0]);
            oh[1] = fmaf(wh, (float)bh[cur][q][1], oh[1]);
            ot[0] = fmaf(wt, (float)bt[cur][q][0], ot[0]);
            ot[1] = fmaf(wt, (float)bt[cur][q][1], ot[1]);
        }
    }
    float invh = 1.f / sh, invt = 1.f / st;
    h2 hv = {(half_t)(oh[0] * invh + ot[0] * invt),
             (half_t)(oh[1] * invh + ot[1] * invt)};
    *(h2*)(s_emb16 + (size_t)w * 128 + c) = hv;
}

// ---------------------------------------------------------------- GAT aggregate (CSR, pipelined)
// TWO nodes per wave (halves), lane owns 4 cols. Software pipeline: adj indices
// prefetched one batch-of-8 ahead (named cur/nxt buffers, static indexing);
// ALL 8 als gathers + 8 h-row gathers issued before any consumption -> ~17
// outstanding loads/wave (vs ~9 at batch-4 interleaved). als/ald pre-scaled by
// log2(e) -> exp2 directly. adj padded +16; index clamped vs pad garbage.
__global__ __launch_bounds__(256) void k_aggregate(const int* __restrict__ indptr,
                                                   const int* __restrict__ adj,
                                                   const half_t* __restrict__ hsrc,
                                                   const float* __restrict__ als,
                                                   const float* __restrict__ ald,
                                                   const float* __restrict__ bias,
                                                   float* __restrict__ out,
                                                   half_t* __restrict__ out16, int N) {
    const int tid = threadIdx.x;
    const int wv = (blockIdx.x * 256 + tid) >> 6;
    const int nodeA = wv * 2;
    if (nodeA >= N) return;
    const int lane = tid & 63;
    const int node = min(nodeA + (lane >> 5), N - 1);
    const int sl = lane & 31;
    const int c = sl * 4;

    const int beg = indptr[node];
    const int deg = indptr[node + 1] - beg;   // >= 1 (self-loop)
    const float adn = ald[node];              // pre-scaled by log2(e)

    float acc[4] = {0.f, 0.f, 0.f, 0.f};
    float exsum = 0.f;

    int cur[8], nxt[8];
#pragma unroll
    for (int q = 0; q < 8; ++q) cur[q] = adj[beg + q];  // batch 0 (padded)

#pragma unroll 1
    for (int j0 = 0; j0 < deg; j0 += 8) {
        // prefetch next batch's indices (in flight during this batch's work)
        if (j0 + 8 < deg) {
#pragma unroll
            for (int q = 0; q < 8; ++q) nxt[q] = adj[beg + j0 + 8 + q];
        }
        // phase 1: clamp + issue ALL als and h-row gathers for this batch
        int ss[8];
        float alv[8];
        h4v hv[8];
#pragma unroll
        for (int q = 0; q < 8; ++q)
            ss[q] = ((unsigned)cur[q] < (unsigned)N) ? cur[q] : 0;  // pad-garbage guard
#pragma unroll
        for (int q = 0; q < 8; ++q) alv[q] = als[ss[q]];
#pragma unroll
        for (int q = 0; q < 8; ++q) hv[q] = *(const h4v*)(hsrc + (size_t)ss[q] * 128 + c);
        // phase 2: consume
#pragma unroll
        for (int q = 0; q < 8; ++q) {
            bool ok = (j0 + q) < deg;
            float e = alv[q] + adn;
            e = fmaxf(e, NEG_SLOPE * e);
            float ex = ok ? exp2f(e - ESHIFT_AGG) : 0.f;
            exsum += ex;
#pragma unroll
            for (int j = 0; j < 4; ++j) acc[j] = fmaf(ex, (float)hv[q][j], acc[j]);
        }
#pragma unroll
        for (int q = 0; q < 8; ++q) cur[q] = nxt[q];
    }

    float inv = 1.f / exsum;
    if (out) {
        f4 o;
#pragma unroll
        for (int j = 0; j < 4; ++j) o[j] = fmaf(acc[j], inv, bias[c + j]);
        *(f4*)(out + (size_t)node * 128 + c) = o;
    } else {
        h4v o;
#pragma unroll
        for (int j = 0; j < 4; ++j) o[j] = (half_t)fmaf(acc[j], inv, bias[c + j]);
        *(h4v*)(out16 + (size_t)node * 128 + c) = o;
    }
}

// ---------------------------------------------------------------- launch
extern "C" void kernel_launch(void* const* d_in, const int* in_sizes, int n_in,
                              void* d_out, int out_size, void* d_ws, size_t ws_size,
                              hipStream_t stream) {
    const int*   hA   = (const int*)d_in[0];
    const int*   tA   = (const int*)d_in[1];
    const int*   rix  = (const int*)d_in[2];
    const int*   ei   = (const int*)d_in[3];
    const float* attr_table = (const float*)d_in[4];
    const float* rel_table  = (const float*)d_in[5];
    const float* femb_w = (const float*)d_in[6];
    const float* femb_b = (const float*)d_in[7];
    const float* g1w  = (const float*)d_in[8];
    const float* g1as = (const float*)d_in[9];
    const float* g1ad = (const float*)d_in[10];
    const float* g1b  = (const float*)d_in[11];
    const float* g2w  = (const float*)d_in[12];
    const float* g2as = (const float*)d_in[13];
    const float* g2ad = (const float*)d_in[14];
    const float* g2b  = (const float*)d_in[15];

    const int N  = in_sizes[2];
    const int E  = in_sizes[3] / 2;
    const int NA = in_sizes[4] / DE;
    const int NR = in_sizes[5] / DE;
    const int EN = E + N;

    char* p = (char*)d_ws;
    auto alloc = [&](size_t bytes) -> char* {
        char* q = p;
        p += (bytes + 255) & ~(size_t)255;
        return q;
    };
    half_t* proj16 = (half_t*)alloc((size_t)NA * DE * 2);
    half_t* s16    = (half_t*)alloc((size_t)N * DE * 2);
    half_t* h16    = (half_t*)alloc((size_t)N * DE * 2);
    half_t* x116   = (half_t*)alloc((size_t)N * DE * 2);
    float* prel    = (float*)alloc((size_t)NR * DE * 4);
    float* rel2    = (float*)alloc((size_t)NR * DE * 4);
    float* alps    = (float*)alloc((size_t)N * 4);
    float* alpd    = (float*)alloc((size_t)N * 4);
    int*   indptr  = (int*)alloc((size_t)(N + 1) * 4);
    int*   cnt     = (int*)alloc((size_t)N * 4);
    int*   cur     = (int*)alloc((size_t)N * 4);
    int*   adj     = (int*)alloc((size_t)(EN + 16) * 4);  // +16 pad for batch-8 over-read

    dim3 b256(256);

    // CSR build (same edge set both layers -> build once)
    hipMemsetAsync(cnt, 0, (size_t)N * 4, stream);
    hipMemsetAsync(cur, 0, (size_t)N * 4, stream);
    k_count<<<dim3((EN + 255) / 256), b256, 0, stream>>>(ei, E, N, cnt);
    k_scan<<<dim3(1), dim3(1024), 0, stream>>>(cnt, N, indptr);
    k_fill<<<dim3((EN + 255) / 256), b256, 0, stream>>>(ei, E, N, indptr, cur, adj);

    // rel-table projections (500 rows, f32 path)
    k_gemm<2><<<dim3((NR + 31) / 32), b256, 0, stream>>>(rel_table, NR, femb_w, DE, 0,
                                                         femb_b, prel);
    k_gemm<2><<<dim3((NR + 31) / 32), b256, 0, stream>>>(rel_table, NR, g1w, 2 * DE, DE,
                                                         nullptr, rel2);

    // attr table projection straight to fp16 (MFMA, f32 A-path)
    k_gemm_mfma<float><<<dim3((NA + 63) / 64), b256, 0, stream>>>(attr_table, NA,
        femb_w, DE, 0, femb_b, nullptr, nullptr, nullptr, nullptr, nullptr, nullptr, proj16);

    // entity attention (h + t fused), ONE node per wave (frozen)
    k_entity<<<dim3((N + 3) / 4), b256, 0, stream>>>(hA, tA, rix, proj16, prel, s16, N);

    // GAT layer 1: h = s_emb @ Wl.T + rel2[r_idx]; alpha fused (pre-scaled); h fp16
    k_gemm_mfma<half_t><<<dim3((N + 63) / 64), b256, 0, stream>>>(s16, N,
        g1w, 2 * DE, 0, nullptr, rel2, rix, g1as, g1ad, alps, alpd, h16);
    k_aggregate<<<dim3((N + 7) / 8), b256, 0, stream>>>(indptr, adj, h16, alps, alpd, g1b,
                                                        nullptr, x116, N);

    // GAT layer 2
    k_gemm_mfma<half_t><<<dim3((N + 63) / 64), b256, 0, stream>>>(x116, N,
        g2w, DE, 0, nullptr, nullptr, nullptr, g2as, g2ad, alps, alpd, h16);
    k_aggregate<<<dim3((N + 7) / 8), b256, 0, stream>>>(indptr, adj, h16, alps, alpd, g2b,
                                                        (float*)d_out, nullptr, N);
}

// Round 13
// 304.967 us; speedup vs baseline: 1.3217x; 1.0587x over previous
//
#include <hip/hip_runtime.h>
#include <math.h>

#define DE 128
#define NEG_SLOPE 0.2f
#define LOG2E 1.4426950408889634f
#define ESHIFT2 57.707801635559926f      /* 40 * log2(e)  (entity) */
#define ESHIFT_AGG 28.853900817779268f   /* 20 * log2(e)  (aggregate) */
#define EXP2(x) __builtin_amdgcn_exp2f(x)  /* raw v_exp_f32; inputs bounded, no range fixup needed */

typedef __attribute__((ext_vector_type(4))) float f4;
typedef __attribute__((ext_vector_type(2))) float f2;
typedef _Float16 half_t;
typedef __attribute__((ext_vector_type(2))) _Float16 h2;
typedef __attribute__((ext_vector_type(4))) _Float16 h4v;
typedef __attribute__((ext_vector_type(8))) _Float16 h8;

// Wave64 sum-reduce on the VALU only (DPP adds + readlane), zero LDS-pipe ops.
__device__ __forceinline__ float wave_red_bcast(float x) {
    union fi { float f; int i; };
    fi a; a.f = x;
    fi t;
    t.i = __builtin_amdgcn_update_dpp(0, a.i, 0x111, 0xf, 0xf, true); a.f += t.f; // row_shr:1
    t.i = __builtin_amdgcn_update_dpp(0, a.i, 0x112, 0xf, 0xf, true); a.f += t.f; // row_shr:2
    t.i = __builtin_amdgcn_update_dpp(0, a.i, 0x114, 0xf, 0xf, true); a.f += t.f; // row_shr:4
    t.i = __builtin_amdgcn_update_dpp(0, a.i, 0x118, 0xf, 0xf, true); a.f += t.f; // row_shr:8
    t.i = __builtin_amdgcn_update_dpp(0, a.i, 0x142, 0xa, 0xf, true); a.f += t.f; // row_bcast:15
    t.i = __builtin_amdgcn_update_dpp(0, a.i, 0x143, 0xc, 0xf, true); a.f += t.f; // row_bcast:31
    fi r; r.i = __builtin_amdgcn_readlane(a.i, 63);
    return r.f;
}

// All-reduce within each 16-lane DPP row (lane gets its row's sum). 4 DPP adds.
__device__ __forceinline__ float row16_allred(float x) {
    union fi { float f; int i; };
    fi a; a.f = x;
    fi t;
    t.i = __builtin_amdgcn_update_dpp(0, a.i, 0x121, 0xf, 0xf, true); a.f += t.f; // row_ror:1
    t.i = __builtin_amdgcn_update_dpp(0, a.i, 0x122, 0xf, 0xf, true); a.f += t.f; // row_ror:2
    t.i = __builtin_amdgcn_update_dpp(0, a.i, 0x124, 0xf, 0xf, true); a.f += t.f; // row_ror:4
    t.i = __builtin_amdgcn_update_dpp(0, a.i, 0x128, 0xf, 0xf, true); a.f += t.f; // row_ror:8
    return a.f;
}

// ---------------------------------------------------------------- CSR build
__global__ __launch_bounds__(256) void k_count(const int* __restrict__ ei, int E, int N,
                                               int* __restrict__ cnt) {
    int e = blockIdx.x * blockDim.x + threadIdx.x;
    int total = E + N;
    if (e >= total) return;
    int dst = (e < E) ? ei[E + e] : (e - E);
    atomicAdd(&cnt[dst], 1);
}

__global__ __launch_bounds__(1024) void k_scan(const int* __restrict__ cnt, int n,
                                               int* __restrict__ indptr) {
    __shared__ int wsum[16];
    __shared__ int btot;
    int tid = threadIdx.x, lane = tid & 63, w = tid >> 6;
    int carry = 0;
    for (int base = 0; base < n; base += 1024) {
        int i = base + tid;
        int v = (i < n) ? cnt[i] : 0;
        int x = v;
#pragma unroll
        for (int off = 1; off < 64; off <<= 1) {
            int t = __shfl_up(x, off, 64);
            if (lane >= off) x += t;
        }
        if (lane == 63) wsum[w] = x;
        __syncthreads();
        if (w == 0) {
            int s = (lane < 16) ? wsum[lane] : 0;
#pragma unroll
            for (int off = 1; off < 16; off <<= 1) {
                int t = __shfl_up(s, off, 64);
                if (lane >= off) s += t;
            }
            if (lane < 16) wsum[lane] = s;
            if (lane == 15) btot = s;
        }
        __syncthreads();
        int wexcl = (w == 0) ? 0 : wsum[w - 1];
        if (i < n) indptr[i] = carry + wexcl + (x - v);
        carry += btot;
        __syncthreads();
    }
    if (tid == 0) indptr[n] = carry;
}

__global__ __launch_bounds__(256) void k_fill(const int* __restrict__ ei, int E, int N,
                                              const int* __restrict__ indptr,
                                              int* __restrict__ cur, int* __restrict__ adj) {
    int e = blockIdx.x * blockDim.x + threadIdx.x;
    int total = E + N;
    if (e >= total) return;
    int src, dst;
    if (e < E) { src = ei[e]; dst = ei[E + e]; }
    else       { src = dst = e - E; }
    int pos = indptr[dst] + atomicAdd(&cur[dst], 1);
    adj[pos] = src;
}

// ---------------------------------------------------------------- rel-table GEMMs (both in ONE dispatch; blockIdx.y selects)
__global__ __launch_bounds__(256) void k_gemm_rel(const float* __restrict__ in, int rows,
                                                  const float* __restrict__ W1,
                                                  const float* __restrict__ bias1,
                                                  float* __restrict__ out1,
                                                  const float* __restrict__ W2,
                                                  float* __restrict__ out2) {
    const float* W; int ldw, wcol0; const float* bias; float* out;
    if (blockIdx.y == 0) { W = W1; ldw = DE;     wcol0 = 0;  bias = bias1;   out = out1; }
    else                 { W = W2; ldw = 2 * DE; wcol0 = DE; bias = nullptr; out = out2; }

    __shared__ float Wt[128 * 128];
    const int tid = threadIdx.x;
#pragma unroll
    for (int it = 0; it < 16; ++it) {
        int idx = it * 256 + tid;
        int c = idx & 127, k4 = idx >> 7;
        f4 wv = *(const f4*)(W + (size_t)c * ldw + wcol0 + k4 * 4);
#pragma unroll
        for (int j = 0; j < 4; ++j) Wt[(4 * k4 + j) * 128 + c] = wv[j];
    }
    __syncthreads();

    const int RPT = 2;
    const int cgrp = tid & 15, rgrp = tid >> 4;
    const int c0 = cgrp * 4;
    const int row0 = blockIdx.x * (16 * RPT) + rgrp * RPT;

    const float* rowp[RPT];
#pragma unroll
    for (int i = 0; i < RPT; ++i)
        rowp[i] = in + (size_t)min(row0 + i, rows - 1) * 128;

    float acc[RPT][8];
#pragma unroll
    for (int i = 0; i < RPT; ++i)
#pragma unroll
        for (int j = 0; j < 8; ++j) acc[i][j] = 0.f;

#pragma unroll 1
    for (int k = 0; k < 128; k += 4) {
        f4 a[RPT];
#pragma unroll
        for (int i = 0; i < RPT; ++i) a[i] = *(const f4*)(rowp[i] + k);
#pragma unroll
        for (int kk = 0; kk < 4; ++kk) {
            f4 b0 = *(const f4*)&Wt[(k + kk) * 128 + c0];
            f4 b1 = *(const f4*)&Wt[(k + kk) * 128 + c0 + 64];
#pragma unroll
            for (int i = 0; i < RPT; ++i) {
                float av = a[i][kk];
#pragma unroll
                for (int j = 0; j < 4; ++j) {
                    acc[i][j]     = fmaf(av, b0[j], acc[i][j]);
                    acc[i][j + 4] = fmaf(av, b1[j], acc[i][j + 4]);
                }
            }
        }
    }
    f4 bi0 = {0.f,0.f,0.f,0.f}, bi1 = {0.f,0.f,0.f,0.f};
    if (bias) { bi0 = *(const f4*)(bias + c0); bi1 = *(const f4*)(bias + c0 + 64); }
#pragma unroll
    for (int i = 0; i < RPT; ++i) {
        int r = row0 + i;
        if (r < rows) {
            f4 v0, v1;
#pragma unroll
            for (int j = 0; j < 4; ++j) { v0[j] = acc[i][j] + bi0[j]; v1[j] = acc[i][j+4] + bi1[j]; }
            *(f4*)(out + (size_t)r * 128 + c0) = v0;
            *(f4*)(out + (size_t)r * 128 + c0 + 64) = v1;
        }
    }
}

// ---------------------------------------------------------------- MFMA GEMM (fp16 in, f32 acc)
// NOTE: als/ald are stored PRE-SCALED by log2(e) (consumed by k_aggregate's exp2).
template <typename AT>
__global__ __launch_bounds__(256) void k_gemm_mfma(const AT* __restrict__ A, int rows,
                                                   const float* __restrict__ W, int ldw, int wcol0,
                                                   const float* __restrict__ bias,
                                                   const float* __restrict__ addtab,
                                                   const int* __restrict__ addidx,
                                                   const float* __restrict__ avs,
                                                   const float* __restrict__ avd,
                                                   float* __restrict__ als,
                                                   float* __restrict__ ald,
                                                   half_t* __restrict__ out16) {
    __shared__ alignas(16) char ldsbuf[128 * 136 * 2];  // Wl (fp16) then aliased as Dl (f32)
    half_t* Wl = (half_t*)ldsbuf;
    float*  Dl = (float*)ldsbuf;

    const int tid = threadIdx.x;
    const int row0 = blockIdx.x * 64;

    for (int i = tid * 4; i < 128 * 128; i += 1024) {
        int c = i >> 7, k = i & 127;
        f4 wv = *(const f4*)(W + (size_t)c * ldw + wcol0 + k);
        h4v hv = {(half_t)wv[0], (half_t)wv[1], (half_t)wv[2], (half_t)wv[3]};
        *(h4v*)(Wl + c * 136 + k) = hv;
    }
    __syncthreads();

    const int wv_id = tid >> 6, l = tid & 63, lr = l & 15, lk = l >> 4;
    const int r_a = min(row0 + wv_id * 16 + lr, rows - 1);

    h8 af[4];
#pragma unroll
    for (int ks = 0; ks < 4; ++ks) {
        if constexpr (sizeof(AT) == 4) {
            f4 a0 = *(const f4*)(A + (size_t)r_a * 128 + ks * 32 + lk * 8);
            f4 a1 = *(const f4*)(A + (size_t)r_a * 128 + ks * 32 + lk * 8 + 4);
            h8 v = {(half_t)a0[0], (half_t)a0[1], (half_t)a0[2], (half_t)a0[3],
                    (half_t)a1[0], (half_t)a1[1], (half_t)a1[2], (half_t)a1[3]};
            af[ks] = v;
        } else {
            af[ks] = *(const h8*)(A + (size_t)r_a * 128 + ks * 32 + lk * 8);
        }
    }

    f4 acc[8];
#pragma unroll
    for (int t = 0; t < 8; ++t) acc[t] = (f4){0.f, 0.f, 0.f, 0.f};
#pragma unroll
    for (int ks = 0; ks < 4; ++ks) {
#pragma unroll
        for (int t = 0; t < 8; ++t) {
            h8 bf = *(const h8*)(Wl + (t * 16 + lr) * 136 + ks * 32 + lk * 8);
            acc[t] = __builtin_amdgcn_mfma_f32_16x16x32_f16(af[ks], bf, acc[t], 0, 0, 0);
        }
    }
    __syncthreads();

#pragma unroll
    for (int t = 0; t < 8; ++t)
#pragma unroll
        for (int q = 0; q < 4; ++q)
            Dl[(wv_id * 16 + lk * 4 + q) * 132 + t * 16 + lr] = acc[t][q];
    __syncthreads();

    const int cl = (tid & 15) * 8;
    f4 bi0 = {0.f,0.f,0.f,0.f}, bi1 = bi0;
    if (bias) { bi0 = *(const f4*)(bias + cl); bi1 = *(const f4*)(bias + cl + 4); }
    f4 as0 = {0.f,0.f,0.f,0.f}, as1 = as0, ad0 = as0, ad1 = as0;
    if (als) {
        as0 = *(const f4*)(avs + cl) * LOG2E; as1 = *(const f4*)(avs + cl + 4) * LOG2E;
        ad0 = *(const f4*)(avd + cl) * LOG2E; ad1 = *(const f4*)(avd + cl + 4) * LOG2E;
    }
#pragma unroll
    for (int pass = 0; pass < 4; ++pass) {
        int lrow = pass * 16 + (tid >> 4);
        int r = row0 + lrow;
        bool ok = r < rows;
        f4 v0 = *(const f4*)(Dl + lrow * 132 + cl);
        f4 v1 = *(const f4*)(Dl + lrow * 132 + cl + 4);
        v0 += bi0; v1 += bi1;
        if (addtab) {
            int ri = addidx[min(r, rows - 1)];
            v0 += *(const f4*)(addtab + (size_t)ri * 128 + cl);
            v1 += *(const f4*)(addtab + (size_t)ri * 128 + cl + 4);
        }
        if (als) {
            float ps = 0.f, pd = 0.f;
#pragma unroll
            for (int j = 0; j < 4; ++j) {
                ps += v0[j] * as0[j] + v1[j] * as1[j];
                pd += v0[j] * ad0[j] + v1[j] * ad1[j];
            }
            ps = row16_allred(ps);
            pd = row16_allred(pd);
            if ((tid & 15) == 0 && ok) { als[r] = ps; ald[r] = pd; }
        }
        if (ok) {
            h8 o = {(half_t)v0[0], (half_t)v0[1], (half_t)v0[2], (half_t)v0[3],
                    (half_t)v1[0], (half_t)v1[1], (half_t)v1[2], (half_t)v1[3]};
            *(h8*)(out16 + (size_t)r * 128 + cl) = o;
        }
    }
}

// ---------------------------------------------------------------- entity attention (r11 skeleton + addr/exp diet)
// One wave per node; lane owns cols {2l,2l+1} (4B fp16 gathers, whole wave =
// one 256B row per instruction — FROZEN access shape). Diet: 32-bit byte-offset
// gather addressing (table 12.8MB < 4GB -> (idx<<8)+lane*4 exact; saddr-form
// loads, 1 VALU addr instr); raw v_exp_f32 via builtin (bounded inputs).
__global__ __launch_bounds__(256) void k_entity(const int* __restrict__ hA,
                                                const int* __restrict__ tA,
                                                const int* __restrict__ ridx,
                                                const half_t* __restrict__ pattr,
                                                const float* __restrict__ prel,
                                                half_t* __restrict__ s_emb16, int N) {
    int w = (blockIdx.x * blockDim.x + threadIdx.x) >> 6;
    if (w >= N) return;
    w = __builtin_amdgcn_readfirstlane(w);
    const int lane = threadIdx.x & 63;
    const int c = lane * 2;
    const int ri = ridx[w];
    const f2 rp = *(const f2*)(prel + (size_t)ri * 128 + c);
    const h2 rph = {(half_t)(rp[0] * LOG2E), (half_t)(rp[1] * LOG2E)};
    const float init = (lane == 0) ? -ESHIFT2 : 0.f;
    const int* __restrict__ hp = hA + (size_t)w * 16;
    const int* __restrict__ tp = tA + (size_t)w * 16;
    const char* __restrict__ pb = (const char*)pattr;
    const unsigned cb = (unsigned)lane << 2;  // lane*4 bytes

    f2 oh = {0.f, 0.f}, ot = {0.f, 0.f};
    float sh = 0.f, st = 0.f;

    auto ld = [&](int idx) -> h2 {
        return *(const h2*)(pb + (((unsigned)idx << 8) + cb));  // 32-bit voffset, saddr form
    };

    h2 bh[2][4], bt[2][4];
#pragma unroll
    for (int q = 0; q < 4; ++q) {
        bh[0][q] = ld(hp[q]);
        bt[0][q] = ld(tp[q]);
    }
#pragma unroll
    for (int b = 0; b < 4; ++b) {
        const int cur = b & 1, nxt = cur ^ 1;
        if (b < 3) {
#pragma unroll
            for (int q = 0; q < 4; ++q) {
                bh[nxt][q] = ld(hp[4 * (b + 1) + q]);
                bt[nxt][q] = ld(tp[4 * (b + 1) + q]);
            }
        }
        float pph[4], ppt[4];
#pragma unroll
        for (int q = 0; q < 4; ++q) {
            pph[q] = __builtin_amdgcn_fdot2(rph, bh[cur][q], init, false);  // v_dot2_f32_f16
            ppt[q] = __builtin_amdgcn_fdot2(rph, bt[cur][q], init, false);
        }
        float Sh[4], St[4];  // 8 independent DPP chains -> latency overlapped
#pragma unroll
        for (int q = 0; q < 4; ++q) {
            Sh[q] = wave_red_bcast(pph[q]);
            St[q] = wave_red_bcast(ppt[q]);
        }
#pragma unroll
        for (int q = 0; q < 4; ++q) {
            float wh = EXP2(Sh[q]);
            float wt = EXP2(St[q]);
            sh += wh; st += wt;
            oh[0] = fmaf(wh, (float)bh[cur][q][0], oh[0]);
            oh[1] = fmaf(wh, (float)bh[cur][q][1], oh[1]);
            ot[0] = fmaf(wt, (float)bt[cur][q][0], ot[0]);
            ot[1] = fmaf(wt, (float)bt[cur][q][1], ot[1]);
        }
    }
    float invh = 1.f / sh, invt = 1.f / st;
    h2 hv = {(half_t)(oh[0] * invh + ot[0] * invt),
             (half_t)(oh[1] * invh + ot[1] * invt)};
    *(h2*)(s_emb16 + (size_t)w * 128 + c) = hv;
}

// ---------------------------------------------------------------- GAT aggregate (CSR, pipelined)
// TWO nodes per wave (halves), lane owns 4 cols. adj prefetched one batch-of-8
// ahead; all 8 als + 8 h-row gathers issued before consumption. 32-bit gather
// offsets; raw v_exp_f32. als/ald pre-scaled by log2(e). adj padded +16.
__global__ __launch_bounds__(256) void k_aggregate(const int* __restrict__ indptr,
                                                   const int* __restrict__ adj,
                                                   const half_t* __restrict__ hsrc,
                                                   const float* __restrict__ als,
                                                   const float* __restrict__ ald,
                                                   const float* __restrict__ bias,
                                                   float* __restrict__ out,
                                                   half_t* __restrict__ out16, int N) {
    const int tid = threadIdx.x;
    const int wv = (blockIdx.x * 256 + tid) >> 6;
    const int nodeA = wv * 2;
    if (nodeA >= N) return;
    const int lane = tid & 63;
    const int node = min(nodeA + (lane >> 5), N - 1);
    const int sl = lane & 31;
    const int c = sl * 4;

    const int beg = indptr[node];
    const int deg = indptr[node + 1] - beg;   // >= 1 (self-loop)
    const float adn = ald[node];              // pre-scaled by log2(e)
    const char* __restrict__ hb = (const char*)hsrc;
    const unsigned cb = (unsigned)sl << 3;    // sl*8 bytes

    float acc[4] = {0.f, 0.f, 0.f, 0.f};
    float exsum = 0.f;

    int cur[8], nxt[8];
#pragma unroll
    for (int q = 0; q < 8; ++q) cur[q] = adj[beg + q];  // batch 0 (padded)

#pragma unroll 1
    for (int j0 = 0; j0 < deg; j0 += 8) {
        if (j0 + 8 < deg) {
#pragma unroll
            for (int q = 0; q < 8; ++q) nxt[q] = adj[beg + j0 + 8 + q];
        }
        int ss[8];
        float alv[8];
        h4v hv[8];
#pragma unroll
        for (int q = 0; q < 8; ++q)
            ss[q] = ((unsigned)cur[q] < (unsigned)N) ? cur[q] : 0;  // pad-garbage guard
#pragma unroll
        for (int q = 0; q < 8; ++q) alv[q] = als[ss[q]];
#pragma unroll
        for (int q = 0; q < 8; ++q)
            hv[q] = *(const h4v*)(hb + (((unsigned)ss[q] << 8) + cb));
#pragma unroll
        for (int q = 0; q < 8; ++q) {
            bool ok = (j0 + q) < deg;
            float e = alv[q] + adn;
            e = fmaxf(e, NEG_SLOPE * e);
            float ex = ok ? EXP2(e - ESHIFT_AGG) : 0.f;
            exsum += ex;
#pragma unroll
            for (int j = 0; j < 4; ++j) acc[j] = fmaf(ex, (float)hv[q][j], acc[j]);
        }
#pragma unroll
        for (int q = 0; q < 8; ++q) cur[q] = nxt[q];
    }

    float inv = 1.f / exsum;
    if (out) {
        f4 o;
#pragma unroll
        for (int j = 0; j < 4; ++j) o[j] = fmaf(acc[j], inv, bias[c + j]);
        *(f4*)(out + (size_t)node * 128 + c) = o;
    } else {
        h4v o;
#pragma unroll
        for (int j = 0; j < 4; ++j) o[j] = (half_t)fmaf(acc[j], inv, bias[c + j]);
        *(h4v*)(out16 + (size_t)node * 128 + c) = o;
    }
}

// ---------------------------------------------------------------- launch
extern "C" void kernel_launch(void* const* d_in, const int* in_sizes, int n_in,
                              void* d_out, int out_size, void* d_ws, size_t ws_size,
                              hipStream_t stream) {
    const int*   hA   = (const int*)d_in[0];
    const int*   tA   = (const int*)d_in[1];
    const int*   rix  = (const int*)d_in[2];
    const int*   ei   = (const int*)d_in[3];
    const float* attr_table = (const float*)d_in[4];
    const float* rel_table  = (const float*)d_in[5];
    const float* femb_w = (const float*)d_in[6];
    const float* femb_b = (const float*)d_in[7];
    const float* g1w  = (const float*)d_in[8];
    const float* g1as = (const float*)d_in[9];
    const float* g1ad = (const float*)d_in[10];
    const float* g1b  = (const float*)d_in[11];
    const float* g2w  = (const float*)d_in[12];
    const float* g2as = (const float*)d_in[13];
    const float* g2ad = (const float*)d_in[14];
    const float* g2b  = (const float*)d_in[15];

    const int N  = in_sizes[2];
    const int E  = in_sizes[3] / 2;
    const int NA = in_sizes[4] / DE;
    const int NR = in_sizes[5] / DE;
    const int EN = E + N;

    char* p = (char*)d_ws;
    auto alloc = [&](size_t bytes) -> char* {
        char* q = p;
        p += (bytes + 255) & ~(size_t)255;
        return q;
    };
    half_t* proj16 = (half_t*)alloc((size_t)NA * DE * 2);
    half_t* s16    = (half_t*)alloc((size_t)N * DE * 2);
    half_t* h16    = (half_t*)alloc((size_t)N * DE * 2);
    half_t* x116   = (half_t*)alloc((size_t)N * DE * 2);
    float* prel    = (float*)alloc((size_t)NR * DE * 4);
    float* rel2    = (float*)alloc((size_t)NR * DE * 4);
    float* alps    = (float*)alloc((size_t)N * 4);
    float* alpd    = (float*)alloc((size_t)N * 4);
    int*   indptr  = (int*)alloc((size_t)(N + 1) * 4);
    int*   cnt     = (int*)alloc((size_t)N * 4);
    int*   cur     = (int*)alloc((size_t)N * 4);   // adjacent to cnt: one memset spans both
    int*   adj     = (int*)alloc((size_t)(EN + 16) * 4);  // +16 pad for batch-8 over-read

    dim3 b256(256);

    // CSR build (same edge set both layers -> build once); single memset spans cnt+cur
    hipMemsetAsync(cnt, 0, (size_t)((char*)cur - (char*)cnt) + (size_t)N * 4, stream);
    k_count<<<dim3((EN + 255) / 256), b256, 0, stream>>>(ei, E, N, cnt);
    k_scan<<<dim3(1), dim3(1024), 0, stream>>>(cnt, N, indptr);
    k_fill<<<dim3((EN + 255) / 256), b256, 0, stream>>>(ei, E, N, indptr, cur, adj);

    // rel-table projections (500 rows), both halves in one dispatch
    k_gemm_rel<<<dim3((NR + 31) / 32, 2), b256, 0, stream>>>(rel_table, NR,
        femb_w, femb_b, prel, g1w, rel2);

    // attr table projection straight to fp16 (MFMA, f32 A-path)
    k_gemm_mfma<float><<<dim3((NA + 63) / 64), b256, 0, stream>>>(attr_table, NA,
        femb_w, DE, 0, femb_b, nullptr, nullptr, nullptr, nullptr, nullptr, nullptr, proj16);

    // entity attention (h + t fused), ONE node per wave (frozen structure)
    k_entity<<<dim3((N + 3) / 4), b256, 0, stream>>>(hA, tA, rix, proj16, prel, s16, N);

    // GAT layer 1: h = s_emb @ Wl.T + rel2[r_idx]; alpha fused (pre-scaled); h fp16
    k_gemm_mfma<half_t><<<dim3((N + 63) / 64), b256, 0, stream>>>(s16, N,
        g1w, 2 * DE, 0, nullptr, rel2, rix, g1as, g1ad, alps, alpd, h16);
    k_aggregate<<<dim3((N + 7) / 8), b256, 0, stream>>>(indptr, adj, h16, alps, alpd, g1b,
                                                        nullptr, x116, N);

    // GAT layer 2
    k_gemm_mfma<half_t><<<dim3((N + 63) / 64), b256, 0, stream>>>(x116, N,
        g2w, DE, 0, nullptr, nullptr, nullptr, g2as, g2ad, alps, alpd, h16);
    k_aggregate<<<dim3((N + 7) / 8), b256, 0, stream>>>(indptr, adj, h16, alps, alpd, g2b,
                                                        (float*)d_out, nullptr, N);
}

// Round 14
// 293.023 us; speedup vs baseline: 1.3755x; 1.0408x over previous
//
#include <hip/hip_runtime.h>
#include <math.h>

#define DE 128
#define NEG_SLOPE 0.2f
#define LOG2E 1.4426950408889634f
#define ESHIFT2 57.707801635559926f      /* 40 * log2(e)  (entity) */
#define ESHIFT_AGG 28.853900817779268f   /* 20 * log2(e)  (aggregate) */
#define EXP2(x) __builtin_amdgcn_exp2f(x)  /* raw v_exp_f32; inputs bounded */

typedef __attribute__((ext_vector_type(4))) float f4;
typedef __attribute__((ext_vector_type(2))) float f2;
typedef _Float16 half_t;
typedef __attribute__((ext_vector_type(2))) _Float16 h2;
typedef __attribute__((ext_vector_type(4))) _Float16 h4v;
typedef __attribute__((ext_vector_type(8))) _Float16 h8;

// Wave64 sum-reduce on the VALU only (DPP adds + readlane), zero LDS-pipe ops.
__device__ __forceinline__ float wave_red_bcast(float x) {
    union fi { float f; int i; };
    fi a; a.f = x;
    fi t;
    t.i = __builtin_amdgcn_update_dpp(0, a.i, 0x111, 0xf, 0xf, true); a.f += t.f; // row_shr:1
    t.i = __builtin_amdgcn_update_dpp(0, a.i, 0x112, 0xf, 0xf, true); a.f += t.f; // row_shr:2
    t.i = __builtin_amdgcn_update_dpp(0, a.i, 0x114, 0xf, 0xf, true); a.f += t.f; // row_shr:4
    t.i = __builtin_amdgcn_update_dpp(0, a.i, 0x118, 0xf, 0xf, true); a.f += t.f; // row_shr:8
    t.i = __builtin_amdgcn_update_dpp(0, a.i, 0x142, 0xa, 0xf, true); a.f += t.f; // row_bcast:15
    t.i = __builtin_amdgcn_update_dpp(0, a.i, 0x143, 0xc, 0xf, true); a.f += t.f; // row_bcast:31
    fi r; r.i = __builtin_amdgcn_readlane(a.i, 63);
    return r.f;
}

// All-reduce within each 16-lane DPP row (lane gets its row's sum). 4 DPP adds.
__device__ __forceinline__ float row16_allred(float x) {
    union fi { float f; int i; };
    fi a; a.f = x;
    fi t;
    t.i = __builtin_amdgcn_update_dpp(0, a.i, 0x121, 0xf, 0xf, true); a.f += t.f; // row_ror:1
    t.i = __builtin_amdgcn_update_dpp(0, a.i, 0x122, 0xf, 0xf, true); a.f += t.f; // row_ror:2
    t.i = __builtin_amdgcn_update_dpp(0, a.i, 0x124, 0xf, 0xf, true); a.f += t.f; // row_ror:4
    t.i = __builtin_amdgcn_update_dpp(0, a.i, 0x128, 0xf, 0xf, true); a.f += t.f; // row_ror:8
    return a.f;
}

// ================================================================ CSR bodies
__device__ __forceinline__ void count_body(int bid, const int* __restrict__ ei, int E, int N,
                                           int* __restrict__ cnt) {
    int e = bid * 256 + threadIdx.x;
    int total = E + N;
    if (e >= total) return;
    int dst = (e < E) ? ei[E + e] : (e - E);
    atomicAdd(&cnt[dst], 1);
}

// 256-thread block scan, 4 items/thread per 1024-tile. smem: >= 5 ints.
__device__ void scan_body(const int* __restrict__ cnt, int n, int* __restrict__ indptr,
                          char* smem) {
    int* wsum = (int*)smem;       // [4]
    int* btot = (int*)smem + 4;
    const int tid = threadIdx.x, lane = tid & 63, w = tid >> 6;
    int carry = 0;
    for (int base = 0; base < n; base += 1024) {
        int i0 = base + tid * 4;
        int4 v = {0, 0, 0, 0};
        if (i0 + 3 < n) v = *(const int4*)(cnt + i0);
        else {
            if (i0 < n)     v.x = cnt[i0];
            if (i0 + 1 < n) v.y = cnt[i0 + 1];
            if (i0 + 2 < n) v.z = cnt[i0 + 2];
        }
        int s = v.x + v.y + v.z + v.w;
        int x = s;
#pragma unroll
        for (int off = 1; off < 64; off <<= 1) {
            int t = __shfl_up(x, off, 64);
            if (lane >= off) x += t;
        }
        if (lane == 63) wsum[w] = x;
        __syncthreads();
        if (tid == 0) {
            int acc = 0;
#pragma unroll
            for (int k = 0; k < 4; ++k) { int t = wsum[k]; wsum[k] = acc; acc += t; }
            *btot = acc;
        }
        __syncthreads();
        int excl = carry + wsum[w] + (x - s);
        if (i0 < n)     indptr[i0]     = excl;
        if (i0 + 1 < n) indptr[i0 + 1] = excl + v.x;
        if (i0 + 2 < n) indptr[i0 + 2] = excl + v.x + v.y;
        if (i0 + 3 < n) indptr[i0 + 3] = excl + v.x + v.y + v.z;
        carry += *btot;
        __syncthreads();
    }
    if (tid == 0) indptr[n] = carry;
}

__device__ __forceinline__ void fill_body(int bid, const int* __restrict__ ei, int E, int N,
                                          const int* __restrict__ indptr,
                                          int* __restrict__ cur, int* __restrict__ adj) {
    int e = bid * 256 + threadIdx.x;
    int total = E + N;
    if (e >= total) return;
    int src, dst;
    if (e < E) { src = ei[e]; dst = ei[E + e]; }
    else       { src = dst = e - E; }
    int pos = indptr[dst] + atomicAdd(&cur[dst], 1);
    adj[pos] = src;
}

// ================================================================ rel-table GEMM body (500 rows)
// sel=0: out1 = in @ W1.T + bias1 ; sel=1: out2 = in @ W2[:,DE:].T
__device__ void rel_body(int bx, int sel, const float* __restrict__ in, int rows,
                         const float* __restrict__ W1, const float* __restrict__ bias1,
                         float* __restrict__ out1, const float* __restrict__ W2,
                         float* __restrict__ out2, char* smem) {
    const float* W; int ldw, wcol0; const float* bias; float* out;
    if (sel == 0) { W = W1; ldw = DE;     wcol0 = 0;  bias = bias1;   out = out1; }
    else          { W = W2; ldw = 2 * DE; wcol0 = DE; bias = nullptr; out = out2; }

    float* Wt = (float*)smem;  // [128*128]
    const int tid = threadIdx.x;
#pragma unroll
    for (int it = 0; it < 16; ++it) {
        int idx = it * 256 + tid;
        int c = idx & 127, k4 = idx >> 7;
        f4 wv = *(const f4*)(W + (size_t)c * ldw + wcol0 + k4 * 4);
#pragma unroll
        for (int j = 0; j < 4; ++j) Wt[(4 * k4 + j) * 128 + c] = wv[j];
    }
    __syncthreads();

    const int RPT = 2;
    const int cgrp = tid & 15, rgrp = tid >> 4;
    const int c0 = cgrp * 4;
    const int row0 = bx * (16 * RPT) + rgrp * RPT;

    const float* rowp[RPT];
#pragma unroll
    for (int i = 0; i < RPT; ++i)
        rowp[i] = in + (size_t)min(row0 + i, rows - 1) * 128;

    float acc[RPT][8];
#pragma unroll
    for (int i = 0; i < RPT; ++i)
#pragma unroll
        for (int j = 0; j < 8; ++j) acc[i][j] = 0.f;

#pragma unroll 1
    for (int k = 0; k < 128; k += 4) {
        f4 a[RPT];
#pragma unroll
        for (int i = 0; i < RPT; ++i) a[i] = *(const f4*)(rowp[i] + k);
#pragma unroll
        for (int kk = 0; kk < 4; ++kk) {
            f4 b0 = *(const f4*)&Wt[(k + kk) * 128 + c0];
            f4 b1 = *(const f4*)&Wt[(k + kk) * 128 + c0 + 64];
#pragma unroll
            for (int i = 0; i < RPT; ++i) {
                float av = a[i][kk];
#pragma unroll
                for (int j = 0; j < 4; ++j) {
                    acc[i][j]     = fmaf(av, b0[j], acc[i][j]);
                    acc[i][j + 4] = fmaf(av, b1[j], acc[i][j + 4]);
                }
            }
        }
    }
    f4 bi0 = {0.f,0.f,0.f,0.f}, bi1 = {0.f,0.f,0.f,0.f};
    if (bias) { bi0 = *(const f4*)(bias + c0); bi1 = *(const f4*)(bias + c0 + 64); }
#pragma unroll
    for (int i = 0; i < RPT; ++i) {
        int r = row0 + i;
        if (r < rows) {
            f4 v0, v1;
#pragma unroll
            for (int j = 0; j < 4; ++j) { v0[j] = acc[i][j] + bi0[j]; v1[j] = acc[i][j+4] + bi1[j]; }
            *(f4*)(out + (size_t)r * 128 + c0) = v0;
            *(f4*)(out + (size_t)r * 128 + c0 + 64) = v1;
        }
    }
}

// ================================================================ MFMA GEMM body (fp16 in, f32 acc)
// als/ald stored PRE-SCALED by log2(e). smem: 128*136*2 bytes.
template <typename AT>
__device__ void gemm_mfma_body(int bid, const AT* __restrict__ A, int rows,
                               const float* __restrict__ W, int ldw, int wcol0,
                               const float* __restrict__ bias,
                               const float* __restrict__ addtab,
                               const int* __restrict__ addidx,
                               const float* __restrict__ avs,
                               const float* __restrict__ avd,
                               float* __restrict__ als,
                               float* __restrict__ ald,
                               half_t* __restrict__ out16, char* smem) {
    half_t* Wl = (half_t*)smem;
    float*  Dl = (float*)smem;

    const int tid = threadIdx.x;
    const int row0 = bid * 64;

    for (int i = tid * 4; i < 128 * 128; i += 1024) {
        int c = i >> 7, k = i & 127;
        f4 wv = *(const f4*)(W + (size_t)c * ldw + wcol0 + k);
        h4v hv = {(half_t)wv[0], (half_t)wv[1], (half_t)wv[2], (half_t)wv[3]};
        *(h4v*)(Wl + c * 136 + k) = hv;
    }
    __syncthreads();

    const int wv_id = tid >> 6, l = tid & 63, lr = l & 15, lk = l >> 4;
    const int r_a = min(row0 + wv_id * 16 + lr, rows - 1);

    h8 af[4];
#pragma unroll
    for (int ks = 0; ks < 4; ++ks) {
        if constexpr (sizeof(AT) == 4) {
            f4 a0 = *(const f4*)(A + (size_t)r_a * 128 + ks * 32 + lk * 8);
            f4 a1 = *(const f4*)(A + (size_t)r_a * 128 + ks * 32 + lk * 8 + 4);
            h8 v = {(half_t)a0[0], (half_t)a0[1], (half_t)a0[2], (half_t)a0[3],
                    (half_t)a1[0], (half_t)a1[1], (half_t)a1[2], (half_t)a1[3]};
            af[ks] = v;
        } else {
            af[ks] = *(const h8*)(A + (size_t)r_a * 128 + ks * 32 + lk * 8);
        }
    }

    f4 acc[8];
#pragma unroll
    for (int t = 0; t < 8; ++t) acc[t] = (f4){0.f, 0.f, 0.f, 0.f};
#pragma unroll
    for (int ks = 0; ks < 4; ++ks) {
#pragma unroll
        for (int t = 0; t < 8; ++t) {
            h8 bf = *(const h8*)(Wl + (t * 16 + lr) * 136 + ks * 32 + lk * 8);
            acc[t] = __builtin_amdgcn_mfma_f32_16x16x32_f16(af[ks], bf, acc[t], 0, 0, 0);
        }
    }
    __syncthreads();

#pragma unroll
    for (int t = 0; t < 8; ++t)
#pragma unroll
        for (int q = 0; q < 4; ++q)
            Dl[(wv_id * 16 + lk * 4 + q) * 132 + t * 16 + lr] = acc[t][q];
    __syncthreads();

    const int cl = (tid & 15) * 8;
    f4 bi0 = {0.f,0.f,0.f,0.f}, bi1 = bi0;
    if (bias) { bi0 = *(const f4*)(bias + cl); bi1 = *(const f4*)(bias + cl + 4); }
    f4 as0 = {0.f,0.f,0.f,0.f}, as1 = as0, ad0 = as0, ad1 = as0;
    if (als) {
        as0 = *(const f4*)(avs + cl) * LOG2E; as1 = *(const f4*)(avs + cl + 4) * LOG2E;
        ad0 = *(const f4*)(avd + cl) * LOG2E; ad1 = *(const f4*)(avd + cl + 4) * LOG2E;
    }
#pragma unroll
    for (int pass = 0; pass < 4; ++pass) {
        int lrow = pass * 16 + (tid >> 4);
        int r = row0 + lrow;
        bool ok = r < rows;
        f4 v0 = *(const f4*)(Dl + lrow * 132 + cl);
        f4 v1 = *(const f4*)(Dl + lrow * 132 + cl + 4);
        v0 += bi0; v1 += bi1;
        if (addtab) {
            int ri = addidx[min(r, rows - 1)];
            v0 += *(const f4*)(addtab + (size_t)ri * 128 + cl);
            v1 += *(const f4*)(addtab + (size_t)ri * 128 + cl + 4);
        }
        if (als) {
            float ps = 0.f, pd = 0.f;
#pragma unroll
            for (int j = 0; j < 4; ++j) {
                ps += v0[j] * as0[j] + v1[j] * as1[j];
                pd += v0[j] * ad0[j] + v1[j] * ad1[j];
            }
            ps = row16_allred(ps);
            pd = row16_allred(pd);
            if ((tid & 15) == 0 && ok) { als[r] = ps; ald[r] = pd; }
        }
        if (ok) {
            h8 o = {(half_t)v0[0], (half_t)v0[1], (half_t)v0[2], (half_t)v0[3],
                    (half_t)v1[0], (half_t)v1[1], (half_t)v1[2], (half_t)v1[3]};
            *(h8*)(out16 + (size_t)r * 128 + cl) = o;
        }
    }
}

// ================================================================ entity body (FROZEN structure)
// One wave per node; lane owns cols {2l,2l+1} (4B fp16 gathers, whole wave =
// one 256B row per instruction). 32-bit byte-offset addressing; raw v_exp_f32;
// fdot2 with shift folded into lane 0's C operand; pure-VALU DPP reduce.
__device__ void entity_body(int bid, const int* __restrict__ hA,
                            const int* __restrict__ tA,
                            const int* __restrict__ ridx,
                            const half_t* __restrict__ pattr,
                            const float* __restrict__ prel,
                            half_t* __restrict__ s_emb16, int N) {
    int w = (bid * 256 + (int)threadIdx.x) >> 6;
    if (w >= N) return;
    w = __builtin_amdgcn_readfirstlane(w);
    const int lane = threadIdx.x & 63;
    const int c = lane * 2;
    const int ri = ridx[w];
    const f2 rp = *(const f2*)(prel + (size_t)ri * 128 + c);
    const h2 rph = {(half_t)(rp[0] * LOG2E), (half_t)(rp[1] * LOG2E)};
    const float init = (lane == 0) ? -ESHIFT2 : 0.f;
    const int* __restrict__ hp = hA + (size_t)w * 16;
    const int* __restrict__ tp = tA + (size_t)w * 16;
    const char* __restrict__ pb = (const char*)pattr;
    const unsigned cb = (unsigned)lane << 2;

    f2 oh = {0.f, 0.f}, ot = {0.f, 0.f};
    float sh = 0.f, st = 0.f;

    auto ld = [&](int idx) -> h2 {
        return *(const h2*)(pb + (((unsigned)idx << 8) + cb));
    };

    h2 bh[2][4], bt[2][4];
#pragma unroll
    for (int q = 0; q < 4; ++q) {
        bh[0][q] = ld(hp[q]);
        bt[0][q] = ld(tp[q]);
    }
#pragma unroll
    for (int b = 0; b < 4; ++b) {
        const int cur = b & 1, nxt = cur ^ 1;
        if (b < 3) {
#pragma unroll
            for (int q = 0; q < 4; ++q) {
                bh[nxt][q] = ld(hp[4 * (b + 1) + q]);
                bt[nxt][q] = ld(tp[4 * (b + 1) + q]);
            }
        }
        float pph[4], ppt[4];
#pragma unroll
        for (int q = 0; q < 4; ++q) {
            pph[q] = __builtin_amdgcn_fdot2(rph, bh[cur][q], init, false);
            ppt[q] = __builtin_amdgcn_fdot2(rph, bt[cur][q], init, false);
        }
        float Sh[4], St[4];
#pragma unroll
        for (int q = 0; q < 4; ++q) {
            Sh[q] = wave_red_bcast(pph[q]);
            St[q] = wave_red_bcast(ppt[q]);
        }
#pragma unroll
        for (int q = 0; q < 4; ++q) {
            float wh = EXP2(Sh[q]);
            float wt = EXP2(St[q]);
            sh += wh; st += wt;
            oh[0] = fmaf(wh, (float)bh[cur][q][0], oh[0]);
            oh[1] = fmaf(wh, (float)bh[cur][q][1], oh[1]);
            ot[0] = fmaf(wt, (float)bt[cur][q][0], ot[0]);
            ot[1] = fmaf(wt, (float)bt[cur][q][1], ot[1]);
        }
    }
    float invh = 1.f / sh, invt = 1.f / st;
    h2 hv = {(half_t)(oh[0] * invh + ot[0] * invt),
             (half_t)(oh[1] * invh + ot[1] * invt)};
    *(h2*)(s_emb16 + (size_t)w * 128 + c) = hv;
}

// ================================================================ fused dispatch kernels
// L1: CSR count  ∥  attr-table MFMA projection
__global__ __launch_bounds__(256) void k_count_attr(const int* __restrict__ ei, int E, int N,
                                                    int* __restrict__ cnt, int CB,
                                                    const float* __restrict__ attr, int NA,
                                                    const float* __restrict__ W,
                                                    const float* __restrict__ bias,
                                                    half_t* __restrict__ out16) {
    __shared__ alignas(16) char smem[128 * 136 * 2];
    int b = blockIdx.x;
    if (b < CB) count_body(b, ei, E, N, cnt);
    else gemm_mfma_body<float>(b - CB, attr, NA, W, DE, 0, bias, nullptr, nullptr,
                               nullptr, nullptr, nullptr, nullptr, out16, smem);
}

// L2: rel-table GEMMs (both)  ∥  CSR scan
__global__ __launch_bounds__(256) void k_rel_scan(const float* __restrict__ in, int rows,
                                                  const float* __restrict__ W1,
                                                  const float* __restrict__ b1,
                                                  float* __restrict__ out1,
                                                  const float* __restrict__ W2,
                                                  float* __restrict__ out2, int RB,
                                                  const int* __restrict__ cnt, int n,
                                                  int* __restrict__ indptr) {
    __shared__ alignas(16) char smem[128 * 128 * 4];  // rel Wt (64KB); scan uses first 20B
    int b = blockIdx.x;
    if (b < 2 * RB) rel_body(b % RB, b / RB, in, rows, W1, b1, out1, W2, out2, smem);
    else scan_body(cnt, n, indptr, smem);
}

// L3: CSR fill  ∥  entity attention
__global__ __launch_bounds__(256) void k_fill_entity(const int* __restrict__ ei, int E,
                                                     const int* __restrict__ indptr,
                                                     int* __restrict__ cur,
                                                     int* __restrict__ adj, int FB,
                                                     const int* __restrict__ hA,
                                                     const int* __restrict__ tA,
                                                     const int* __restrict__ ridx,
                                                     const half_t* __restrict__ pattr,
                                                     const float* __restrict__ prel,
                                                     half_t* __restrict__ s_emb16, int N) {
    int b = blockIdx.x;
    if (b < FB) fill_body(b, ei, E, N, indptr, cur, adj);
    else entity_body(b - FB, hA, tA, ridx, pattr, prel, s_emb16, N);
}

// standalone MFMA GEMM (gat layers, fp16 A)
__global__ __launch_bounds__(256) void k_gemm_mfma_h(const half_t* __restrict__ A, int rows,
                                                     const float* __restrict__ W, int ldw, int wcol0,
                                                     const float* __restrict__ bias,
                                                     const float* __restrict__ addtab,
                                                     const int* __restrict__ addidx,
                                                     const float* __restrict__ avs,
                                                     const float* __restrict__ avd,
                                                     float* __restrict__ als,
                                                     float* __restrict__ ald,
                                                     half_t* __restrict__ out16) {
    __shared__ alignas(16) char smem[128 * 136 * 2];
    gemm_mfma_body<half_t>(blockIdx.x, A, rows, W, ldw, wcol0, bias, addtab, addidx,
                           avs, avd, als, ald, out16, smem);
}

// ---------------------------------------------------------------- GAT aggregate (CSR, pipelined; unchanged)
__global__ __launch_bounds__(256) void k_aggregate(const int* __restrict__ indptr,
                                                   const int* __restrict__ adj,
                                                   const half_t* __restrict__ hsrc,
                                                   const float* __restrict__ als,
                                                   const float* __restrict__ ald,
                                                   const float* __restrict__ bias,
                                                   float* __restrict__ out,
                                                   half_t* __restrict__ out16, int N) {
    const int tid = threadIdx.x;
    const int wv = (blockIdx.x * 256 + tid) >> 6;
    const int nodeA = wv * 2;
    if (nodeA >= N) return;
    const int lane = tid & 63;
    const int node = min(nodeA + (lane >> 5), N - 1);
    const int sl = lane & 31;
    const int c = sl * 4;

    const int beg = indptr[node];
    const int deg = indptr[node + 1] - beg;   // >= 1 (self-loop)
    const float adn = ald[node];              // pre-scaled by log2(e)
    const char* __restrict__ hb = (const char*)hsrc;
    const unsigned cb = (unsigned)sl << 3;

    float acc[4] = {0.f, 0.f, 0.f, 0.f};
    float exsum = 0.f;

    int cur[8], nxt[8];
#pragma unroll
    for (int q = 0; q < 8; ++q) cur[q] = adj[beg + q];  // batch 0 (padded)

#pragma unroll 1
    for (int j0 = 0; j0 < deg; j0 += 8) {
        if (j0 + 8 < deg) {
#pragma unroll
            for (int q = 0; q < 8; ++q) nxt[q] = adj[beg + j0 + 8 + q];
        }
        int ss[8];
        float alv[8];
        h4v hv[8];
#pragma unroll
        for (int q = 0; q < 8; ++q)
            ss[q] = ((unsigned)cur[q] < (unsigned)N) ? cur[q] : 0;
#pragma unroll
        for (int q = 0; q < 8; ++q) alv[q] = als[ss[q]];
#pragma unroll
        for (int q = 0; q < 8; ++q)
            hv[q] = *(const h4v*)(hb + (((unsigned)ss[q] << 8) + cb));
#pragma unroll
        for (int q = 0; q < 8; ++q) {
            bool ok = (j0 + q) < deg;
            float e = alv[q] + adn;
            e = fmaxf(e, NEG_SLOPE * e);
            float ex = ok ? EXP2(e - ESHIFT_AGG) : 0.f;
            exsum += ex;
#pragma unroll
            for (int j = 0; j < 4; ++j) acc[j] = fmaf(ex, (float)hv[q][j], acc[j]);
        }
#pragma unroll
        for (int q = 0; q < 8; ++q) cur[q] = nxt[q];
    }

    float inv = 1.f / exsum;
    if (out) {
        f4 o;
#pragma unroll
        for (int j = 0; j < 4; ++j) o[j] = fmaf(acc[j], inv, bias[c + j]);
        *(f4*)(out + (size_t)node * 128 + c) = o;
    } else {
        h4v o;
#pragma unroll
        for (int j = 0; j < 4; ++j) o[j] = (half_t)fmaf(acc[j], inv, bias[c + j]);
        *(h4v*)(out16 + (size_t)node * 128 + c) = o;
    }
}

// ---------------------------------------------------------------- launch
extern "C" void kernel_launch(void* const* d_in, const int* in_sizes, int n_in,
                              void* d_out, int out_size, void* d_ws, size_t ws_size,
                              hipStream_t stream) {
    const int*   hA   = (const int*)d_in[0];
    const int*   tA   = (const int*)d_in[1];
    const int*   rix  = (const int*)d_in[2];
    const int*   ei   = (const int*)d_in[3];
    const float* attr_table = (const float*)d_in[4];
    const float* rel_table  = (const float*)d_in[5];
    const float* femb_w = (const float*)d_in[6];
    const float* femb_b = (const float*)d_in[7];
    const float* g1w  = (const float*)d_in[8];
    const float* g1as = (const float*)d_in[9];
    const float* g1ad = (const float*)d_in[10];
    const float* g1b  = (const float*)d_in[11];
    const float* g2w  = (const float*)d_in[12];
    const float* g2as = (const float*)d_in[13];
    const float* g2ad = (const float*)d_in[14];
    const float* g2b  = (const float*)d_in[15];

    const int N  = in_sizes[2];
    const int E  = in_sizes[3] / 2;
    const int NA = in_sizes[4] / DE;
    const int NR = in_sizes[5] / DE;
    const int EN = E + N;

    char* p = (char*)d_ws;
    auto alloc = [&](size_t bytes) -> char* {
        char* q = p;
        p += (bytes + 255) & ~(size_t)255;
        return q;
    };
    half_t* proj16 = (half_t*)alloc((size_t)NA * DE * 2);
    half_t* s16    = (half_t*)alloc((size_t)N * DE * 2);
    half_t* h16    = (half_t*)alloc((size_t)N * DE * 2);
    half_t* x116   = (half_t*)alloc((size_t)N * DE * 2);
    float* prel    = (float*)alloc((size_t)NR * DE * 4);
    float* rel2    = (float*)alloc((size_t)NR * DE * 4);
    float* alps    = (float*)alloc((size_t)N * 4);
    float* alpd    = (float*)alloc((size_t)N * 4);
    int*   indptr  = (int*)alloc((size_t)(N + 1) * 4);
    int*   cnt     = (int*)alloc((size_t)N * 4);
    int*   cur     = (int*)alloc((size_t)N * 4);   // adjacent to cnt: one memset spans both
    int*   adj     = (int*)alloc((size_t)(EN + 16) * 4);  // +16 pad for batch-8 over-read

    dim3 b256(256);
    const int CB = (EN + 255) / 256;         // count blocks
    const int MB = (NA + 63) / 64;           // attr mfma blocks
    const int RB = (NR + 31) / 32;           // rel gemm blocks (per W)
    const int FB = CB;                       // fill blocks
    const int EB = (N + 3) / 4;              // entity blocks

    // memset cnt+cur (adjacent) in one call
    hipMemsetAsync(cnt, 0, (size_t)((char*)cur - (char*)cnt) + (size_t)N * 4, stream);

    // L1: CSR count ∥ attr-table MFMA projection
    k_count_attr<<<dim3(CB + MB), b256, 0, stream>>>(ei, E, N, cnt, CB,
                                                     attr_table, NA, femb_w, femb_b, proj16);

    // L2: rel-table GEMMs ∥ CSR scan
    k_rel_scan<<<dim3(2 * RB + 1), b256, 0, stream>>>(rel_table, NR, femb_w, femb_b, prel,
                                                      g1w, rel2, RB, cnt, N, indptr);

    // L3: CSR fill ∥ entity attention
    k_fill_entity<<<dim3(FB + EB), b256, 0, stream>>>(ei, E, indptr, cur, adj, FB,
                                                      hA, tA, rix, proj16, prel, s16, N);

    // GAT layer 1: h = s_emb @ Wl.T + rel2[r_idx]; alpha fused (pre-scaled); h fp16
    k_gemm_mfma_h<<<dim3((N + 63) / 64), b256, 0, stream>>>(s16, N,
        g1w, 2 * DE, 0, nullptr, rel2, rix, g1as, g1ad, alps, alpd, h16);
    k_aggregate<<<dim3((N + 7) / 8), b256, 0, stream>>>(indptr, adj, h16, alps, alpd, g1b,
                                                        nullptr, x116, N);

    // GAT layer 2
    k_gemm_mfma_h<<<dim3((N + 63) / 64), b256, 0, stream>>>(x116, N,
        g2w, DE, 0, nullptr, nullptr, nullptr, g2as, g2ad, alps, alpd, h16);
    k_aggregate<<<dim3((N + 7) / 8), b256, 0, stream>>>(indptr, adj, h16, alps, alpd, g2b,
                                                        (float*)d_out, nullptr, N);
}

// Round 15
// 291.439 us; speedup vs baseline: 1.3830x; 1.0054x over previous
//
#include <hip/hip_runtime.h>
#include <math.h>

#define DE 128
#define NEG_SLOPE 0.2f
#define LOG2E 1.4426950408889634f
#define ESHIFT2 57.707801635559926f      /* 40 * log2(e)  (entity) */
#define ESHIFT_AGG 28.853900817779268f   /* 20 * log2(e)  (aggregate) */
#define EXP2(x) __builtin_amdgcn_exp2f(x)  /* raw v_exp_f32; inputs bounded */

typedef __attribute__((ext_vector_type(4))) float f4;
typedef __attribute__((ext_vector_type(2))) float f2;
typedef _Float16 half_t;
typedef __attribute__((ext_vector_type(2))) _Float16 h2;
typedef __attribute__((ext_vector_type(4))) _Float16 h4v;
typedef __attribute__((ext_vector_type(8))) _Float16 h8;

// Wave64 sum-reduce on the VALU only (DPP adds + readlane), zero LDS-pipe ops.
__device__ __forceinline__ float wave_red_bcast(float x) {
    union fi { float f; int i; };
    fi a; a.f = x;
    fi t;
    t.i = __builtin_amdgcn_update_dpp(0, a.i, 0x111, 0xf, 0xf, true); a.f += t.f; // row_shr:1
    t.i = __builtin_amdgcn_update_dpp(0, a.i, 0x112, 0xf, 0xf, true); a.f += t.f; // row_shr:2
    t.i = __builtin_amdgcn_update_dpp(0, a.i, 0x114, 0xf, 0xf, true); a.f += t.f; // row_shr:4
    t.i = __builtin_amdgcn_update_dpp(0, a.i, 0x118, 0xf, 0xf, true); a.f += t.f; // row_shr:8
    t.i = __builtin_amdgcn_update_dpp(0, a.i, 0x142, 0xa, 0xf, true); a.f += t.f; // row_bcast:15
    t.i = __builtin_amdgcn_update_dpp(0, a.i, 0x143, 0xc, 0xf, true); a.f += t.f; // row_bcast:31
    fi r; r.i = __builtin_amdgcn_readlane(a.i, 63);
    return r.f;
}

// All-reduce within each 16-lane DPP row (lane gets its row's sum). 4 DPP adds.
__device__ __forceinline__ float row16_allred(float x) {
    union fi { float f; int i; };
    fi a; a.f = x;
    fi t;
    t.i = __builtin_amdgcn_update_dpp(0, a.i, 0x121, 0xf, 0xf, true); a.f += t.f; // row_ror:1
    t.i = __builtin_amdgcn_update_dpp(0, a.i, 0x122, 0xf, 0xf, true); a.f += t.f; // row_ror:2
    t.i = __builtin_amdgcn_update_dpp(0, a.i, 0x124, 0xf, 0xf, true); a.f += t.f; // row_ror:4
    t.i = __builtin_amdgcn_update_dpp(0, a.i, 0x128, 0xf, 0xf, true); a.f += t.f; // row_ror:8
    return a.f;
}

// ================================================================ CSR bodies
__device__ __forceinline__ void count_body(int bid, const int* __restrict__ ei, int E, int N,
                                           int* __restrict__ cnt) {
    int e = bid * 256 + threadIdx.x;
    int total = E + N;
    if (e >= total) return;
    int dst = (e < E) ? ei[E + e] : (e - E);
    atomicAdd(&cnt[dst], 1);
}

// 256-thread block scan, 4 items/thread per 1024-tile. smem: >= 5 ints.
__device__ void scan_body(const int* __restrict__ cnt, int n, int* __restrict__ indptr,
                          char* smem) {
    int* wsum = (int*)smem;       // [4]
    int* btot = (int*)smem + 4;
    const int tid = threadIdx.x, lane = tid & 63, w = tid >> 6;
    int carry = 0;
    for (int base = 0; base < n; base += 1024) {
        int i0 = base + tid * 4;
        int4 v = {0, 0, 0, 0};
        if (i0 + 3 < n) v = *(const int4*)(cnt + i0);
        else {
            if (i0 < n)     v.x = cnt[i0];
            if (i0 + 1 < n) v.y = cnt[i0 + 1];
            if (i0 + 2 < n) v.z = cnt[i0 + 2];
        }
        int s = v.x + v.y + v.z + v.w;
        int x = s;
#pragma unroll
        for (int off = 1; off < 64; off <<= 1) {
            int t = __shfl_up(x, off, 64);
            if (lane >= off) x += t;
        }
        if (lane == 63) wsum[w] = x;
        __syncthreads();
        if (tid == 0) {
            int acc = 0;
#pragma unroll
            for (int k = 0; k < 4; ++k) { int t = wsum[k]; wsum[k] = acc; acc += t; }
            *btot = acc;
        }
        __syncthreads();
        int excl = carry + wsum[w] + (x - s);
        if (i0 < n)     indptr[i0]     = excl;
        if (i0 + 1 < n) indptr[i0 + 1] = excl + v.x;
        if (i0 + 2 < n) indptr[i0 + 2] = excl + v.x + v.y;
        if (i0 + 3 < n) indptr[i0 + 3] = excl + v.x + v.y + v.z;
        carry += *btot;
        __syncthreads();
    }
    if (tid == 0) indptr[n] = carry;
}

__device__ __forceinline__ void fill_body(int bid, const int* __restrict__ ei, int E, int N,
                                          const int* __restrict__ indptr,
                                          int* __restrict__ cur, int* __restrict__ adj) {
    int e = bid * 256 + threadIdx.x;
    int total = E + N;
    if (e >= total) return;
    int src, dst;
    if (e < E) { src = ei[e]; dst = ei[E + e]; }
    else       { src = dst = e - E; }
    int pos = indptr[dst] + atomicAdd(&cur[dst], 1);
    adj[pos] = src;
}

// ================================================================ rel-table GEMM body (500 rows)
__device__ void rel_body(int bx, int sel, const float* __restrict__ in, int rows,
                         const float* __restrict__ W1, const float* __restrict__ bias1,
                         float* __restrict__ out1, const float* __restrict__ W2,
                         float* __restrict__ out2, char* smem) {
    const float* W; int ldw, wcol0; const float* bias; float* out;
    if (sel == 0) { W = W1; ldw = DE;     wcol0 = 0;  bias = bias1;   out = out1; }
    else          { W = W2; ldw = 2 * DE; wcol0 = DE; bias = nullptr; out = out2; }

    float* Wt = (float*)smem;  // [128*128]
    const int tid = threadIdx.x;
#pragma unroll
    for (int it = 0; it < 16; ++it) {
        int idx = it * 256 + tid;
        int c = idx & 127, k4 = idx >> 7;
        f4 wv = *(const f4*)(W + (size_t)c * ldw + wcol0 + k4 * 4);
#pragma unroll
        for (int j = 0; j < 4; ++j) Wt[(4 * k4 + j) * 128 + c] = wv[j];
    }
    __syncthreads();

    const int RPT = 2;
    const int cgrp = tid & 15, rgrp = tid >> 4;
    const int c0 = cgrp * 4;
    const int row0 = bx * (16 * RPT) + rgrp * RPT;

    const float* rowp[RPT];
#pragma unroll
    for (int i = 0; i < RPT; ++i)
        rowp[i] = in + (size_t)min(row0 + i, rows - 1) * 128;

    float acc[RPT][8];
#pragma unroll
    for (int i = 0; i < RPT; ++i)
#pragma unroll
        for (int j = 0; j < 8; ++j) acc[i][j] = 0.f;

#pragma unroll 1
    for (int k = 0; k < 128; k += 4) {
        f4 a[RPT];
#pragma unroll
        for (int i = 0; i < RPT; ++i) a[i] = *(const f4*)(rowp[i] + k);
#pragma unroll
        for (int kk = 0; kk < 4; ++kk) {
            f4 b0 = *(const f4*)&Wt[(k + kk) * 128 + c0];
            f4 b1 = *(const f4*)&Wt[(k + kk) * 128 + c0 + 64];
#pragma unroll
            for (int i = 0; i < RPT; ++i) {
                float av = a[i][kk];
#pragma unroll
                for (int j = 0; j < 4; ++j) {
                    acc[i][j]     = fmaf(av, b0[j], acc[i][j]);
                    acc[i][j + 4] = fmaf(av, b1[j], acc[i][j + 4]);
                }
            }
        }
    }
    f4 bi0 = {0.f,0.f,0.f,0.f}, bi1 = {0.f,0.f,0.f,0.f};
    if (bias) { bi0 = *(const f4*)(bias + c0); bi1 = *(const f4*)(bias + c0 + 64); }
#pragma unroll
    for (int i = 0; i < RPT; ++i) {
        int r = row0 + i;
        if (r < rows) {
            f4 v0, v1;
#pragma unroll
            for (int j = 0; j < 4; ++j) { v0[j] = acc[i][j] + bi0[j]; v1[j] = acc[i][j+4] + bi1[j]; }
            *(f4*)(out + (size_t)r * 128 + c0) = v0;
            *(f4*)(out + (size_t)r * 128 + c0 + 64) = v1;
        }
    }
}

// ================================================================ MFMA GEMM body (fp16 in, f32 acc)
// als/ald stored PRE-SCALED by log2(e). smem: 128*136*2 bytes.
template <typename AT>
__device__ void gemm_mfma_body(int bid, const AT* __restrict__ A, int rows,
                               const float* __restrict__ W, int ldw, int wcol0,
                               const float* __restrict__ bias,
                               const float* __restrict__ addtab,
                               const int* __restrict__ addidx,
                               const float* __restrict__ avs,
                               const float* __restrict__ avd,
                               float* __restrict__ als,
                               float* __restrict__ ald,
                               half_t* __restrict__ out16, char* smem) {
    half_t* Wl = (half_t*)smem;
    float*  Dl = (float*)smem;

    const int tid = threadIdx.x;
    const int row0 = bid * 64;

    for (int i = tid * 4; i < 128 * 128; i += 1024) {
        int c = i >> 7, k = i & 127;
        f4 wv = *(const f4*)(W + (size_t)c * ldw + wcol0 + k);
        h4v hv = {(half_t)wv[0], (half_t)wv[1], (half_t)wv[2], (half_t)wv[3]};
        *(h4v*)(Wl + c * 136 + k) = hv;
    }
    __syncthreads();

    const int wv_id = tid >> 6, l = tid & 63, lr = l & 15, lk = l >> 4;
    const int r_a = min(row0 + wv_id * 16 + lr, rows - 1);

    h8 af[4];
#pragma unroll
    for (int ks = 0; ks < 4; ++ks) {
        if constexpr (sizeof(AT) == 4) {
            f4 a0 = *(const f4*)(A + (size_t)r_a * 128 + ks * 32 + lk * 8);
            f4 a1 = *(const f4*)(A + (size_t)r_a * 128 + ks * 32 + lk * 8 + 4);
            h8 v = {(half_t)a0[0], (half_t)a0[1], (half_t)a0[2], (half_t)a0[3],
                    (half_t)a1[0], (half_t)a1[1], (half_t)a1[2], (half_t)a1[3]};
            af[ks] = v;
        } else {
            af[ks] = *(const h8*)(A + (size_t)r_a * 128 + ks * 32 + lk * 8);
        }
    }

    f4 acc[8];
#pragma unroll
    for (int t = 0; t < 8; ++t) acc[t] = (f4){0.f, 0.f, 0.f, 0.f};
#pragma unroll
    for (int ks = 0; ks < 4; ++ks) {
#pragma unroll
        for (int t = 0; t < 8; ++t) {
            h8 bf = *(const h8*)(Wl + (t * 16 + lr) * 136 + ks * 32 + lk * 8);
            acc[t] = __builtin_amdgcn_mfma_f32_16x16x32_f16(af[ks], bf, acc[t], 0, 0, 0);
        }
    }
    __syncthreads();

#pragma unroll
    for (int t = 0; t < 8; ++t)
#pragma unroll
        for (int q = 0; q < 4; ++q)
            Dl[(wv_id * 16 + lk * 4 + q) * 132 + t * 16 + lr] = acc[t][q];
    __syncthreads();

    const int cl = (tid & 15) * 8;
    f4 bi0 = {0.f,0.f,0.f,0.f}, bi1 = bi0;
    if (bias) { bi0 = *(const f4*)(bias + cl); bi1 = *(const f4*)(bias + cl + 4); }
    f4 as0 = {0.f,0.f,0.f,0.f}, as1 = as0, ad0 = as0, ad1 = as0;
    if (als) {
        as0 = *(const f4*)(avs + cl) * LOG2E; as1 = *(const f4*)(avs + cl + 4) * LOG2E;
        ad0 = *(const f4*)(avd + cl) * LOG2E; ad1 = *(const f4*)(avd + cl + 4) * LOG2E;
    }
#pragma unroll
    for (int pass = 0; pass < 4; ++pass) {
        int lrow = pass * 16 + (tid >> 4);
        int r = row0 + lrow;
        bool ok = r < rows;
        f4 v0 = *(const f4*)(Dl + lrow * 132 + cl);
        f4 v1 = *(const f4*)(Dl + lrow * 132 + cl + 4);
        v0 += bi0; v1 += bi1;
        if (addtab) {
            int ri = addidx[min(r, rows - 1)];
            v0 += *(const f4*)(addtab + (size_t)ri * 128 + cl);
            v1 += *(const f4*)(addtab + (size_t)ri * 128 + cl + 4);
        }
        if (als) {
            float ps = 0.f, pd = 0.f;
#pragma unroll
            for (int j = 0; j < 4; ++j) {
                ps += v0[j] * as0[j] + v1[j] * as1[j];
                pd += v0[j] * ad0[j] + v1[j] * ad1[j];
            }
            ps = row16_allred(ps);
            pd = row16_allred(pd);
            if ((tid & 15) == 0 && ok) { als[r] = ps; ald[r] = pd; }
        }
        if (ok) {
            h8 o = {(half_t)v0[0], (half_t)v0[1], (half_t)v0[2], (half_t)v0[3],
                    (half_t)v1[0], (half_t)v1[1], (half_t)v1[2], (half_t)v1[3]};
            *(h8*)(out16 + (size_t)r * 128 + cl) = o;
        }
    }
}

// ================================================================ entity body (FROZEN structure)
__device__ void entity_body(int bid, const int* __restrict__ hA,
                            const int* __restrict__ tA,
                            const int* __restrict__ ridx,
                            const half_t* __restrict__ pattr,
                            const float* __restrict__ prel,
                            half_t* __restrict__ s_emb16, int N) {
    int w = (bid * 256 + (int)threadIdx.x) >> 6;
    if (w >= N) return;
    w = __builtin_amdgcn_readfirstlane(w);
    const int lane = threadIdx.x & 63;
    const int c = lane * 2;
    const int ri = ridx[w];
    const f2 rp = *(const f2*)(prel + (size_t)ri * 128 + c);
    const h2 rph = {(half_t)(rp[0] * LOG2E), (half_t)(rp[1] * LOG2E)};
    const float init = (lane == 0) ? -ESHIFT2 : 0.f;
    const int* __restrict__ hp = hA + (size_t)w * 16;
    const int* __restrict__ tp = tA + (size_t)w * 16;
    const char* __restrict__ pb = (const char*)pattr;
    const unsigned cb = (unsigned)lane << 2;

    f2 oh = {0.f, 0.f}, ot = {0.f, 0.f};
    float sh = 0.f, st = 0.f;

    auto ld = [&](int idx) -> h2 {
        return *(const h2*)(pb + (((unsigned)idx << 8) + cb));
    };

    h2 bh[2][4], bt[2][4];
#pragma unroll
    for (int q = 0; q < 4; ++q) {
        bh[0][q] = ld(hp[q]);
        bt[0][q] = ld(tp[q]);
    }
#pragma unroll
    for (int b = 0; b < 4; ++b) {
        const int cur = b & 1, nxt = cur ^ 1;
        if (b < 3) {
#pragma unroll
            for (int q = 0; q < 4; ++q) {
                bh[nxt][q] = ld(hp[4 * (b + 1) + q]);
                bt[nxt][q] = ld(tp[4 * (b + 1) + q]);
            }
        }
        float pph[4], ppt[4];
#pragma unroll
        for (int q = 0; q < 4; ++q) {
            pph[q] = __builtin_amdgcn_fdot2(rph, bh[cur][q], init, false);
            ppt[q] = __builtin_amdgcn_fdot2(rph, bt[cur][q], init, false);
        }
        float Sh[4], St[4];
#pragma unroll
        for (int q = 0; q < 4; ++q) {
            Sh[q] = wave_red_bcast(pph[q]);
            St[q] = wave_red_bcast(ppt[q]);
        }
#pragma unroll
        for (int q = 0; q < 4; ++q) {
            float wh = EXP2(Sh[q]);
            float wt = EXP2(St[q]);
            sh += wh; st += wt;
            oh[0] = fmaf(wh, (float)bh[cur][q][0], oh[0]);
            oh[1] = fmaf(wh, (float)bh[cur][q][1], oh[1]);
            ot[0] = fmaf(wt, (float)bt[cur][q][0], ot[0]);
            ot[1] = fmaf(wt, (float)bt[cur][q][1], ot[1]);
        }
    }
    float invh = 1.f / sh, invt = 1.f / st;
    h2 hv = {(half_t)(oh[0] * invh + ot[0] * invt),
             (half_t)(oh[1] * invh + ot[1] * invt)};
    *(h2*)(s_emb16 + (size_t)w * 128 + c) = hv;
}

// ================================================================ fused dispatch kernels
// L1: attr-table MFMA projection (blocks FIRST — compute-critical)  ∥  CSR count
__global__ __launch_bounds__(256) void k_attr_count(const float* __restrict__ attr, int NA,
                                                    const float* __restrict__ W,
                                                    const float* __restrict__ bias,
                                                    half_t* __restrict__ out16, int MB,
                                                    const int* __restrict__ ei, int E, int N,
                                                    int* __restrict__ cnt) {
    __shared__ alignas(16) char smem[128 * 136 * 2];
    int b = blockIdx.x;
    if (b < MB) gemm_mfma_body<float>(b, attr, NA, W, DE, 0, bias, nullptr, nullptr,
                                      nullptr, nullptr, nullptr, nullptr, out16, smem);
    else count_body(b - MB, ei, E, N, cnt);
}

// L2: rel-table GEMMs (both)  ∥  CSR scan
__global__ __launch_bounds__(256) void k_rel_scan(const float* __restrict__ in, int rows,
                                                  const float* __restrict__ W1,
                                                  const float* __restrict__ b1,
                                                  float* __restrict__ out1,
                                                  const float* __restrict__ W2,
                                                  float* __restrict__ out2, int RB,
                                                  const int* __restrict__ cnt, int n,
                                                  int* __restrict__ indptr) {
    __shared__ alignas(16) char smem[128 * 128 * 4];  // rel Wt (64KB); scan uses first 20B
    int b = blockIdx.x;
    if (b < 2 * RB) rel_body(b % RB, b / RB, in, rows, W1, b1, out1, W2, out2, smem);
    else scan_body(cnt, n, indptr, smem);
}

// entity standalone (latency-critical; keep CUs to itself)
__global__ __launch_bounds__(256) void k_entity(const int* __restrict__ hA,
                                                const int* __restrict__ tA,
                                                const int* __restrict__ ridx,
                                                const half_t* __restrict__ pattr,
                                                const float* __restrict__ prel,
                                                half_t* __restrict__ s_emb16, int N) {
    entity_body(blockIdx.x, hA, tA, ridx, pattr, prel, s_emb16, N);
}

// L4: GAT-1 GEMM (blocks FIRST)  ∥  CSR fill (atomic filler back-fills)
__global__ __launch_bounds__(256) void k_gemm1_fill(const half_t* __restrict__ A, int rows,
                                                    const float* __restrict__ W,
                                                    const float* __restrict__ rel2,
                                                    const int* __restrict__ rix,
                                                    const float* __restrict__ avs,
                                                    const float* __restrict__ avd,
                                                    float* __restrict__ als,
                                                    float* __restrict__ ald,
                                                    half_t* __restrict__ out16, int GB,
                                                    const int* __restrict__ ei, int E,
                                                    const int* __restrict__ indptr,
                                                    int* __restrict__ cur,
                                                    int* __restrict__ adj) {
    __shared__ alignas(16) char smem[128 * 136 * 2];
    int b = blockIdx.x;
    if (b < GB) gemm_mfma_body<half_t>(b, A, rows, W, 2 * DE, 0, nullptr, rel2, rix,
                                       avs, avd, als, ald, out16, smem);
    else fill_body(b - GB, ei, E, rows, indptr, cur, adj);
}

// standalone MFMA GEMM (gat layer 2)
__global__ __launch_bounds__(256) void k_gemm_mfma_h(const half_t* __restrict__ A, int rows,
                                                     const float* __restrict__ W, int ldw, int wcol0,
                                                     const float* __restrict__ bias,
                                                     const float* __restrict__ addtab,
                                                     const int* __restrict__ addidx,
                                                     const float* __restrict__ avs,
                                                     const float* __restrict__ avd,
                                                     float* __restrict__ als,
                                                     float* __restrict__ ald,
                                                     half_t* __restrict__ out16) {
    __shared__ alignas(16) char smem[128 * 136 * 2];
    gemm_mfma_body<half_t>(blockIdx.x, A, rows, W, ldw, wcol0, bias, addtab, addidx,
                           avs, avd, als, ald, out16, smem);
}

// ---------------------------------------------------------------- GAT aggregate (CSR, pipelined; unchanged)
__global__ __launch_bounds__(256) void k_aggregate(const int* __restrict__ indptr,
                                                   const int* __restrict__ adj,
                                                   const half_t* __restrict__ hsrc,
                                                   const float* __restrict__ als,
                                                   const float* __restrict__ ald,
                                                   const float* __restrict__ bias,
                                                   float* __restrict__ out,
                                                   half_t* __restrict__ out16, int N) {
    const int tid = threadIdx.x;
    const int wv = (blockIdx.x * 256 + tid) >> 6;
    const int nodeA = wv * 2;
    if (nodeA >= N) return;
    const int lane = tid & 63;
    const int node = min(nodeA + (lane >> 5), N - 1);
    const int sl = lane & 31;
    const int c = sl * 4;

    const int beg = indptr[node];
    const int deg = indptr[node + 1] - beg;   // >= 1 (self-loop)
    const float adn = ald[node];              // pre-scaled by log2(e)
    const char* __restrict__ hb = (const char*)hsrc;
    const unsigned cb = (unsigned)sl << 3;

    float acc[4] = {0.f, 0.f, 0.f, 0.f};
    float exsum = 0.f;

    int cur[8], nxt[8];
#pragma unroll
    for (int q = 0; q < 8; ++q) cur[q] = adj[beg + q];  // batch 0 (padded)

#pragma unroll 1
    for (int j0 = 0; j0 < deg; j0 += 8) {
        if (j0 + 8 < deg) {
#pragma unroll
            for (int q = 0; q < 8; ++q) nxt[q] = adj[beg + j0 + 8 + q];
        }
        int ss[8];
        float alv[8];
        h4v hv[8];
#pragma unroll
        for (int q = 0; q < 8; ++q)
            ss[q] = ((unsigned)cur[q] < (unsigned)N) ? cur[q] : 0;
#pragma unroll
        for (int q = 0; q < 8; ++q) alv[q] = als[ss[q]];
#pragma unroll
        for (int q = 0; q < 8; ++q)
            hv[q] = *(const h4v*)(hb + (((unsigned)ss[q] << 8) + cb));
#pragma unroll
        for (int q = 0; q < 8; ++q) {
            bool ok = (j0 + q) < deg;
            float e = alv[q] + adn;
            e = fmaxf(e, NEG_SLOPE * e);
            float ex = ok ? EXP2(e - ESHIFT_AGG) : 0.f;
            exsum += ex;
#pragma unroll
            for (int j = 0; j < 4; ++j) acc[j] = fmaf(ex, (float)hv[q][j], acc[j]);
        }
#pragma unroll
        for (int q = 0; q < 8; ++q) cur[q] = nxt[q];
    }

    float inv = 1.f / exsum;
    if (out) {
        f4 o;
#pragma unroll
        for (int j = 0; j < 4; ++j) o[j] = fmaf(acc[j], inv, bias[c + j]);
        *(f4*)(out + (size_t)node * 128 + c) = o;
    } else {
        h4v o;
#pragma unroll
        for (int j = 0; j < 4; ++j) o[j] = (half_t)fmaf(acc[j], inv, bias[c + j]);
        *(h4v*)(out16 + (size_t)node * 128 + c) = o;
    }
}

// ---------------------------------------------------------------- launch
extern "C" void kernel_launch(void* const* d_in, const int* in_sizes, int n_in,
                              void* d_out, int out_size, void* d_ws, size_t ws_size,
                              hipStream_t stream) {
    const int*   hA   = (const int*)d_in[0];
    const int*   tA   = (const int*)d_in[1];
    const int*   rix  = (const int*)d_in[2];
    const int*   ei   = (const int*)d_in[3];
    const float* attr_table = (const float*)d_in[4];
    const float* rel_table  = (const float*)d_in[5];
    const float* femb_w = (const float*)d_in[6];
    const float* femb_b = (const float*)d_in[7];
    const float* g1w  = (const float*)d_in[8];
    const float* g1as = (const float*)d_in[9];
    const float* g1ad = (const float*)d_in[10];
    const float* g1b  = (const float*)d_in[11];
    const float* g2w  = (const float*)d_in[12];
    const float* g2as = (const float*)d_in[13];
    const float* g2ad = (const float*)d_in[14];
    const float* g2b  = (const float*)d_in[15];

    const int N  = in_sizes[2];
    const int E  = in_sizes[3] / 2;
    const int NA = in_sizes[4] / DE;
    const int NR = in_sizes[5] / DE;
    const int EN = E + N;

    char* p = (char*)d_ws;
    auto alloc = [&](size_t bytes) -> char* {
        char* q = p;
        p += (bytes + 255) & ~(size_t)255;
        return q;
    };
    half_t* proj16 = (half_t*)alloc((size_t)NA * DE * 2);
    half_t* s16    = (half_t*)alloc((size_t)N * DE * 2);
    half_t* h16    = (half_t*)alloc((size_t)N * DE * 2);
    half_t* x116   = (half_t*)alloc((size_t)N * DE * 2);
    float* prel    = (float*)alloc((size_t)NR * DE * 4);
    float* rel2    = (float*)alloc((size_t)NR * DE * 4);
    float* alps    = (float*)alloc((size_t)N * 4);
    float* alpd    = (float*)alloc((size_t)N * 4);
    int*   indptr  = (int*)alloc((size_t)(N + 1) * 4);
    int*   cnt     = (int*)alloc((size_t)N * 4);
    int*   cur     = (int*)alloc((size_t)N * 4);   // adjacent to cnt: one memset spans both
    int*   adj     = (int*)alloc((size_t)(EN + 16) * 4);  // +16 pad for batch-8 over-read

    dim3 b256(256);
    const int CB = (EN + 255) / 256;         // count/fill blocks
    const int MB = (NA + 63) / 64;           // attr mfma blocks
    const int RB = (NR + 31) / 32;           // rel gemm blocks (per W)
    const int GB = (N + 63) / 64;            // gat gemm blocks
    const int EB = (N + 3) / 4;              // entity blocks

    // memset cnt+cur (adjacent) in one call
    hipMemsetAsync(cnt, 0, (size_t)((char*)cur - (char*)cnt) + (size_t)N * 4, stream);

    // L1: attr MFMA (first) ∥ CSR count
    k_attr_count<<<dim3(MB + CB), b256, 0, stream>>>(attr_table, NA, femb_w, femb_b,
                                                     proj16, MB, ei, E, N, cnt);

    // L2: rel-table GEMMs ∥ CSR scan
    k_rel_scan<<<dim3(2 * RB + 1), b256, 0, stream>>>(rel_table, NR, femb_w, femb_b, prel,
                                                      g1w, rel2, RB, cnt, N, indptr);

    // L3: entity attention STANDALONE (latency-critical; r14 showed fusion costs ~45 µs)
    k_entity<<<dim3(EB), b256, 0, stream>>>(hA, tA, rix, proj16, prel, s16, N);

    // L4: GAT-1 GEMM (first) ∥ CSR fill
    k_gemm1_fill<<<dim3(GB + CB), b256, 0, stream>>>(s16, N, g1w, rel2, rix,
                                                     g1as, g1ad, alps, alpd, h16, GB,
                                                     ei, E, indptr, cur, adj);

    k_aggregate<<<dim3((N + 7) / 8), b256, 0, stream>>>(indptr, adj, h16, alps, alpd, g1b,
                                                        nullptr, x116, N);

    // GAT layer 2
    k_gemm_mfma_h<<<dim3(GB), b256, 0, stream>>>(x116, N,
        g2w, DE, 0, nullptr, nullptr, nullptr, g2as, g2ad, alps, alpd, h16);
    k_aggregate<<<dim3((N + 7) / 8), b256, 0, stream>>>(indptr, adj, h16, alps, alpd, g2b,
                                                        (float*)d_out, nullptr, N);
}

// Round 16
// 265.707 us; speedup vs baseline: 1.5170x; 1.0968x over previous
//
#include <hip/hip_runtime.h>
#include <math.h>

#define DE 128
#define NEG_SLOPE 0.2f
#define LOG2E 1.4426950408889634f
#define ESHIFT2 57.707801635559926f      /* 40 * log2(e)  (entity) */
#define ESHIFT_AGG 28.853900817779268f   /* 20 * log2(e)  (aggregate) */
#define EXP2(x) __builtin_amdgcn_exp2f(x)  /* raw v_exp_f32; inputs bounded */

typedef __attribute__((ext_vector_type(4))) float f4;
typedef __attribute__((ext_vector_type(2))) float f2;
typedef _Float16 half_t;
typedef __attribute__((ext_vector_type(2))) _Float16 h2;
typedef __attribute__((ext_vector_type(4))) _Float16 h4v;
typedef __attribute__((ext_vector_type(8))) _Float16 h8;

// Wave64 sum-reduce on the VALU only (DPP adds + readlane), zero LDS-pipe ops.
__device__ __forceinline__ float wave_red_bcast(float x) {
    union fi { float f; int i; };
    fi a; a.f = x;
    fi t;
    t.i = __builtin_amdgcn_update_dpp(0, a.i, 0x111, 0xf, 0xf, true); a.f += t.f; // row_shr:1
    t.i = __builtin_amdgcn_update_dpp(0, a.i, 0x112, 0xf, 0xf, true); a.f += t.f; // row_shr:2
    t.i = __builtin_amdgcn_update_dpp(0, a.i, 0x114, 0xf, 0xf, true); a.f += t.f; // row_shr:4
    t.i = __builtin_amdgcn_update_dpp(0, a.i, 0x118, 0xf, 0xf, true); a.f += t.f; // row_shr:8
    t.i = __builtin_amdgcn_update_dpp(0, a.i, 0x142, 0xa, 0xf, true); a.f += t.f; // row_bcast:15
    t.i = __builtin_amdgcn_update_dpp(0, a.i, 0x143, 0xc, 0xf, true); a.f += t.f; // row_bcast:31
    fi r; r.i = __builtin_amdgcn_readlane(a.i, 63);
    return r.f;
}

// All-reduce within each 16-lane DPP row (lane gets its row's sum). 4 DPP adds.
__device__ __forceinline__ float row16_allred(float x) {
    union fi { float f; int i; };
    fi a; a.f = x;
    fi t;
    t.i = __builtin_amdgcn_update_dpp(0, a.i, 0x121, 0xf, 0xf, true); a.f += t.f; // row_ror:1
    t.i = __builtin_amdgcn_update_dpp(0, a.i, 0x122, 0xf, 0xf, true); a.f += t.f; // row_ror:2
    t.i = __builtin_amdgcn_update_dpp(0, a.i, 0x124, 0xf, 0xf, true); a.f += t.f; // row_ror:4
    t.i = __builtin_amdgcn_update_dpp(0, a.i, 0x128, 0xf, 0xf, true); a.f += t.f; // row_ror:8
    return a.f;
}

// ================================================================ CSR bodies
// count ALSO records each edge's rank among same-dst edges (atomic return value)
// -> fill needs NO atomics at all.
__device__ __forceinline__ void count_body(int bid, const int* __restrict__ ei, int E, int N,
                                           int* __restrict__ cnt, int* __restrict__ rank) {
    int e = bid * 256 + threadIdx.x;
    int total = E + N;
    if (e >= total) return;
    int dst = (e < E) ? ei[E + e] : (e - E);
    rank[e] = atomicAdd(&cnt[dst], 1);  // rank write is coalesced (indexed by e)
}

// 256-thread block scan, 4 items/thread per 1024-tile. smem: >= 5 ints.
__device__ void scan_body(const int* __restrict__ cnt, int n, int* __restrict__ indptr,
                          char* smem) {
    int* wsum = (int*)smem;       // [4]
    int* btot = (int*)smem + 4;
    const int tid = threadIdx.x, lane = tid & 63, w = tid >> 6;
    int carry = 0;
    for (int base = 0; base < n; base += 1024) {
        int i0 = base + tid * 4;
        int4 v = {0, 0, 0, 0};
        if (i0 + 3 < n) v = *(const int4*)(cnt + i0);
        else {
            if (i0 < n)     v.x = cnt[i0];
            if (i0 + 1 < n) v.y = cnt[i0 + 1];
            if (i0 + 2 < n) v.z = cnt[i0 + 2];
        }
        int s = v.x + v.y + v.z + v.w;
        int x = s;
#pragma unroll
        for (int off = 1; off < 64; off <<= 1) {
            int t = __shfl_up(x, off, 64);
            if (lane >= off) x += t;
        }
        if (lane == 63) wsum[w] = x;
        __syncthreads();
        if (tid == 0) {
            int acc = 0;
#pragma unroll
            for (int k = 0; k < 4; ++k) { int t = wsum[k]; wsum[k] = acc; acc += t; }
            *btot = acc;
        }
        __syncthreads();
        int excl = carry + wsum[w] + (x - s);
        if (i0 < n)     indptr[i0]     = excl;
        if (i0 + 1 < n) indptr[i0 + 1] = excl + v.x;
        if (i0 + 2 < n) indptr[i0 + 2] = excl + v.x + v.y;
        if (i0 + 3 < n) indptr[i0 + 3] = excl + v.x + v.y + v.z;
        carry += *btot;
        __syncthreads();
    }
    if (tid == 0) indptr[n] = carry;
}

// atomic-free fill: pos = indptr[dst] + rank[e]
__device__ __forceinline__ void fill_body(int bid, const int* __restrict__ ei, int E, int N,
                                          const int* __restrict__ indptr,
                                          const int* __restrict__ rank,
                                          int* __restrict__ adj) {
    int e = bid * 256 + threadIdx.x;
    int total = E + N;
    if (e >= total) return;
    int src, dst;
    if (e < E) { src = ei[e]; dst = ei[E + e]; }
    else       { src = dst = e - E; }
    adj[indptr[dst] + rank[e]] = src;
}

// ================================================================ rel-table GEMM body (500 rows)
__device__ void rel_body(int bx, int sel, const float* __restrict__ in, int rows,
                         const float* __restrict__ W1, const float* __restrict__ bias1,
                         float* __restrict__ out1, const float* __restrict__ W2,
                         float* __restrict__ out2, char* smem) {
    const float* W; int ldw, wcol0; const float* bias; float* out;
    if (sel == 0) { W = W1; ldw = DE;     wcol0 = 0;  bias = bias1;   out = out1; }
    else          { W = W2; ldw = 2 * DE; wcol0 = DE; bias = nullptr; out = out2; }

    float* Wt = (float*)smem;  // [128*128]
    const int tid = threadIdx.x;
#pragma unroll
    for (int it = 0; it < 16; ++it) {
        int idx = it * 256 + tid;
        int c = idx & 127, k4 = idx >> 7;
        f4 wv = *(const f4*)(W + (size_t)c * ldw + wcol0 + k4 * 4);
#pragma unroll
        for (int j = 0; j < 4; ++j) Wt[(4 * k4 + j) * 128 + c] = wv[j];
    }
    __syncthreads();

    const int RPT = 2;
    const int cgrp = tid & 15, rgrp = tid >> 4;
    const int c0 = cgrp * 4;
    const int row0 = bx * (16 * RPT) + rgrp * RPT;

    const float* rowp[RPT];
#pragma unroll
    for (int i = 0; i < RPT; ++i)
        rowp[i] = in + (size_t)min(row0 + i, rows - 1) * 128;

    float acc[RPT][8];
#pragma unroll
    for (int i = 0; i < RPT; ++i)
#pragma unroll
        for (int j = 0; j < 8; ++j) acc[i][j] = 0.f;

#pragma unroll 1
    for (int k = 0; k < 128; k += 4) {
        f4 a[RPT];
#pragma unroll
        for (int i = 0; i < RPT; ++i) a[i] = *(const f4*)(rowp[i] + k);
#pragma unroll
        for (int kk = 0; kk < 4; ++kk) {
            f4 b0 = *(const f4*)&Wt[(k + kk) * 128 + c0];
            f4 b1 = *(const f4*)&Wt[(k + kk) * 128 + c0 + 64];
#pragma unroll
            for (int i = 0; i < RPT; ++i) {
                float av = a[i][kk];
#pragma unroll
                for (int j = 0; j < 4; ++j) {
                    acc[i][j]     = fmaf(av, b0[j], acc[i][j]);
                    acc[i][j + 4] = fmaf(av, b1[j], acc[i][j + 4]);
                }
            }
        }
    }
    f4 bi0 = {0.f,0.f,0.f,0.f}, bi1 = {0.f,0.f,0.f,0.f};
    if (bias) { bi0 = *(const f4*)(bias + c0); bi1 = *(const f4*)(bias + c0 + 64); }
#pragma unroll
    for (int i = 0; i < RPT; ++i) {
        int r = row0 + i;
        if (r < rows) {
            f4 v0, v1;
#pragma unroll
            for (int j = 0; j < 4; ++j) { v0[j] = acc[i][j] + bi0[j]; v1[j] = acc[i][j+4] + bi1[j]; }
            *(f4*)(out + (size_t)r * 128 + c0) = v0;
            *(f4*)(out + (size_t)r * 128 + c0 + 64) = v1;
        }
    }
}

// ================================================================ MFMA GEMM body (fp16 in, f32 acc)
// als/ald stored PRE-SCALED by log2(e). smem: 128*136*2 bytes.
template <typename AT>
__device__ void gemm_mfma_body(int bid, const AT* __restrict__ A, int rows,
                               const float* __restrict__ W, int ldw, int wcol0,
                               const float* __restrict__ bias,
                               const float* __restrict__ addtab,
                               const int* __restrict__ addidx,
                               const float* __restrict__ avs,
                               const float* __restrict__ avd,
                               float* __restrict__ als,
                               float* __restrict__ ald,
                               half_t* __restrict__ out16, char* smem) {
    half_t* Wl = (half_t*)smem;
    float*  Dl = (float*)smem;

    const int tid = threadIdx.x;
    const int row0 = bid * 64;

    for (int i = tid * 4; i < 128 * 128; i += 1024) {
        int c = i >> 7, k = i & 127;
        f4 wv = *(const f4*)(W + (size_t)c * ldw + wcol0 + k);
        h4v hv = {(half_t)wv[0], (half_t)wv[1], (half_t)wv[2], (half_t)wv[3]};
        *(h4v*)(Wl + c * 136 + k) = hv;
    }
    __syncthreads();

    const int wv_id = tid >> 6, l = tid & 63, lr = l & 15, lk = l >> 4;
    const int r_a = min(row0 + wv_id * 16 + lr, rows - 1);

    h8 af[4];
#pragma unroll
    for (int ks = 0; ks < 4; ++ks) {
        if constexpr (sizeof(AT) == 4) {
            f4 a0 = *(const f4*)(A + (size_t)r_a * 128 + ks * 32 + lk * 8);
            f4 a1 = *(const f4*)(A + (size_t)r_a * 128 + ks * 32 + lk * 8 + 4);
            h8 v = {(half_t)a0[0], (half_t)a0[1], (half_t)a0[2], (half_t)a0[3],
                    (half_t)a1[0], (half_t)a1[1], (half_t)a1[2], (half_t)a1[3]};
            af[ks] = v;
        } else {
            af[ks] = *(const h8*)(A + (size_t)r_a * 128 + ks * 32 + lk * 8);
        }
    }

    f4 acc[8];
#pragma unroll
    for (int t = 0; t < 8; ++t) acc[t] = (f4){0.f, 0.f, 0.f, 0.f};
#pragma unroll
    for (int ks = 0; ks < 4; ++ks) {
#pragma unroll
        for (int t = 0; t < 8; ++t) {
            h8 bf = *(const h8*)(Wl + (t * 16 + lr) * 136 + ks * 32 + lk * 8);
            acc[t] = __builtin_amdgcn_mfma_f32_16x16x32_f16(af[ks], bf, acc[t], 0, 0, 0);
        }
    }
    __syncthreads();

#pragma unroll
    for (int t = 0; t < 8; ++t)
#pragma unroll
        for (int q = 0; q < 4; ++q)
            Dl[(wv_id * 16 + lk * 4 + q) * 132 + t * 16 + lr] = acc[t][q];
    __syncthreads();

    const int cl = (tid & 15) * 8;
    f4 bi0 = {0.f,0.f,0.f,0.f}, bi1 = bi0;
    if (bias) { bi0 = *(const f4*)(bias + cl); bi1 = *(const f4*)(bias + cl + 4); }
    f4 as0 = {0.f,0.f,0.f,0.f}, as1 = as0, ad0 = as0, ad1 = as0;
    if (als) {
        as0 = *(const f4*)(avs + cl) * LOG2E; as1 = *(const f4*)(avs + cl + 4) * LOG2E;
        ad0 = *(const f4*)(avd + cl) * LOG2E; ad1 = *(const f4*)(avd + cl + 4) * LOG2E;
    }
#pragma unroll
    for (int pass = 0; pass < 4; ++pass) {
        int lrow = pass * 16 + (tid >> 4);
        int r = row0 + lrow;
        bool ok = r < rows;
        f4 v0 = *(const f4*)(Dl + lrow * 132 + cl);
        f4 v1 = *(const f4*)(Dl + lrow * 132 + cl + 4);
        v0 += bi0; v1 += bi1;
        if (addtab) {
            int ri = addidx[min(r, rows - 1)];
            v0 += *(const f4*)(addtab + (size_t)ri * 128 + cl);
            v1 += *(const f4*)(addtab + (size_t)ri * 128 + cl + 4);
        }
        if (als) {
            float ps = 0.f, pd = 0.f;
#pragma unroll
            for (int j = 0; j < 4; ++j) {
                ps += v0[j] * as0[j] + v1[j] * as1[j];
                pd += v0[j] * ad0[j] + v1[j] * ad1[j];
            }
            ps = row16_allred(ps);
            pd = row16_allred(pd);
            if ((tid & 15) == 0 && ok) { als[r] = ps; ald[r] = pd; }
        }
        if (ok) {
            h8 o = {(half_t)v0[0], (half_t)v0[1], (half_t)v0[2], (half_t)v0[3],
                    (half_t)v1[0], (half_t)v1[1], (half_t)v1[2], (half_t)v1[3]};
            *(h8*)(out16 + (size_t)r * 128 + cl) = o;
        }
    }
}

// ================================================================ entity body (FROZEN structure)
__device__ void entity_body(int bid, const int* __restrict__ hA,
                            const int* __restrict__ tA,
                            const int* __restrict__ ridx,
                            const half_t* __restrict__ pattr,
                            const float* __restrict__ prel,
                            half_t* __restrict__ s_emb16, int N) {
    int w = (bid * 256 + (int)threadIdx.x) >> 6;
    if (w >= N) return;
    w = __builtin_amdgcn_readfirstlane(w);
    const int lane = threadIdx.x & 63;
    const int c = lane * 2;
    const int ri = ridx[w];
    const f2 rp = *(const f2*)(prel + (size_t)ri * 128 + c);
    const h2 rph = {(half_t)(rp[0] * LOG2E), (half_t)(rp[1] * LOG2E)};
    const float init = (lane == 0) ? -ESHIFT2 : 0.f;
    const int* __restrict__ hp = hA + (size_t)w * 16;
    const int* __restrict__ tp = tA + (size_t)w * 16;
    const char* __restrict__ pb = (const char*)pattr;
    const unsigned cb = (unsigned)lane << 2;

    f2 oh = {0.f, 0.f}, ot = {0.f, 0.f};
    float sh = 0.f, st = 0.f;

    auto ld = [&](int idx) -> h2 {
        return *(const h2*)(pb + (((unsigned)idx << 8) + cb));
    };

    h2 bh[2][4], bt[2][4];
#pragma unroll
    for (int q = 0; q < 4; ++q) {
        bh[0][q] = ld(hp[q]);
        bt[0][q] = ld(tp[q]);
    }
#pragma unroll
    for (int b = 0; b < 4; ++b) {
        const int cur = b & 1, nxt = cur ^ 1;
        if (b < 3) {
#pragma unroll
            for (int q = 0; q < 4; ++q) {
                bh[nxt][q] = ld(hp[4 * (b + 1) + q]);
                bt[nxt][q] = ld(tp[4 * (b + 1) + q]);
            }
        }
        float pph[4], ppt[4];
#pragma unroll
        for (int q = 0; q < 4; ++q) {
            pph[q] = __builtin_amdgcn_fdot2(rph, bh[cur][q], init, false);
            ppt[q] = __builtin_amdgcn_fdot2(rph, bt[cur][q], init, false);
        }
        float Sh[4], St[4];
#pragma unroll
        for (int q = 0; q < 4; ++q) {
            Sh[q] = wave_red_bcast(pph[q]);
            St[q] = wave_red_bcast(ppt[q]);
        }
#pragma unroll
        for (int q = 0; q < 4; ++q) {
            float wh = EXP2(Sh[q]);
            float wt = EXP2(St[q]);
            sh += wh; st += wt;
            oh[0] = fmaf(wh, (float)bh[cur][q][0], oh[0]);
            oh[1] = fmaf(wh, (float)bh[cur][q][1], oh[1]);
            ot[0] = fmaf(wt, (float)bt[cur][q][0], ot[0]);
            ot[1] = fmaf(wt, (float)bt[cur][q][1], ot[1]);
        }
    }
    float invh = 1.f / sh, invt = 1.f / st;
    h2 hv = {(half_t)(oh[0] * invh + ot[0] * invt),
             (half_t)(oh[1] * invh + ot[1] * invt)};
    *(h2*)(s_emb16 + (size_t)w * 128 + c) = hv;
}

// ================================================================ fused dispatch kernels
// L1: attr-table MFMA projection (blocks FIRST — compute-critical)  ∥  CSR count+rank
__global__ __launch_bounds__(256) void k_attr_count(const float* __restrict__ attr, int NA,
                                                    const float* __restrict__ W,
                                                    const float* __restrict__ bias,
                                                    half_t* __restrict__ out16, int MB,
                                                    const int* __restrict__ ei, int E, int N,
                                                    int* __restrict__ cnt,
                                                    int* __restrict__ rank) {
    __shared__ alignas(16) char smem[128 * 136 * 2];
    int b = blockIdx.x;
    if (b < MB) gemm_mfma_body<float>(b, attr, NA, W, DE, 0, bias, nullptr, nullptr,
                                      nullptr, nullptr, nullptr, nullptr, out16, smem);
    else count_body(b - MB, ei, E, N, cnt, rank);
}

// L2: rel-table GEMMs (both)  ∥  CSR scan
__global__ __launch_bounds__(256) void k_rel_scan(const float* __restrict__ in, int rows,
                                                  const float* __restrict__ W1,
                                                  const float* __restrict__ b1,
                                                  float* __restrict__ out1,
                                                  const float* __restrict__ W2,
                                                  float* __restrict__ out2, int RB,
                                                  const int* __restrict__ cnt, int n,
                                                  int* __restrict__ indptr) {
    __shared__ alignas(16) char smem[128 * 128 * 4];  // rel Wt (64KB); scan uses first 20B
    int b = blockIdx.x;
    if (b < 2 * RB) rel_body(b % RB, b / RB, in, rows, W1, b1, out1, W2, out2, smem);
    else scan_body(cnt, n, indptr, smem);
}

// entity standalone (latency-critical; keep CUs to itself)
__global__ __launch_bounds__(256) void k_entity(const int* __restrict__ hA,
                                                const int* __restrict__ tA,
                                                const int* __restrict__ ridx,
                                                const half_t* __restrict__ pattr,
                                                const float* __restrict__ prel,
                                                half_t* __restrict__ s_emb16, int N) {
    entity_body(blockIdx.x, hA, tA, ridx, pattr, prel, s_emb16, N);
}

// L4: GAT-1 GEMM (blocks FIRST)  ∥  atomic-free CSR fill
__global__ __launch_bounds__(256) void k_gemm1_fill(const half_t* __restrict__ A, int rows,
                                                    const float* __restrict__ W,
                                                    const float* __restrict__ rel2,
                                                    const int* __restrict__ rix,
                                                    const float* __restrict__ avs,
                                                    const float* __restrict__ avd,
                                                    float* __restrict__ als,
                                                    float* __restrict__ ald,
                                                    half_t* __restrict__ out16, int GB,
                                                    const int* __restrict__ ei, int E,
                                                    const int* __restrict__ indptr,
                                                    const int* __restrict__ rank,
                                                    int* __restrict__ adj) {
    __shared__ alignas(16) char smem[128 * 136 * 2];
    int b = blockIdx.x;
    if (b < GB) gemm_mfma_body<half_t>(b, A, rows, W, 2 * DE, 0, nullptr, rel2, rix,
                                       avs, avd, als, ald, out16, smem);
    else fill_body(b - GB, ei, E, rows, indptr, rank, adj);
}

// standalone MFMA GEMM (gat layer 2)
__global__ __launch_bounds__(256) void k_gemm_mfma_h(const half_t* __restrict__ A, int rows,
                                                     const float* __restrict__ W, int ldw, int wcol0,
                                                     const float* __restrict__ bias,
                                                     const float* __restrict__ addtab,
                                                     const int* __restrict__ addidx,
                                                     const float* __restrict__ avs,
                                                     const float* __restrict__ avd,
                                                     float* __restrict__ als,
                                                     float* __restrict__ ald,
                                                     half_t* __restrict__ out16) {
    __shared__ alignas(16) char smem[128 * 136 * 2];
    gemm_mfma_body<half_t>(blockIdx.x, A, rows, W, ldw, wcol0, bias, addtab, addidx,
                           avs, avd, als, ald, out16, smem);
}

// ---------------------------------------------------------------- GAT aggregate (CSR, pipelined; unchanged)
__global__ __launch_bounds__(256) void k_aggregate(const int* __restrict__ indptr,
                                                   const int* __restrict__ adj,
                                                   const half_t* __restrict__ hsrc,
                                                   const float* __restrict__ als,
                                                   const float* __restrict__ ald,
                                                   const float* __restrict__ bias,
                                                   float* __restrict__ out,
                                                   half_t* __restrict__ out16, int N) {
    const int tid = threadIdx.x;
    const int wv = (blockIdx.x * 256 + tid) >> 6;
    const int nodeA = wv * 2;
    if (nodeA >= N) return;
    const int lane = tid & 63;
    const int node = min(nodeA + (lane >> 5), N - 1);
    const int sl = lane & 31;
    const int c = sl * 4;

    const int beg = indptr[node];
    const int deg = indptr[node + 1] - beg;   // >= 1 (self-loop)
    const float adn = ald[node];              // pre-scaled by log2(e)
    const char* __restrict__ hb = (const char*)hsrc;
    const unsigned cb = (unsigned)sl << 3;

    float acc[4] = {0.f, 0.f, 0.f, 0.f};
    float exsum = 0.f;

    int cur[8], nxt[8];
#pragma unroll
    for (int q = 0; q < 8; ++q) cur[q] = adj[beg + q];  // batch 0 (padded)

#pragma unroll 1
    for (int j0 = 0; j0 < deg; j0 += 8) {
        if (j0 + 8 < deg) {
#pragma unroll
            for (int q = 0; q < 8; ++q) nxt[q] = adj[beg + j0 + 8 + q];
        }
        int ss[8];
        float alv[8];
        h4v hv[8];
#pragma unroll
        for (int q = 0; q < 8; ++q)
            ss[q] = ((unsigned)cur[q] < (unsigned)N) ? cur[q] : 0;
#pragma unroll
        for (int q = 0; q < 8; ++q) alv[q] = als[ss[q]];
#pragma unroll
        for (int q = 0; q < 8; ++q)
            hv[q] = *(const h4v*)(hb + (((unsigned)ss[q] << 8) + cb));
#pragma unroll
        for (int q = 0; q < 8; ++q) {
            bool ok = (j0 + q) < deg;
            float e = alv[q] + adn;
            e = fmaxf(e, NEG_SLOPE * e);
            float ex = ok ? EXP2(e - ESHIFT_AGG) : 0.f;
            exsum += ex;
#pragma unroll
            for (int j = 0; j < 4; ++j) acc[j] = fmaf(ex, (float)hv[q][j], acc[j]);
        }
#pragma unroll
        for (int q = 0; q < 8; ++q) cur[q] = nxt[q];
    }

    float inv = 1.f / exsum;
    if (out) {
        f4 o;
#pragma unroll
        for (int j = 0; j < 4; ++j) o[j] = fmaf(acc[j], inv, bias[c + j]);
        *(f4*)(out + (size_t)node * 128 + c) = o;
    } else {
        h4v o;
#pragma unroll
        for (int j = 0; j < 4; ++j) o[j] = (half_t)fmaf(acc[j], inv, bias[c + j]);
        *(h4v*)(out16 + (size_t)node * 128 + c) = o;
    }
}

// ---------------------------------------------------------------- launch
extern "C" void kernel_launch(void* const* d_in, const int* in_sizes, int n_in,
                              void* d_out, int out_size, void* d_ws, size_t ws_size,
                              hipStream_t stream) {
    const int*   hA   = (const int*)d_in[0];
    const int*   tA   = (const int*)d_in[1];
    const int*   rix  = (const int*)d_in[2];
    const int*   ei   = (const int*)d_in[3];
    const float* attr_table = (const float*)d_in[4];
    const float* rel_table  = (const float*)d_in[5];
    const float* femb_w = (const float*)d_in[6];
    const float* femb_b = (const float*)d_in[7];
    const float* g1w  = (const float*)d_in[8];
    const float* g1as = (const float*)d_in[9];
    const float* g1ad = (const float*)d_in[10];
    const float* g1b  = (const float*)d_in[11];
    const float* g2w  = (const float*)d_in[12];
    const float* g2as = (const float*)d_in[13];
    const float* g2ad = (const float*)d_in[14];
    const float* g2b  = (const float*)d_in[15];

    const int N  = in_sizes[2];
    const int E  = in_sizes[3] / 2;
    const int NA = in_sizes[4] / DE;
    const int NR = in_sizes[5] / DE;
    const int EN = E + N;

    char* p = (char*)d_ws;
    auto alloc = [&](size_t bytes) -> char* {
        char* q = p;
        p += (bytes + 255) & ~(size_t)255;
        return q;
    };
    half_t* proj16 = (half_t*)alloc((size_t)NA * DE * 2);
    half_t* s16    = (half_t*)alloc((size_t)N * DE * 2);
    half_t* h16    = (half_t*)alloc((size_t)N * DE * 2);
    half_t* x116   = (half_t*)alloc((size_t)N * DE * 2);
    float* prel    = (float*)alloc((size_t)NR * DE * 4);
    float* rel2    = (float*)alloc((size_t)NR * DE * 4);
    float* alps    = (float*)alloc((size_t)N * 4);
    float* alpd    = (float*)alloc((size_t)N * 4);
    int*   indptr  = (int*)alloc((size_t)(N + 1) * 4);
    int*   cnt     = (int*)alloc((size_t)N * 4);
    int*   rank    = (int*)alloc((size_t)EN * 4);
    int*   adj     = (int*)alloc((size_t)(EN + 16) * 4);  // +16 pad for batch-8 over-read

    dim3 b256(256);
    const int CB = (EN + 255) / 256;         // count/fill blocks
    const int MB = (NA + 63) / 64;           // attr mfma blocks
    const int RB = (NR + 31) / 32;           // rel gemm blocks (per W)
    const int GB = (N + 63) / 64;            // gat gemm blocks
    const int EB = (N + 3) / 4;              // entity blocks

    hipMemsetAsync(cnt, 0, (size_t)N * 4, stream);

    // L1: attr MFMA (first) ∥ CSR count (+rank record)
    k_attr_count<<<dim3(MB + CB), b256, 0, stream>>>(attr_table, NA, femb_w, femb_b,
                                                     proj16, MB, ei, E, N, cnt, rank);

    // L2: rel-table GEMMs ∥ CSR scan
    k_rel_scan<<<dim3(2 * RB + 1), b256, 0, stream>>>(rel_table, NR, femb_w, femb_b, prel,
                                                      g1w, rel2, RB, cnt, N, indptr);

    // L3: entity attention STANDALONE (latency-critical)
    k_entity<<<dim3(EB), b256, 0, stream>>>(hA, tA, rix, proj16, prel, s16, N);

    // L4: GAT-1 GEMM (first) ∥ atomic-free CSR fill
    k_gemm1_fill<<<dim3(GB + CB), b256, 0, stream>>>(s16, N, g1w, rel2, rix,
                                                     g1as, g1ad, alps, alpd, h16, GB,
                                                     ei, E, indptr, rank, adj);

    k_aggregate<<<dim3((N + 7) / 8), b256, 0, stream>>>(indptr, adj, h16, alps, alpd, g1b,
                                                        nullptr, x116, N);

    // GAT layer 2
    k_gemm_mfma_h<<<dim3(GB), b256, 0, stream>>>(x116, N,
        g2w, DE, 0, nullptr, nullptr, nullptr, g2as, g2ad, alps, alpd, h16);
    k_aggregate<<<dim3((N + 7) / 8), b256, 0, stream>>>(indptr, adj, h16, alps, alpd, g2b,
                                                        (float*)d_out, nullptr, N);
}

// Round 17
// 251.558 us; speedup vs baseline: 1.6023x; 1.0562x over previous
//
#include <hip/hip_runtime.h>
#include <math.h>

#define DE 128
#define NEG_SLOPE 0.2f
#define LOG2E 1.4426950408889634f
#define ESHIFT2 57.707801635559926f      /* 40 * log2(e)  (entity) */
#define ESHIFT_AGG 28.853900817779268f   /* 20 * log2(e)  (aggregate) */
#define EXP2(x) __builtin_amdgcn_exp2f(x)  /* raw v_exp_f32; inputs bounded */

typedef __attribute__((ext_vector_type(4))) float f4;
typedef __attribute__((ext_vector_type(2))) float f2;
typedef _Float16 half_t;
typedef __attribute__((ext_vector_type(2))) _Float16 h2;
typedef __attribute__((ext_vector_type(4))) _Float16 h4v;
typedef __attribute__((ext_vector_type(8))) _Float16 h8;

// Wave64 sum-reduce on the VALU only (DPP adds + readlane), zero LDS-pipe ops.
__device__ __forceinline__ float wave_red_bcast(float x) {
    union fi { float f; int i; };
    fi a; a.f = x;
    fi t;
    t.i = __builtin_amdgcn_update_dpp(0, a.i, 0x111, 0xf, 0xf, true); a.f += t.f; // row_shr:1
    t.i = __builtin_amdgcn_update_dpp(0, a.i, 0x112, 0xf, 0xf, true); a.f += t.f; // row_shr:2
    t.i = __builtin_amdgcn_update_dpp(0, a.i, 0x114, 0xf, 0xf, true); a.f += t.f; // row_shr:4
    t.i = __builtin_amdgcn_update_dpp(0, a.i, 0x118, 0xf, 0xf, true); a.f += t.f; // row_shr:8
    t.i = __builtin_amdgcn_update_dpp(0, a.i, 0x142, 0xa, 0xf, true); a.f += t.f; // row_bcast:15
    t.i = __builtin_amdgcn_update_dpp(0, a.i, 0x143, 0xc, 0xf, true); a.f += t.f; // row_bcast:31
    fi r; r.i = __builtin_amdgcn_readlane(a.i, 63);
    return r.f;
}

// All-reduce within each 16-lane DPP row (lane gets its row's sum). 4 DPP adds.
__device__ __forceinline__ float row16_allred(float x) {
    union fi { float f; int i; };
    fi a; a.f = x;
    fi t;
    t.i = __builtin_amdgcn_update_dpp(0, a.i, 0x121, 0xf, 0xf, true); a.f += t.f; // row_ror:1
    t.i = __builtin_amdgcn_update_dpp(0, a.i, 0x122, 0xf, 0xf, true); a.f += t.f; // row_ror:2
    t.i = __builtin_amdgcn_update_dpp(0, a.i, 0x124, 0xf, 0xf, true); a.f += t.f; // row_ror:4
    t.i = __builtin_amdgcn_update_dpp(0, a.i, 0x128, 0xf, 0xf, true); a.f += t.f; // row_ror:8
    return a.f;
}

// ================================================================ CSR bodies
// count ALSO records each edge's rank among same-dst edges (atomic return value)
// -> fill needs NO atomics at all.
__device__ __forceinline__ void count_body(int bid, const int* __restrict__ ei, int E, int N,
                                           int* __restrict__ cnt, int* __restrict__ rank) {
    int e = bid * 256 + threadIdx.x;
    int total = E + N;
    if (e >= total) return;
    int dst = (e < E) ? ei[E + e] : (e - E);
    rank[e] = atomicAdd(&cnt[dst], 1);  // rank write is coalesced (indexed by e)
}

// 256-thread block scan, 4 items/thread per 1024-tile. smem: >= 5 ints.
__device__ void scan_body(const int* __restrict__ cnt, int n, int* __restrict__ indptr,
                          char* smem) {
    int* wsum = (int*)smem;       // [4]
    int* btot = (int*)smem + 4;
    const int tid = threadIdx.x, lane = tid & 63, w = tid >> 6;
    int carry = 0;
    for (int base = 0; base < n; base += 1024) {
        int i0 = base + tid * 4;
        int4 v = {0, 0, 0, 0};
        if (i0 + 3 < n) v = *(const int4*)(cnt + i0);
        else {
            if (i0 < n)     v.x = cnt[i0];
            if (i0 + 1 < n) v.y = cnt[i0 + 1];
            if (i0 + 2 < n) v.z = cnt[i0 + 2];
        }
        int s = v.x + v.y + v.z + v.w;
        int x = s;
#pragma unroll
        for (int off = 1; off < 64; off <<= 1) {
            int t = __shfl_up(x, off, 64);
            if (lane >= off) x += t;
        }
        if (lane == 63) wsum[w] = x;
        __syncthreads();
        if (tid == 0) {
            int acc = 0;
#pragma unroll
            for (int k = 0; k < 4; ++k) { int t = wsum[k]; wsum[k] = acc; acc += t; }
            *btot = acc;
        }
        __syncthreads();
        int excl = carry + wsum[w] + (x - s);
        if (i0 < n)     indptr[i0]     = excl;
        if (i0 + 1 < n) indptr[i0 + 1] = excl + v.x;
        if (i0 + 2 < n) indptr[i0 + 2] = excl + v.x + v.y;
        if (i0 + 3 < n) indptr[i0 + 3] = excl + v.x + v.y + v.z;
        carry += *btot;
        __syncthreads();
    }
    if (tid == 0) indptr[n] = carry;
}

// atomic-free fill: pos = indptr[dst] + rank[e]
__device__ __forceinline__ void fill_body(int bid, const int* __restrict__ ei, int E, int N,
                                          const int* __restrict__ indptr,
                                          const int* __restrict__ rank,
                                          int* __restrict__ adj) {
    int e = bid * 256 + threadIdx.x;
    int total = E + N;
    if (e >= total) return;
    int src, dst;
    if (e < E) { src = ei[e]; dst = ei[E + e]; }
    else       { src = dst = e - E; }
    adj[indptr[dst] + rank[e]] = src;
}

// ================================================================ rel-table GEMM body (500 rows)
__device__ void rel_body(int bx, int sel, const float* __restrict__ in, int rows,
                         const float* __restrict__ W1, const float* __restrict__ bias1,
                         float* __restrict__ out1, const float* __restrict__ W2,
                         float* __restrict__ out2, char* smem) {
    const float* W; int ldw, wcol0; const float* bias; float* out;
    if (sel == 0) { W = W1; ldw = DE;     wcol0 = 0;  bias = bias1;   out = out1; }
    else          { W = W2; ldw = 2 * DE; wcol0 = DE; bias = nullptr; out = out2; }

    float* Wt = (float*)smem;  // [128*128]
    const int tid = threadIdx.x;
#pragma unroll
    for (int it = 0; it < 16; ++it) {
        int idx = it * 256 + tid;
        int c = idx & 127, k4 = idx >> 7;
        f4 wv = *(const f4*)(W + (size_t)c * ldw + wcol0 + k4 * 4);
#pragma unroll
        for (int j = 0; j < 4; ++j) Wt[(4 * k4 + j) * 128 + c] = wv[j];
    }
    __syncthreads();

    const int RPT = 2;
    const int cgrp = tid & 15, rgrp = tid >> 4;
    const int c0 = cgrp * 4;
    const int row0 = bx * (16 * RPT) + rgrp * RPT;

    const float* rowp[RPT];
#pragma unroll
    for (int i = 0; i < RPT; ++i)
        rowp[i] = in + (size_t)min(row0 + i, rows - 1) * 128;

    float acc[RPT][8];
#pragma unroll
    for (int i = 0; i < RPT; ++i)
#pragma unroll
        for (int j = 0; j < 8; ++j) acc[i][j] = 0.f;

#pragma unroll 1
    for (int k = 0; k < 128; k += 4) {
        f4 a[RPT];
#pragma unroll
        for (int i = 0; i < RPT; ++i) a[i] = *(const f4*)(rowp[i] + k);
#pragma unroll
        for (int kk = 0; kk < 4; ++kk) {
            f4 b0 = *(const f4*)&Wt[(k + kk) * 128 + c0];
            f4 b1 = *(const f4*)&Wt[(k + kk) * 128 + c0 + 64];
#pragma unroll
            for (int i = 0; i < RPT; ++i) {
                float av = a[i][kk];
#pragma unroll
                for (int j = 0; j < 4; ++j) {
                    acc[i][j]     = fmaf(av, b0[j], acc[i][j]);
                    acc[i][j + 4] = fmaf(av, b1[j], acc[i][j + 4]);
                }
            }
        }
    }
    f4 bi0 = {0.f,0.f,0.f,0.f}, bi1 = {0.f,0.f,0.f,0.f};
    if (bias) { bi0 = *(const f4*)(bias + c0); bi1 = *(const f4*)(bias + c0 + 64); }
#pragma unroll
    for (int i = 0; i < RPT; ++i) {
        int r = row0 + i;
        if (r < rows) {
            f4 v0, v1;
#pragma unroll
            for (int j = 0; j < 4; ++j) { v0[j] = acc[i][j] + bi0[j]; v1[j] = acc[i][j+4] + bi1[j]; }
            *(f4*)(out + (size_t)r * 128 + c0) = v0;
            *(f4*)(out + (size_t)r * 128 + c0 + 64) = v1;
        }
    }
}

// ================================================================ MFMA GEMM body (fp16 in, f32 acc)
// als/ald stored PRE-SCALED by log2(e). smem: 128*136*2 bytes.
template <typename AT>
__device__ void gemm_mfma_body(int bid, const AT* __restrict__ A, int rows,
                               const float* __restrict__ W, int ldw, int wcol0,
                               const float* __restrict__ bias,
                               const float* __restrict__ addtab,
                               const int* __restrict__ addidx,
                               const float* __restrict__ avs,
                               const float* __restrict__ avd,
                               float* __restrict__ als,
                               float* __restrict__ ald,
                               half_t* __restrict__ out16, char* smem) {
    half_t* Wl = (half_t*)smem;
    float*  Dl = (float*)smem;

    const int tid = threadIdx.x;
    const int row0 = bid * 64;

    for (int i = tid * 4; i < 128 * 128; i += 1024) {
        int c = i >> 7, k = i & 127;
        f4 wv = *(const f4*)(W + (size_t)c * ldw + wcol0 + k);
        h4v hv = {(half_t)wv[0], (half_t)wv[1], (half_t)wv[2], (half_t)wv[3]};
        *(h4v*)(Wl + c * 136 + k) = hv;
    }
    __syncthreads();

    const int wv_id = tid >> 6, l = tid & 63, lr = l & 15, lk = l >> 4;
    const int r_a = min(row0 + wv_id * 16 + lr, rows - 1);

    h8 af[4];
#pragma unroll
    for (int ks = 0; ks < 4; ++ks) {
        if constexpr (sizeof(AT) == 4) {
            f4 a0 = *(const f4*)(A + (size_t)r_a * 128 + ks * 32 + lk * 8);
            f4 a1 = *(const f4*)(A + (size_t)r_a * 128 + ks * 32 + lk * 8 + 4);
            h8 v = {(half_t)a0[0], (half_t)a0[1], (half_t)a0[2], (half_t)a0[3],
                    (half_t)a1[0], (half_t)a1[1], (half_t)a1[2], (half_t)a1[3]};
            af[ks] = v;
        } else {
            af[ks] = *(const h8*)(A + (size_t)r_a * 128 + ks * 32 + lk * 8);
        }
    }

    f4 acc[8];
#pragma unroll
    for (int t = 0; t < 8; ++t) acc[t] = (f4){0.f, 0.f, 0.f, 0.f};
#pragma unroll
    for (int ks = 0; ks < 4; ++ks) {
#pragma unroll
        for (int t = 0; t < 8; ++t) {
            h8 bf = *(const h8*)(Wl + (t * 16 + lr) * 136 + ks * 32 + lk * 8);
            acc[t] = __builtin_amdgcn_mfma_f32_16x16x32_f16(af[ks], bf, acc[t], 0, 0, 0);
        }
    }
    __syncthreads();

#pragma unroll
    for (int t = 0; t < 8; ++t)
#pragma unroll
        for (int q = 0; q < 4; ++q)
            Dl[(wv_id * 16 + lk * 4 + q) * 132 + t * 16 + lr] = acc[t][q];
    __syncthreads();

    const int cl = (tid & 15) * 8;
    f4 bi0 = {0.f,0.f,0.f,0.f}, bi1 = bi0;
    if (bias) { bi0 = *(const f4*)(bias + cl); bi1 = *(const f4*)(bias + cl + 4); }
    f4 as0 = {0.f,0.f,0.f,0.f}, as1 = as0, ad0 = as0, ad1 = as0;
    if (als) {
        as0 = *(const f4*)(avs + cl) * LOG2E; as1 = *(const f4*)(avs + cl + 4) * LOG2E;
        ad0 = *(const f4*)(avd + cl) * LOG2E; ad1 = *(const f4*)(avd + cl + 4) * LOG2E;
    }
#pragma unroll
    for (int pass = 0; pass < 4; ++pass) {
        int lrow = pass * 16 + (tid >> 4);
        int r = row0 + lrow;
        bool ok = r < rows;
        f4 v0 = *(const f4*)(Dl + lrow * 132 + cl);
        f4 v1 = *(const f4*)(Dl + lrow * 132 + cl + 4);
        v0 += bi0; v1 += bi1;
        if (addtab) {
            int ri = addidx[min(r, rows - 1)];
            v0 += *(const f4*)(addtab + (size_t)ri * 128 + cl);
            v1 += *(const f4*)(addtab + (size_t)ri * 128 + cl + 4);
        }
        if (als) {
            float ps = 0.f, pd = 0.f;
#pragma unroll
            for (int j = 0; j < 4; ++j) {
                ps += v0[j] * as0[j] + v1[j] * as1[j];
                pd += v0[j] * ad0[j] + v1[j] * ad1[j];
            }
            ps = row16_allred(ps);
            pd = row16_allred(pd);
            if ((tid & 15) == 0 && ok) { als[r] = ps; ald[r] = pd; }
        }
        if (ok) {
            h8 o = {(half_t)v0[0], (half_t)v0[1], (half_t)v0[2], (half_t)v0[3],
                    (half_t)v1[0], (half_t)v1[1], (half_t)v1[2], (half_t)v1[3]};
            *(h8*)(out16 + (size_t)r * 128 + cl) = o;
        }
    }
}

// ================================================================ entity body (FROZEN structure)
__device__ void entity_body(int bid, const int* __restrict__ hA,
                            const int* __restrict__ tA,
                            const int* __restrict__ ridx,
                            const half_t* __restrict__ pattr,
                            const float* __restrict__ prel,
                            half_t* __restrict__ s_emb16, int N) {
    int w = (bid * 256 + (int)threadIdx.x) >> 6;
    if (w >= N) return;
    w = __builtin_amdgcn_readfirstlane(w);
    const int lane = threadIdx.x & 63;
    const int c = lane * 2;
    const int ri = ridx[w];
    const f2 rp = *(const f2*)(prel + (size_t)ri * 128 + c);
    const h2 rph = {(half_t)(rp[0] * LOG2E), (half_t)(rp[1] * LOG2E)};
    const float init = (lane == 0) ? -ESHIFT2 : 0.f;
    const int* __restrict__ hp = hA + (size_t)w * 16;
    const int* __restrict__ tp = tA + (size_t)w * 16;
    const char* __restrict__ pb = (const char*)pattr;
    const unsigned cb = (unsigned)lane << 2;

    f2 oh = {0.f, 0.f}, ot = {0.f, 0.f};
    float sh = 0.f, st = 0.f;

    auto ld = [&](int idx) -> h2 {
        return *(const h2*)(pb + (((unsigned)idx << 8) + cb));
    };

    h2 bh[2][4], bt[2][4];
#pragma unroll
    for (int q = 0; q < 4; ++q) {
        bh[0][q] = ld(hp[q]);
        bt[0][q] = ld(tp[q]);
    }
#pragma unroll
    for (int b = 0; b < 4; ++b) {
        const int cur = b & 1, nxt = cur ^ 1;
        if (b < 3) {
#pragma unroll
            for (int q = 0; q < 4; ++q) {
                bh[nxt][q] = ld(hp[4 * (b + 1) + q]);
                bt[nxt][q] = ld(tp[4 * (b + 1) + q]);
            }
        }
        float pph[4], ppt[4];
#pragma unroll
        for (int q = 0; q < 4; ++q) {
            pph[q] = __builtin_amdgcn_fdot2(rph, bh[cur][q], init, false);
            ppt[q] = __builtin_amdgcn_fdot2(rph, bt[cur][q], init, false);
        }
        float Sh[4], St[4];
#pragma unroll
        for (int q = 0; q < 4; ++q) {
            Sh[q] = wave_red_bcast(pph[q]);
            St[q] = wave_red_bcast(ppt[q]);
        }
#pragma unroll
        for (int q = 0; q < 4; ++q) {
            float wh = EXP2(Sh[q]);
            float wt = EXP2(St[q]);
            sh += wh; st += wt;
            oh[0] = fmaf(wh, (float)bh[cur][q][0], oh[0]);
            oh[1] = fmaf(wh, (float)bh[cur][q][1], oh[1]);
            ot[0] = fmaf(wt, (float)bt[cur][q][0], ot[0]);
            ot[1] = fmaf(wt, (float)bt[cur][q][1], ot[1]);
        }
    }
    float invh = 1.f / sh, invt = 1.f / st;
    h2 hv = {(half_t)(oh[0] * invh + ot[0] * invt),
             (half_t)(oh[1] * invh + ot[1] * invt)};
    *(h2*)(s_emb16 + (size_t)w * 128 + c) = hv;
}

// ================================================================ fused dispatch kernels
// L1: attr-table MFMA projection (blocks FIRST — compute-critical)  ∥  CSR count+rank
__global__ __launch_bounds__(256) void k_attr_count(const float* __restrict__ attr, int NA,
                                                    const float* __restrict__ W,
                                                    const float* __restrict__ bias,
                                                    half_t* __restrict__ out16, int MB,
                                                    const int* __restrict__ ei, int E, int N,
                                                    int* __restrict__ cnt,
                                                    int* __restrict__ rank) {
    __shared__ alignas(16) char smem[128 * 136 * 2];
    int b = blockIdx.x;
    if (b < MB) gemm_mfma_body<float>(b, attr, NA, W, DE, 0, bias, nullptr, nullptr,
                                      nullptr, nullptr, nullptr, nullptr, out16, smem);
    else count_body(b - MB, ei, E, N, cnt, rank);
}

// L2: rel-table GEMMs (both)  ∥  CSR scan
__global__ __launch_bounds__(256) void k_rel_scan(const float* __restrict__ in, int rows,
                                                  const float* __restrict__ W1,
                                                  const float* __restrict__ b1,
                                                  float* __restrict__ out1,
                                                  const float* __restrict__ W2,
                                                  float* __restrict__ out2, int RB,
                                                  const int* __restrict__ cnt, int n,
                                                  int* __restrict__ indptr) {
    __shared__ alignas(16) char smem[128 * 128 * 4];  // rel Wt (64KB); scan uses first 20B
    int b = blockIdx.x;
    if (b < 2 * RB) rel_body(b % RB, b / RB, in, rows, W1, b1, out1, W2, out2, smem);
    else scan_body(cnt, n, indptr, smem);
}

// L3: entity attention (blocks FIRST — latency-critical)  ∥  atomic-free CSR fill
// r14 retry with both failure causes removed: fill has NO atomic RMW (r15) and
// entity owns the occupancy ramp (critical-first ordering). Fill's scattered
// stores land in entity's drain tail.
__global__ __launch_bounds__(256) void k_entity_fill(const int* __restrict__ hA,
                                                     const int* __restrict__ tA,
                                                     const int* __restrict__ ridx,
                                                     const half_t* __restrict__ pattr,
                                                     const float* __restrict__ prel,
                                                     half_t* __restrict__ s_emb16, int N, int EB,
                                                     const int* __restrict__ ei, int E,
                                                     const int* __restrict__ indptr,
                                                     const int* __restrict__ rank,
                                                     int* __restrict__ adj) {
    int b = blockIdx.x;
    if (b < EB) entity_body(b, hA, tA, ridx, pattr, prel, s_emb16, N);
    else fill_body(b - EB, ei, E, N, indptr, rank, adj);
}

// standalone MFMA GEMM (gat layers)
__global__ __launch_bounds__(256) void k_gemm_mfma_h(const half_t* __restrict__ A, int rows,
                                                     const float* __restrict__ W, int ldw, int wcol0,
                                                     const float* __restrict__ bias,
                                                     const float* __restrict__ addtab,
                                                     const int* __restrict__ addidx,
                                                     const float* __restrict__ avs,
                                                     const float* __restrict__ avd,
                                                     float* __restrict__ als,
                                                     float* __restrict__ ald,
                                                     half_t* __restrict__ out16) {
    __shared__ alignas(16) char smem[128 * 136 * 2];
    gemm_mfma_body<half_t>(blockIdx.x, A, rows, W, ldw, wcol0, bias, addtab, addidx,
                           avs, avd, als, ald, out16, smem);
}

// ---------------------------------------------------------------- GAT aggregate (CSR, pipelined; unchanged)
__global__ __launch_bounds__(256) void k_aggregate(const int* __restrict__ indptr,
                                                   const int* __restrict__ adj,
                                                   const half_t* __restrict__ hsrc,
                                                   const float* __restrict__ als,
                                                   const float* __restrict__ ald,
                                                   const float* __restrict__ bias,
                                                   float* __restrict__ out,
                                                   half_t* __restrict__ out16, int N) {
    const int tid = threadIdx.x;
    const int wv = (blockIdx.x * 256 + tid) >> 6;
    const int nodeA = wv * 2;
    if (nodeA >= N) return;
    const int lane = tid & 63;
    const int node = min(nodeA + (lane >> 5), N - 1);
    const int sl = lane & 31;
    const int c = sl * 4;

    const int beg = indptr[node];
    const int deg = indptr[node + 1] - beg;   // >= 1 (self-loop)
    const float adn = ald[node];              // pre-scaled by log2(e)
    const char* __restrict__ hb = (const char*)hsrc;
    const unsigned cb = (unsigned)sl << 3;

    float acc[4] = {0.f, 0.f, 0.f, 0.f};
    float exsum = 0.f;

    int cur[8], nxt[8];
#pragma unroll
    for (int q = 0; q < 8; ++q) cur[q] = adj[beg + q];  // batch 0 (padded)

#pragma unroll 1
    for (int j0 = 0; j0 < deg; j0 += 8) {
        if (j0 + 8 < deg) {
#pragma unroll
            for (int q = 0; q < 8; ++q) nxt[q] = adj[beg + j0 + 8 + q];
        }
        int ss[8];
        float alv[8];
        h4v hv[8];
#pragma unroll
        for (int q = 0; q < 8; ++q)
            ss[q] = ((unsigned)cur[q] < (unsigned)N) ? cur[q] : 0;
#pragma unroll
        for (int q = 0; q < 8; ++q) alv[q] = als[ss[q]];
#pragma unroll
        for (int q = 0; q < 8; ++q)
            hv[q] = *(const h4v*)(hb + (((unsigned)ss[q] << 8) + cb));
#pragma unroll
        for (int q = 0; q < 8; ++q) {
            bool ok = (j0 + q) < deg;
            float e = alv[q] + adn;
            e = fmaxf(e, NEG_SLOPE * e);
            float ex = ok ? EXP2(e - ESHIFT_AGG) : 0.f;
            exsum += ex;
#pragma unroll
            for (int j = 0; j < 4; ++j) acc[j] = fmaf(ex, (float)hv[q][j], acc[j]);
        }
#pragma unroll
        for (int q = 0; q < 8; ++q) cur[q] = nxt[q];
    }

    float inv = 1.f / exsum;
    if (out) {
        f4 o;
#pragma unroll
        for (int j = 0; j < 4; ++j) o[j] = fmaf(acc[j], inv, bias[c + j]);
        *(f4*)(out + (size_t)node * 128 + c) = o;
    } else {
        h4v o;
#pragma unroll
        for (int j = 0; j < 4; ++j) o[j] = (half_t)fmaf(acc[j], inv, bias[c + j]);
        *(h4v*)(out16 + (size_t)node * 128 + c) = o;
    }
}

// ---------------------------------------------------------------- launch
extern "C" void kernel_launch(void* const* d_in, const int* in_sizes, int n_in,
                              void* d_out, int out_size, void* d_ws, size_t ws_size,
                              hipStream_t stream) {
    const int*   hA   = (const int*)d_in[0];
    const int*   tA   = (const int*)d_in[1];
    const int*   rix  = (const int*)d_in[2];
    const int*   ei   = (const int*)d_in[3];
    const float* attr_table = (const float*)d_in[4];
    const float* rel_table  = (const float*)d_in[5];
    const float* femb_w = (const float*)d_in[6];
    const float* femb_b = (const float*)d_in[7];
    const float* g1w  = (const float*)d_in[8];
    const float* g1as = (const float*)d_in[9];
    const float* g1ad = (const float*)d_in[10];
    const float* g1b  = (const float*)d_in[11];
    const float* g2w  = (const float*)d_in[12];
    const float* g2as = (const float*)d_in[13];
    const float* g2ad = (const float*)d_in[14];
    const float* g2b  = (const float*)d_in[15];

    const int N  = in_sizes[2];
    const int E  = in_sizes[3] / 2;
    const int NA = in_sizes[4] / DE;
    const int NR = in_sizes[5] / DE;
    const int EN = E + N;

    char* p = (char*)d_ws;
    auto alloc = [&](size_t bytes) -> char* {
        char* q = p;
        p += (bytes + 255) & ~(size_t)255;
        return q;
    };
    half_t* proj16 = (half_t*)alloc((size_t)NA * DE * 2);
    half_t* s16    = (half_t*)alloc((size_t)N * DE * 2);
    half_t* h16    = (half_t*)alloc((size_t)N * DE * 2);
    half_t* x116   = (half_t*)alloc((size_t)N * DE * 2);
    float* prel    = (float*)alloc((size_t)NR * DE * 4);
    float* rel2    = (float*)alloc((size_t)NR * DE * 4);
    float* alps    = (float*)alloc((size_t)N * 4);
    float* alpd    = (float*)alloc((size_t)N * 4);
    int*   indptr  = (int*)alloc((size_t)(N + 1) * 4);
    int*   cnt     = (int*)alloc((size_t)N * 4);
    int*   rank    = (int*)alloc((size_t)EN * 4);
    int*   adj     = (int*)alloc((size_t)(EN + 16) * 4);  // +16 pad for batch-8 over-read

    dim3 b256(256);
    const int CB = (EN + 255) / 256;         // count/fill blocks
    const int MB = (NA + 63) / 64;           // attr mfma blocks
    const int RB = (NR + 31) / 32;           // rel gemm blocks (per W)
    const int GB = (N + 63) / 64;            // gat gemm blocks
    const int EB = (N + 3) / 4;              // entity blocks

    hipMemsetAsync(cnt, 0, (size_t)N * 4, stream);

    // L1: attr MFMA (first) ∥ CSR count (+rank record)
    k_attr_count<<<dim3(MB + CB), b256, 0, stream>>>(attr_table, NA, femb_w, femb_b,
                                                     proj16, MB, ei, E, N, cnt, rank);

    // L2: rel-table GEMMs ∥ CSR scan
    k_rel_scan<<<dim3(2 * RB + 1), b256, 0, stream>>>(rel_table, NR, femb_w, femb_b, prel,
                                                      g1w, rel2, RB, cnt, N, indptr);

    // L3: entity (first) ∥ atomic-free fill
    k_entity_fill<<<dim3(EB + CB), b256, 0, stream>>>(hA, tA, rix, proj16, prel, s16, N, EB,
                                                      ei, E, indptr, rank, adj);

    // L4: GAT-1 GEMM standalone (alpha fused, pre-scaled; h fp16)
    k_gemm_mfma_h<<<dim3(GB), b256, 0, stream>>>(s16, N,
        g1w, 2 * DE, 0, nullptr, rel2, rix, g1as, g1ad, alps, alpd, h16);

    k_aggregate<<<dim3((N + 7) / 8), b256, 0, stream>>>(indptr, adj, h16, alps, alpd, g1b,
                                                        nullptr, x116, N);

    // GAT layer 2
    k_gemm_mfma_h<<<dim3(GB), b256, 0, stream>>>(x116, N,
        g2w, DE, 0, nullptr, nullptr, nullptr, g2as, g2ad, alps, alpd, h16);
    k_aggregate<<<dim3((N + 7) / 8), b256, 0, stream>>>(indptr, adj, h16, alps, alpd, g2b,
                                                        (float*)d_out, nullptr, N);
}